// Round 1
// baseline (10380.409 us; speedup 1.0000x reference)
//
#include <hip/hip_runtime.h>
#include <hip/hip_bf16.h>

#define NNODES 50000
#define NEDGES 800000
#define EN 850000   // edges + self loops

// ---------------- degree / norm ----------------
__global__ __launch_bounds__(256) void deg_kernel(const int* __restrict__ ei, float* __restrict__ deg) {
    int e = blockIdx.x * blockDim.x + threadIdx.x;
    if (e < NEDGES) atomicAdd(&deg[ei[NEDGES + e]], 1.0f);
}

__global__ __launch_bounds__(256) void dinv_kernel(const float* __restrict__ deg, float* __restrict__ dinv) {
    int i = blockIdx.x * blockDim.x + threadIdx.x;
    if (i < NNODES) dinv[i] = rsqrtf(deg[i] + 1.0f);   // +1 = self loop
}

// ---------------- fp32 tiled GEMM: C[M,Nc] = A[M,K] @ W[K,Nc], row-major ----------------
__global__ __launch_bounds__(256) void gemm_rrr(const float* __restrict__ A, const float* __restrict__ W,
                                                float* __restrict__ C, int M, int K, int Nc) {
    __shared__ float As[16][68];
    __shared__ float Bs[16][68];
    int t = threadIdx.x;
    int row0 = blockIdx.x * 64, col0 = blockIdx.y * 64;
    int tx = t & 15, ty = t >> 4;
    float c[4][4] = {};
    for (int k0 = 0; k0 < K; k0 += 16) {
        {   // A tile 64x16, transpose into As[k][m]
            int m = t >> 2, k4 = t & 3;
            int row = row0 + m;
            float4 v = make_float4(0.f, 0.f, 0.f, 0.f);
            if (row < M) v = *(const float4*)&A[(size_t)row * K + k0 + k4 * 4];
            As[k4 * 4 + 0][m] = v.x; As[k4 * 4 + 1][m] = v.y;
            As[k4 * 4 + 2][m] = v.z; As[k4 * 4 + 3][m] = v.w;
        }
        {   // B tile 16x64
            int k = t >> 4, n4 = t & 15;
            float4 v = *(const float4*)&W[(size_t)(k0 + k) * Nc + col0 + n4 * 4];
            *(float4*)&Bs[k][n4 * 4] = v;
        }
        __syncthreads();
#pragma unroll
        for (int k = 0; k < 16; ++k) {
            float a[4], b[4];
#pragma unroll
            for (int i = 0; i < 4; ++i) a[i] = As[k][ty * 4 + i];
#pragma unroll
            for (int j = 0; j < 4; ++j) b[j] = Bs[k][tx * 4 + j];
#pragma unroll
            for (int i = 0; i < 4; ++i)
#pragma unroll
                for (int j = 0; j < 4; ++j) c[i][j] += a[i] * b[j];
        }
        __syncthreads();
    }
    for (int i = 0; i < 4; ++i) {
        int row = row0 + ty * 4 + i;
        if (row < M) {
            float4 v = make_float4(c[i][0], c[i][1], c[i][2], c[i][3]);
            *(float4*)&C[(size_t)row * Nc + col0 + tx * 4] = v;
        }
    }
}

// ---------------- GCN scatter-add aggregation ----------------
__global__ __launch_bounds__(256) void gcn_agg(const float* __restrict__ h, const int* __restrict__ ei,
                                               const float* __restrict__ dinv, float* __restrict__ out,
                                               int shift /*log2(hc/4)*/) {
    int gid = blockIdx.x * blockDim.x + threadIdx.x;
    int total = EN << shift;
    if (gid >= total) return;
    int e = gid >> shift;
    int per = 1 << shift;
    int f = gid & (per - 1);
    int s, d;
    if (e < NEDGES) { s = ei[e]; d = ei[NEDGES + e]; } else { s = e - NEDGES; d = s; }
    float nrm = dinv[s] * dinv[d];
    int hc = per << 2;
    float4 v = *(const float4*)&h[(size_t)s * hc + (f << 2)];
    float* o = out + (size_t)d * hc + (f << 2);
    atomicAdd(o + 0, v.x * nrm); atomicAdd(o + 1, v.y * nrm);
    atomicAdd(o + 2, v.z * nrm); atomicAdd(o + 3, v.w * nrm);
}

// io = relu(io + b[col]) (+ res)
__global__ __launch_bounds__(256) void bias_relu_res(float* __restrict__ io, const float* __restrict__ b,
                                                     const float* __restrict__ res, int colMask, int total) {
    int i = blockIdx.x * blockDim.x + threadIdx.x;
    if (i >= total) return;
    float v = io[i] + b[i & colMask];
    v = fmaxf(v, 0.0f);
    if (res) v += res[i];
    io[i] = v;
}

// ---------------- GAT ----------------
__global__ __launch_bounds__(256) void att_logits(const float* __restrict__ hg, const float* __restrict__ a_src,
                                                  const float* __restrict__ a_dst, float* __restrict__ als,
                                                  float* __restrict__ ald) {
    int gid = blockIdx.x * blockDim.x + threadIdx.x;
    if (gid >= NNODES * 4) return;
    int n = gid >> 2, h = gid & 3;
    const float* hr = hg + (size_t)n * 256 + h * 64;
    const float* as_ = a_src + h * 64;
    const float* ad_ = a_dst + h * 64;
    float s1 = 0.f, s2 = 0.f;
#pragma unroll
    for (int f = 0; f < 64; ++f) { float x = hr[f]; s1 += x * as_[f]; s2 += x * ad_[f]; }
    als[gid] = s1; ald[gid] = s2;
}

__device__ __forceinline__ unsigned enc_f(float f) {
    unsigned u = __float_as_uint(f);
    return (u & 0x80000000u) ? ~u : (u | 0x80000000u);
}
__device__ __forceinline__ float dec_f(unsigned u) {
    return (u & 0x80000000u) ? __uint_as_float(u & 0x7fffffffu) : __uint_as_float(~u);
}

__global__ __launch_bounds__(256) void gat_pass1(const int* __restrict__ ei, const float* __restrict__ als,
                                                 const float* __restrict__ ald, float* __restrict__ eb,
                                                 unsigned* __restrict__ mmax) {
    int gid = blockIdx.x * blockDim.x + threadIdx.x;
    if (gid >= EN * 4) return;
    int e = gid >> 2, h = gid & 3;
    int s, d;
    if (e < NEDGES) { s = ei[e]; d = ei[NEDGES + e]; } else { s = e - NEDGES; d = s; }
    float sc = als[s * 4 + h] + ald[d * 4 + h];
    sc = sc < 0.f ? 0.2f * sc : sc;   // leaky_relu
    eb[gid] = sc;
    atomicMax(&mmax[d * 4 + h], enc_f(sc));
}

__global__ __launch_bounds__(256) void gat_pass2(const int* __restrict__ ei, const unsigned* __restrict__ mmax,
                                                 float* __restrict__ eb, float* __restrict__ den) {
    int gid = blockIdx.x * blockDim.x + threadIdx.x;
    if (gid >= EN * 4) return;
    int e = gid >> 2, h = gid & 3;
    int d;
    if (e < NEDGES) { d = ei[NEDGES + e]; } else { d = e - NEDGES; }
    float ex = expf(eb[gid] - dec_f(mmax[d * 4 + h]));
    eb[gid] = ex;
    atomicAdd(&den[d * 4 + h], ex);
}

__global__ __launch_bounds__(256) void gat_pass3(const int* __restrict__ ei, const float* __restrict__ hg,
                                                 const float* __restrict__ eb, const float* __restrict__ den,
                                                 float* __restrict__ out) {
    int gid = blockIdx.x * blockDim.x + threadIdx.x;
    if (gid >= EN * 64) return;
    int e = gid >> 6, f = gid & 63;
    int s, d;
    if (e < NEDGES) { s = ei[e]; d = ei[NEDGES + e]; } else { s = e - NEDGES; d = s; }
    int h = f >> 4;
    float alpha = eb[e * 4 + h] / den[d * 4 + h];
    float4 v = *(const float4*)&hg[(size_t)s * 256 + (f << 2)];
    float* o = out + (size_t)d * 256 + (f << 2);
    atomicAdd(o + 0, v.x * alpha); atomicAdd(o + 1, v.y * alpha);
    atomicAdd(o + 2, v.z * alpha); atomicAdd(o + 3, v.w * alpha);
}

// ---------------- pooling + MLP ----------------
__global__ __launch_bounds__(256) void pool_kernel(const float* __restrict__ hatt, float* __restrict__ pooled) {
    int col = threadIdx.x;
    int r0 = blockIdx.x * 256;
    int r1 = r0 + 256 < NNODES ? r0 + 256 : NNODES;
    float s = 0.f;
    for (int r = r0; r < r1; ++r) s += hatt[(size_t)r * 256 + col];
    atomicAdd(&pooled[col], s);
}

__global__ __launch_bounds__(256) void mlp_kernel(const float* __restrict__ pooled,
                                                  const float* __restrict__ Wc1, const float* __restrict__ bc1,
                                                  const float* __restrict__ Wc2, const float* __restrict__ bc2,
                                                  const float* __restrict__ Wc3, const float* __restrict__ bc3,
                                                  float* __restrict__ out) {
    __shared__ float p[256], z1[128], z2[64];
    int t = threadIdx.x;
    p[t] = pooled[t] * (1.0f / NNODES);
    __syncthreads();
    if (t < 128) {
        float s = bc1[t];
        for (int k = 0; k < 256; ++k) s += p[k] * Wc1[k * 128 + t];
        z1[t] = fmaxf(s, 0.f);
    }
    __syncthreads();
    if (t < 64) {
        float s = bc2[t];
        for (int k = 0; k < 128; ++k) s += z1[k] * Wc2[k * 64 + t];
        z2[t] = fmaxf(s, 0.f);
    }
    __syncthreads();
    if (t < 8) {
        float s = bc3[t];
        for (int k = 0; k < 64; ++k) s += z2[k] * Wc3[k * 8 + t];
        out[t] = s;
    }
}

extern "C" void kernel_launch(void* const* d_in, const int* in_sizes, int n_in,
                              void* d_out, int out_size, void* d_ws, size_t ws_size,
                              hipStream_t stream) {
    const float* x   = (const float*)d_in[0];
    const int*   ei  = (const int*)d_in[1];
    const float* W1  = (const float*)d_in[2];  const float* b1  = (const float*)d_in[3];
    const float* W2  = (const float*)d_in[4];  const float* b2  = (const float*)d_in[5];
    const float* W3  = (const float*)d_in[6];  const float* b3  = (const float*)d_in[7];
    const float* Wg  = (const float*)d_in[8];
    const float* asr = (const float*)d_in[9];  const float* ads = (const float*)d_in[10];
    const float* bg  = (const float*)d_in[11];
    const float* Wc1 = (const float*)d_in[12]; const float* bc1 = (const float*)d_in[13];
    const float* Wc2 = (const float*)d_in[14]; const float* bc2 = (const float*)d_in[15];
    const float* Wc3 = (const float*)d_in[16]; const float* bc3 = (const float*)d_in[17];
    float* out = (float*)d_out;

    char* w = (char*)d_ws;
    float* deg    = (float*)w; w += (size_t)NNODES * 4;
    float* dinv   = (float*)w; w += (size_t)NNODES * 4;
    float* bufA   = (float*)w; w += (size_t)NNODES * 256 * 4;
    float* bufB   = (float*)w; w += (size_t)NNODES * 256 * 4;
    float* bufC   = (float*)w; w += (size_t)NNODES * 256 * 4;
    float* als    = (float*)w; w += (size_t)NNODES * 4 * 4;
    float* ald    = (float*)w; w += (size_t)NNODES * 4 * 4;
    unsigned* mmx = (unsigned*)w; w += (size_t)NNODES * 4 * 4;
    float* den    = (float*)w; w += (size_t)NNODES * 4 * 4;
    float* eb     = (float*)w; w += (size_t)EN * 4 * 4;
    float* pooled = (float*)w; w += 256 * 4;

    // degree / norm
    hipMemsetAsync(deg, 0, (size_t)NNODES * 4, stream);
    deg_kernel<<<(NEDGES + 255) / 256, 256, 0, stream>>>(ei, deg);
    dinv_kernel<<<(NNODES + 255) / 256, 256, 0, stream>>>(deg, dinv);

    dim3 g256((NNODES + 63) / 64, 4);   // Nc = 256
    dim3 g128((NNODES + 63) / 64, 2);   // Nc = 128
    int aggT256 = EN * 64, aggT128 = EN * 32, e4 = EN * 4;

    // GCN 1: h1 = relu(agg(x@W1) + b1)
    gemm_rrr<<<g256, 256, 0, stream>>>(x, W1, bufA, NNODES, 128, 256);
    hipMemsetAsync(bufB, 0, (size_t)NNODES * 256 * 4, stream);
    gcn_agg<<<(aggT256 + 255) / 256, 256, 0, stream>>>(bufA, ei, dinv, bufB, 6);
    bias_relu_res<<<(NNODES * 256 + 255) / 256, 256, 0, stream>>>(bufB, b1, nullptr, 255, NNODES * 256);

    // GCN 2: h2 = relu(agg(h1@W2) + b2) + h1
    gemm_rrr<<<g256, 256, 0, stream>>>(bufB, W2, bufA, NNODES, 256, 256);
    hipMemsetAsync(bufC, 0, (size_t)NNODES * 256 * 4, stream);
    gcn_agg<<<(aggT256 + 255) / 256, 256, 0, stream>>>(bufA, ei, dinv, bufC, 6);
    bias_relu_res<<<(NNODES * 256 + 255) / 256, 256, 0, stream>>>(bufC, b2, bufB, 255, NNODES * 256);

    // GCN 3: h3 = relu(agg(h2@W3) + b3)   [N,128]
    gemm_rrr<<<g128, 256, 0, stream>>>(bufC, W3, bufA, NNODES, 256, 128);
    hipMemsetAsync(bufB, 0, (size_t)NNODES * 128 * 4, stream);
    gcn_agg<<<(aggT128 + 255) / 256, 256, 0, stream>>>(bufA, ei, dinv, bufB, 5);
    bias_relu_res<<<(NNODES * 128 + 255) / 256, 256, 0, stream>>>(bufB, b3, nullptr, 127, NNODES * 128);

    // GAT: hg = h3@Wg   [N,256] = [N,4,64]
    gemm_rrr<<<g256, 256, 0, stream>>>(bufB, Wg, bufA, NNODES, 128, 256);
    att_logits<<<(NNODES * 4 + 255) / 256, 256, 0, stream>>>(bufA, asr, ads, als, ald);
    hipMemsetAsync(mmx, 0, (size_t)NNODES * 4 * 4, stream);
    hipMemsetAsync(den, 0, (size_t)NNODES * 4 * 4, stream);
    gat_pass1<<<(e4 + 255) / 256, 256, 0, stream>>>(ei, als, ald, eb, mmx);
    gat_pass2<<<(e4 + 255) / 256, 256, 0, stream>>>(ei, mmx, eb, den);
    hipMemsetAsync(bufC, 0, (size_t)NNODES * 256 * 4, stream);
    gat_pass3<<<(aggT256 + 255) / 256, 256, 0, stream>>>(ei, bufA, eb, den, bufC);
    bias_relu_res<<<(NNODES * 256 + 255) / 256, 256, 0, stream>>>(bufC, bg, nullptr, 255, NNODES * 256);

    // mean pool + MLP
    hipMemsetAsync(pooled, 0, 256 * 4, stream);
    pool_kernel<<<(NNODES + 255) / 256, 256, 0, stream>>>(bufC, pooled);
    mlp_kernel<<<1, 256, 0, stream>>>(pooled, Wc1, bc1, Wc2, bc2, Wc3, bc3, out);
}

// Round 2
// 1187.068 us; speedup vs baseline: 8.7446x; 8.7446x over previous
//
#include <hip/hip_runtime.h>
#include <hip/hip_bf16.h>

#define NNODES 50000
#define NEDGES 800000
#define EN 850000   // edges + self loops

// ---------------- degree / norm ----------------
__global__ __launch_bounds__(256) void deg_kernel(const int* __restrict__ ei, float* __restrict__ deg) {
    int e = blockIdx.x * blockDim.x + threadIdx.x;
    if (e < NEDGES) atomicAdd(&deg[ei[NEDGES + e]], 1.0f);
}

__global__ __launch_bounds__(256) void dinv_kernel(const float* __restrict__ deg, float* __restrict__ dinv) {
    int i = blockIdx.x * blockDim.x + threadIdx.x;
    if (i < NNODES) dinv[i] = rsqrtf(deg[i] + 1.0f);   // +1 = self loop
}

// ---------------- CSR build ----------------
// exclusive scan of (deg[i]+1); single block of 256 threads
__global__ __launch_bounds__(256) void scan_kernel(const float* __restrict__ deg, int* __restrict__ row) {
    __shared__ int sdata[256];
    __shared__ int run;
    int t = threadIdx.x;
    if (t == 0) run = 0;
    __syncthreads();
    int nchunks = (NNODES + 255) / 256;
    for (int c = 0; c < nchunks; ++c) {
        int idx = c * 256 + t;
        int v = idx < NNODES ? (int)deg[idx] + 1 : 0;
        sdata[t] = v;
        __syncthreads();
        for (int off = 1; off < 256; off <<= 1) {
            int tmp = t >= off ? sdata[t - off] : 0;
            __syncthreads();
            sdata[t] += tmp;
            __syncthreads();
        }
        if (idx < NNODES) row[idx] = run + sdata[t] - v;
        __syncthreads();
        if (t == 255) run += sdata[255];
        __syncthreads();
    }
    if (t == 0) row[NNODES] = run;   // == EN
}

__global__ __launch_bounds__(256) void scatter_kernel(const int* __restrict__ ei, const int* __restrict__ row,
                                                      int* __restrict__ cursor, const float* __restrict__ dinv,
                                                      int* __restrict__ csr_src, float* __restrict__ csr_w) {
    int e = blockIdx.x * blockDim.x + threadIdx.x;
    if (e >= EN) return;
    int s, d;
    if (e < NEDGES) { s = ei[e]; d = ei[NEDGES + e]; } else { s = e - NEDGES; d = s; }
    int pos = row[d] + atomicAdd(&cursor[d], 1);
    csr_src[pos] = s;
    csr_w[pos] = dinv[s] * dinv[d];
}

// ---------------- fp32 tiled GEMM: C[M,Nc] = A[M,K] @ W[K,Nc], row-major ----------------
__global__ __launch_bounds__(256) void gemm_rrr(const float* __restrict__ A, const float* __restrict__ W,
                                                float* __restrict__ C, int M, int K, int Nc) {
    __shared__ float As[16][68];
    __shared__ float Bs[16][68];
    int t = threadIdx.x;
    int row0 = blockIdx.x * 64, col0 = blockIdx.y * 64;
    int tx = t & 15, ty = t >> 4;
    float c[4][4] = {};
    for (int k0 = 0; k0 < K; k0 += 16) {
        {
            int m = t >> 2, k4 = t & 3;
            int row = row0 + m;
            float4 v = make_float4(0.f, 0.f, 0.f, 0.f);
            if (row < M) v = *(const float4*)&A[(size_t)row * K + k0 + k4 * 4];
            As[k4 * 4 + 0][m] = v.x; As[k4 * 4 + 1][m] = v.y;
            As[k4 * 4 + 2][m] = v.z; As[k4 * 4 + 3][m] = v.w;
        }
        {
            int k = t >> 4, n4 = t & 15;
            float4 v = *(const float4*)&W[(size_t)(k0 + k) * Nc + col0 + n4 * 4];
            *(float4*)&Bs[k][n4 * 4] = v;
        }
        __syncthreads();
#pragma unroll
        for (int k = 0; k < 16; ++k) {
            float a[4], b[4];
#pragma unroll
            for (int i = 0; i < 4; ++i) a[i] = As[k][ty * 4 + i];
#pragma unroll
            for (int j = 0; j < 4; ++j) b[j] = Bs[k][tx * 4 + j];
#pragma unroll
            for (int i = 0; i < 4; ++i)
#pragma unroll
                for (int j = 0; j < 4; ++j) c[i][j] += a[i] * b[j];
        }
        __syncthreads();
    }
    for (int i = 0; i < 4; ++i) {
        int row = row0 + ty * 4 + i;
        if (row < M) {
            float4 v = make_float4(c[i][0], c[i][1], c[i][2], c[i][3]);
            *(float4*)&C[(size_t)row * Nc + col0 + tx * 4] = v;
        }
    }
}

// ---------------- GCN gather aggregation: one wave per dst node, fused bias+relu(+res) ----------------
template<int NC>
__global__ __launch_bounds__(256) void gcn_agg_csr(const float* __restrict__ h, const int* __restrict__ row,
                                                   const int* __restrict__ csr_src, const float* __restrict__ csr_w,
                                                   const float* __restrict__ b, const float* __restrict__ res,
                                                   float* __restrict__ out) {
    int wid = (int)((blockIdx.x * blockDim.x + threadIdx.x) >> 6);
    if (wid >= NNODES) return;
    int lane = threadIdx.x & 63;
    constexpr int V = NC / 64;
    int col = lane * V;
    float acc[V];
#pragma unroll
    for (int i = 0; i < V; ++i) acc[i] = 0.f;
    int j0 = row[wid], j1 = row[wid + 1];
    for (int j = j0; j < j1; ++j) {
        int s = csr_src[j];
        float wg = csr_w[j];
        const float* hp = &h[(size_t)s * NC + col];
        if constexpr (V == 4) {
            float4 v = *(const float4*)hp;
            acc[0] += v.x * wg; acc[1] += v.y * wg; acc[2] += v.z * wg; acc[3] += v.w * wg;
        } else {
            float2 v = *(const float2*)hp;
            acc[0] += v.x * wg; acc[1] += v.y * wg;
        }
    }
    float* op = &out[(size_t)wid * NC + col];
    const float* rp = res ? &res[(size_t)wid * NC + col] : nullptr;
#pragma unroll
    for (int i = 0; i < V; ++i) {
        float v = fmaxf(acc[i] + b[col + i], 0.f);
        if (rp) v += rp[i];
        op[i] = v;
    }
}

// ---------------- GAT ----------------
__global__ __launch_bounds__(256) void att_logits(const float* __restrict__ hg, const float* __restrict__ a_src,
                                                  const float* __restrict__ a_dst, float* __restrict__ als,
                                                  float* __restrict__ ald) {
    int gid = blockIdx.x * blockDim.x + threadIdx.x;
    if (gid >= NNODES * 4) return;
    int n = gid >> 2, h = gid & 3;
    const float* hr = hg + (size_t)n * 256 + h * 64;
    const float* as_ = a_src + h * 64;
    const float* ad_ = a_dst + h * 64;
    float s1 = 0.f, s2 = 0.f;
#pragma unroll
    for (int f = 0; f < 64; ++f) { float x = hr[f]; s1 += x * as_[f]; s2 += x * ad_[f]; }
    als[gid] = s1; ald[gid] = s2;
}

__device__ __forceinline__ float lrelu(float x) { return x < 0.f ? 0.2f * x : x; }

// one wave per dst node: softmax over in-edges (3 loops, recompute logits) + weighted gather, fused bias+relu
__global__ __launch_bounds__(256) void gat_csr(const float* __restrict__ hg, const int* __restrict__ row,
                                               const int* __restrict__ csr_src, const float* __restrict__ als,
                                               const float* __restrict__ ald, const float* __restrict__ bg,
                                               float* __restrict__ out) {
    int wid = (int)((blockIdx.x * blockDim.x + threadIdx.x) >> 6);
    if (wid >= NNODES) return;
    int lane = threadIdx.x & 63;
    int j0 = row[wid], j1 = row[wid + 1];
    float4 ad = *(const float4*)&ald[wid * 4];

    // pass 1: per-head max over edges (lane-strided)
    float m0 = -1e30f, m1 = -1e30f, m2 = -1e30f, m3 = -1e30f;
    for (int j = j0 + lane; j < j1; j += 64) {
        int s = csr_src[j];
        float4 as4 = *(const float4*)&als[s * 4];
        m0 = fmaxf(m0, lrelu(as4.x + ad.x));
        m1 = fmaxf(m1, lrelu(as4.y + ad.y));
        m2 = fmaxf(m2, lrelu(as4.z + ad.z));
        m3 = fmaxf(m3, lrelu(as4.w + ad.w));
    }
#pragma unroll
    for (int off = 32; off >= 1; off >>= 1) {
        m0 = fmaxf(m0, __shfl_xor(m0, off));
        m1 = fmaxf(m1, __shfl_xor(m1, off));
        m2 = fmaxf(m2, __shfl_xor(m2, off));
        m3 = fmaxf(m3, __shfl_xor(m3, off));
    }
    // pass 2: per-head denominator
    float d0 = 0.f, d1 = 0.f, d2 = 0.f, d3 = 0.f;
    for (int j = j0 + lane; j < j1; j += 64) {
        int s = csr_src[j];
        float4 as4 = *(const float4*)&als[s * 4];
        d0 += __expf(lrelu(as4.x + ad.x) - m0);
        d1 += __expf(lrelu(as4.y + ad.y) - m1);
        d2 += __expf(lrelu(as4.z + ad.z) - m2);
        d3 += __expf(lrelu(as4.w + ad.w) - m3);
    }
#pragma unroll
    for (int off = 32; off >= 1; off >>= 1) {
        d0 += __shfl_xor(d0, off);
        d1 += __shfl_xor(d1, off);
        d2 += __shfl_xor(d2, off);
        d3 += __shfl_xor(d3, off);
    }
    int h = lane >> 4;   // head for this lane's 4-col slice
    float mh   = h == 0 ? m0 : h == 1 ? m1 : h == 2 ? m2 : m3;
    float invh = 1.f / (h == 0 ? d0 : h == 1 ? d1 : h == 2 ? d2 : d3);
    float adh  = h == 0 ? ad.x : h == 1 ? ad.y : h == 2 ? ad.z : ad.w;

    // pass 3: weighted gather (serial over edges, all lanes on feature slices)
    int col = lane * 4;
    float4 acc = make_float4(0.f, 0.f, 0.f, 0.f);
    for (int j = j0; j < j1; ++j) {
        int s = csr_src[j];
        float e = lrelu(als[s * 4 + h] + adh);
        float alpha = __expf(e - mh) * invh;
        float4 v = *(const float4*)&hg[(size_t)s * 256 + col];
        acc.x += v.x * alpha; acc.y += v.y * alpha;
        acc.z += v.z * alpha; acc.w += v.w * alpha;
    }
    float4 bb = *(const float4*)&bg[col];
    float4 o;
    o.x = fmaxf(acc.x + bb.x, 0.f);
    o.y = fmaxf(acc.y + bb.y, 0.f);
    o.z = fmaxf(acc.z + bb.z, 0.f);
    o.w = fmaxf(acc.w + bb.w, 0.f);
    *(float4*)&out[(size_t)wid * 256 + col] = o;
}

// ---------------- pooling + MLP ----------------
__global__ __launch_bounds__(256) void pool_kernel(const float* __restrict__ hatt, float* __restrict__ pooled) {
    int col = threadIdx.x;
    int r0 = blockIdx.x * 256;
    int r1 = r0 + 256 < NNODES ? r0 + 256 : NNODES;
    float s = 0.f;
    for (int r = r0; r < r1; ++r) s += hatt[(size_t)r * 256 + col];
    atomicAdd(&pooled[col], s);
}

__global__ __launch_bounds__(256) void mlp_kernel(const float* __restrict__ pooled,
                                                  const float* __restrict__ Wc1, const float* __restrict__ bc1,
                                                  const float* __restrict__ Wc2, const float* __restrict__ bc2,
                                                  const float* __restrict__ Wc3, const float* __restrict__ bc3,
                                                  float* __restrict__ out) {
    __shared__ float p[256], z1[128], z2[64];
    int t = threadIdx.x;
    p[t] = pooled[t] * (1.0f / NNODES);
    __syncthreads();
    if (t < 128) {
        float s = bc1[t];
        for (int k = 0; k < 256; ++k) s += p[k] * Wc1[k * 128 + t];
        z1[t] = fmaxf(s, 0.f);
    }
    __syncthreads();
    if (t < 64) {
        float s = bc2[t];
        for (int k = 0; k < 128; ++k) s += z1[k] * Wc2[k * 64 + t];
        z2[t] = fmaxf(s, 0.f);
    }
    __syncthreads();
    if (t < 8) {
        float s = bc3[t];
        for (int k = 0; k < 64; ++k) s += z2[k] * Wc3[k * 8 + t];
        out[t] = s;
    }
}

extern "C" void kernel_launch(void* const* d_in, const int* in_sizes, int n_in,
                              void* d_out, int out_size, void* d_ws, size_t ws_size,
                              hipStream_t stream) {
    const float* x   = (const float*)d_in[0];
    const int*   ei  = (const int*)d_in[1];
    const float* W1  = (const float*)d_in[2];  const float* b1  = (const float*)d_in[3];
    const float* W2  = (const float*)d_in[4];  const float* b2  = (const float*)d_in[5];
    const float* W3  = (const float*)d_in[6];  const float* b3  = (const float*)d_in[7];
    const float* Wg  = (const float*)d_in[8];
    const float* asr = (const float*)d_in[9];  const float* ads = (const float*)d_in[10];
    const float* bg  = (const float*)d_in[11];
    const float* Wc1 = (const float*)d_in[12]; const float* bc1 = (const float*)d_in[13];
    const float* Wc2 = (const float*)d_in[14]; const float* bc2 = (const float*)d_in[15];
    const float* Wc3 = (const float*)d_in[16]; const float* bc3 = (const float*)d_in[17];
    float* out = (float*)d_out;

    char* w = (char*)d_ws;
    float* deg    = (float*)w; w += (size_t)NNODES * 4;
    float* dinv   = (float*)w; w += (size_t)NNODES * 4;
    int*   rowp   = (int*)w;   w += (size_t)(NNODES + 1) * 4;
    int*   cursor = (int*)w;   w += (size_t)NNODES * 4;
    int*   csr_src= (int*)w;   w += (size_t)EN * 4;
    float* csr_w  = (float*)w; w += (size_t)EN * 4;
    float* bufA   = (float*)w; w += (size_t)NNODES * 256 * 4;
    float* bufB   = (float*)w; w += (size_t)NNODES * 256 * 4;
    float* bufC   = (float*)w; w += (size_t)NNODES * 256 * 4;
    float* als    = (float*)w; w += (size_t)NNODES * 4 * 4;
    float* ald    = (float*)w; w += (size_t)NNODES * 4 * 4;
    float* pooled = (float*)w; w += 256 * 4;

    // degree / norm / CSR
    hipMemsetAsync(deg, 0, (size_t)NNODES * 4, stream);
    hipMemsetAsync(cursor, 0, (size_t)NNODES * 4, stream);
    deg_kernel<<<(NEDGES + 255) / 256, 256, 0, stream>>>(ei, deg);
    dinv_kernel<<<(NNODES + 255) / 256, 256, 0, stream>>>(deg, dinv);
    scan_kernel<<<1, 256, 0, stream>>>(deg, rowp);
    scatter_kernel<<<(EN + 255) / 256, 256, 0, stream>>>(ei, rowp, cursor, dinv, csr_src, csr_w);

    dim3 g256((NNODES + 63) / 64, 4);   // Nc = 256
    dim3 g128((NNODES + 63) / 64, 2);   // Nc = 128
    int aggBlocks = (NNODES * 64 + 255) / 256;

    // GCN 1: h1 = relu(agg(x@W1) + b1)            -> bufB
    gemm_rrr<<<g256, 256, 0, stream>>>(x, W1, bufA, NNODES, 128, 256);
    gcn_agg_csr<256><<<aggBlocks, 256, 0, stream>>>(bufA, rowp, csr_src, csr_w, b1, nullptr, bufB);

    // GCN 2: h2 = relu(agg(h1@W2) + b2) + h1      -> bufC
    gemm_rrr<<<g256, 256, 0, stream>>>(bufB, W2, bufA, NNODES, 256, 256);
    gcn_agg_csr<256><<<aggBlocks, 256, 0, stream>>>(bufA, rowp, csr_src, csr_w, b2, bufB, bufC);

    // GCN 3: h3 = relu(agg(h2@W3) + b3)           -> bufB [N,128]
    gemm_rrr<<<g128, 256, 0, stream>>>(bufC, W3, bufA, NNODES, 256, 128);
    gcn_agg_csr<128><<<aggBlocks, 256, 0, stream>>>(bufA, rowp, csr_src, csr_w, b3, nullptr, bufB);

    // GAT: hg = h3@Wg -> bufA [N,256]; fused softmax-aggregate -> bufC
    gemm_rrr<<<g256, 256, 0, stream>>>(bufB, Wg, bufA, NNODES, 128, 256);
    att_logits<<<(NNODES * 4 + 255) / 256, 256, 0, stream>>>(bufA, asr, ads, als, ald);
    gat_csr<<<aggBlocks, 256, 0, stream>>>(bufA, rowp, csr_src, als, ald, bg, bufC);

    // mean pool + MLP
    hipMemsetAsync(pooled, 0, 256 * 4, stream);
    pool_kernel<<<(NNODES + 255) / 256, 256, 0, stream>>>(bufC, pooled);
    mlp_kernel<<<1, 256, 0, stream>>>(pooled, Wc1, bc1, Wc2, bc2, Wc3, bc3, out);
}

// Round 3
// 1019.941 us; speedup vs baseline: 10.1775x; 1.1639x over previous
//
#include <hip/hip_runtime.h>
#include <hip/hip_bf16.h>

#define NNODES 50000
#define NEDGES 800000
#define EN 850000   // edges + self loops
#define SCAN_B 196  // ceil(NNODES/256)

// ---------------- degree / norm ----------------
__global__ __launch_bounds__(256) void deg_kernel(const int* __restrict__ ei, float* __restrict__ deg) {
    int e = blockIdx.x * blockDim.x + threadIdx.x;
    if (e < NEDGES) atomicAdd(&deg[ei[NEDGES + e]], 1.0f);
}

__global__ __launch_bounds__(256) void dinv_kernel(const float* __restrict__ deg, float* __restrict__ dinv) {
    int i = blockIdx.x * blockDim.x + threadIdx.x;
    if (i < NNODES) dinv[i] = rsqrtf(deg[i] + 1.0f);   // +1 = self loop
}

// ---------------- hierarchical exclusive scan of (deg[i]+1) ----------------
__global__ __launch_bounds__(256) void scan_part1(const float* __restrict__ deg, int* __restrict__ row,
                                                  int* __restrict__ bsum) {
    __shared__ int sdata[256];
    int t = threadIdx.x;
    int idx = blockIdx.x * 256 + t;
    int v = idx < NNODES ? (int)deg[idx] + 1 : 0;
    sdata[t] = v;
    __syncthreads();
    for (int off = 1; off < 256; off <<= 1) {
        int tmp = t >= off ? sdata[t - off] : 0;
        __syncthreads();
        sdata[t] += tmp;
        __syncthreads();
    }
    if (idx < NNODES) row[idx] = sdata[t] - v;    // local exclusive
    if (t == 255) bsum[blockIdx.x] = sdata[255];
}

__global__ __launch_bounds__(256) void scan_part2(int* __restrict__ bsum, int* __restrict__ bofs,
                                                  int* __restrict__ row) {
    __shared__ int sdata[256];
    int t = threadIdx.x;
    int v = t < SCAN_B ? bsum[t] : 0;
    sdata[t] = v;
    __syncthreads();
    for (int off = 1; off < 256; off <<= 1) {
        int tmp = t >= off ? sdata[t - off] : 0;
        __syncthreads();
        sdata[t] += tmp;
        __syncthreads();
    }
    if (t < SCAN_B) bofs[t] = sdata[t] - v;
    if (t == 0) row[NNODES] = EN;
}

__global__ __launch_bounds__(256) void scan_part3(int* __restrict__ row, const int* __restrict__ bofs) {
    int idx = blockIdx.x * 256 + threadIdx.x;
    if (idx < NNODES) row[idx] += bofs[blockIdx.x];
}

__global__ __launch_bounds__(256) void scatter_kernel(const int* __restrict__ ei, const int* __restrict__ row,
                                                      int* __restrict__ cursor, const float* __restrict__ dinv,
                                                      int* __restrict__ csr_src, float* __restrict__ csr_w) {
    int e = blockIdx.x * blockDim.x + threadIdx.x;
    if (e >= EN) return;
    int s, d;
    if (e < NEDGES) { s = ei[e]; d = ei[NEDGES + e]; } else { s = e - NEDGES; d = s; }
    int pos = row[d] + atomicAdd(&cursor[d], 1);
    csr_src[pos] = s;
    csr_w[pos] = dinv[s] * dinv[d];
}

// ---------------- fp32 GEMM: C[M,Nc] = A[M,K] @ W[K,Nc]; 128x128 tile, 8x8/thread ----------------
__global__ __launch_bounds__(256) void gemm_rrr(const float* __restrict__ A, const float* __restrict__ W,
                                                float* __restrict__ C, int M, int K, int Nc) {
    __shared__ float As[16][132];
    __shared__ float Bs[16][132];
    int t = threadIdx.x;
    int row0 = blockIdx.x * 128, col0 = blockIdx.y * 128;
    int tx = t & 15, ty = t >> 4;
    float c[8][8] = {};
    for (int k0 = 0; k0 < K; k0 += 16) {
        {   // A tile 128x16 -> As[k][m] (transposed)
            int m = t >> 1, kk = (t & 1) * 8;
            int row = row0 + m;
            float4 v0 = make_float4(0.f,0.f,0.f,0.f), v1 = v0;
            if (row < M) {
                const float* ap = &A[(size_t)row * K + k0 + kk];
                v0 = *(const float4*)ap;
                v1 = *(const float4*)(ap + 4);
            }
            As[kk+0][m]=v0.x; As[kk+1][m]=v0.y; As[kk+2][m]=v0.z; As[kk+3][m]=v0.w;
            As[kk+4][m]=v1.x; As[kk+5][m]=v1.y; As[kk+6][m]=v1.z; As[kk+7][m]=v1.w;
        }
        {   // B tile 16x128
            int k = t >> 4, n8 = (t & 15) * 8;
            const float* wp = &W[(size_t)(k0 + k) * Nc + col0 + n8];
            *(float4*)&Bs[k][n8]     = *(const float4*)wp;
            *(float4*)&Bs[k][n8 + 4] = *(const float4*)(wp + 4);
        }
        __syncthreads();
#pragma unroll
        for (int k = 0; k < 16; ++k) {
            float a[8], b[8];
#pragma unroll
            for (int i = 0; i < 8; ++i) a[i] = As[k][ty * 8 + i];
#pragma unroll
            for (int j = 0; j < 8; ++j) b[j] = Bs[k][tx * 8 + j];
#pragma unroll
            for (int i = 0; i < 8; ++i)
#pragma unroll
                for (int j = 0; j < 8; ++j) c[i][j] += a[i] * b[j];
        }
        __syncthreads();
    }
#pragma unroll
    for (int i = 0; i < 8; ++i) {
        int row = row0 + ty * 8 + i;
        if (row < M) {
            float* cp = &C[(size_t)row * Nc + col0 + tx * 8];
            *(float4*)cp       = make_float4(c[i][0], c[i][1], c[i][2], c[i][3]);
            *(float4*)(cp + 4) = make_float4(c[i][4], c[i][5], c[i][6], c[i][7]);
        }
    }
}

// ---------------- GCN gather aggregation: one wave per dst node, fused bias+relu(+res) ----------------
template<int NC>
__global__ __launch_bounds__(256) void gcn_agg_csr(const float* __restrict__ h, const int* __restrict__ row,
                                                   const int* __restrict__ csr_src, const float* __restrict__ csr_w,
                                                   const float* __restrict__ b, const float* __restrict__ res,
                                                   float* __restrict__ out) {
    int wid = (int)((blockIdx.x * blockDim.x + threadIdx.x) >> 6);
    if (wid >= NNODES) return;
    int lane = threadIdx.x & 63;
    constexpr int V = NC / 64;
    int col = lane * V;
    float acc[V];
#pragma unroll
    for (int i = 0; i < V; ++i) acc[i] = 0.f;
    int j0 = row[wid], j1 = row[wid + 1];
    for (int j = j0; j < j1; ++j) {
        int s = csr_src[j];
        float wg = csr_w[j];
        const float* hp = &h[(size_t)s * NC + col];
        if constexpr (V == 4) {
            float4 v = *(const float4*)hp;
            acc[0] += v.x * wg; acc[1] += v.y * wg; acc[2] += v.z * wg; acc[3] += v.w * wg;
        } else {
            float2 v = *(const float2*)hp;
            acc[0] += v.x * wg; acc[1] += v.y * wg;
        }
    }
    float* op = &out[(size_t)wid * NC + col];
    const float* rp = res ? &res[(size_t)wid * NC + col] : nullptr;
#pragma unroll
    for (int i = 0; i < V; ++i) {
        float v = fmaxf(acc[i] + b[col + i], 0.f);
        if (rp) v += rp[i];
        op[i] = v;
    }
}

// ---------------- GAT ----------------
__global__ __launch_bounds__(256) void att_logits(const float* __restrict__ hg, const float* __restrict__ a_src,
                                                  const float* __restrict__ a_dst, float* __restrict__ als,
                                                  float* __restrict__ ald) {
    int gid = blockIdx.x * blockDim.x + threadIdx.x;
    if (gid >= NNODES * 4) return;
    int n = gid >> 2, h = gid & 3;
    const float* hr = hg + (size_t)n * 256 + h * 64;
    const float* as_ = a_src + h * 64;
    const float* ad_ = a_dst + h * 64;
    float s1 = 0.f, s2 = 0.f;
#pragma unroll
    for (int f = 0; f < 64; ++f) { float x = hr[f]; s1 += x * as_[f]; s2 += x * ad_[f]; }
    als[gid] = s1; ald[gid] = s2;
}

__device__ __forceinline__ float lrelu(float x) { return x < 0.f ? 0.2f * x : x; }

__global__ __launch_bounds__(256) void gat_csr(const float* __restrict__ hg, const int* __restrict__ row,
                                               const int* __restrict__ csr_src, const float* __restrict__ als,
                                               const float* __restrict__ ald, const float* __restrict__ bg,
                                               float* __restrict__ out) {
    int wid = (int)((blockIdx.x * blockDim.x + threadIdx.x) >> 6);
    if (wid >= NNODES) return;
    int lane = threadIdx.x & 63;
    int j0 = row[wid], j1 = row[wid + 1];
    float4 ad = *(const float4*)&ald[wid * 4];

    float m0 = -1e30f, m1 = -1e30f, m2 = -1e30f, m3 = -1e30f;
    for (int j = j0 + lane; j < j1; j += 64) {
        int s = csr_src[j];
        float4 as4 = *(const float4*)&als[s * 4];
        m0 = fmaxf(m0, lrelu(as4.x + ad.x));
        m1 = fmaxf(m1, lrelu(as4.y + ad.y));
        m2 = fmaxf(m2, lrelu(as4.z + ad.z));
        m3 = fmaxf(m3, lrelu(as4.w + ad.w));
    }
#pragma unroll
    for (int off = 32; off >= 1; off >>= 1) {
        m0 = fmaxf(m0, __shfl_xor(m0, off));
        m1 = fmaxf(m1, __shfl_xor(m1, off));
        m2 = fmaxf(m2, __shfl_xor(m2, off));
        m3 = fmaxf(m3, __shfl_xor(m3, off));
    }
    float d0 = 0.f, d1 = 0.f, d2 = 0.f, d3 = 0.f;
    for (int j = j0 + lane; j < j1; j += 64) {
        int s = csr_src[j];
        float4 as4 = *(const float4*)&als[s * 4];
        d0 += __expf(lrelu(as4.x + ad.x) - m0);
        d1 += __expf(lrelu(as4.y + ad.y) - m1);
        d2 += __expf(lrelu(as4.z + ad.z) - m2);
        d3 += __expf(lrelu(as4.w + ad.w) - m3);
    }
#pragma unroll
    for (int off = 32; off >= 1; off >>= 1) {
        d0 += __shfl_xor(d0, off);
        d1 += __shfl_xor(d1, off);
        d2 += __shfl_xor(d2, off);
        d3 += __shfl_xor(d3, off);
    }
    int h = lane >> 4;
    float mh   = h == 0 ? m0 : h == 1 ? m1 : h == 2 ? m2 : m3;
    float invh = 1.f / (h == 0 ? d0 : h == 1 ? d1 : h == 2 ? d2 : d3);
    float adh  = h == 0 ? ad.x : h == 1 ? ad.y : h == 2 ? ad.z : ad.w;

    int col = lane * 4;
    float4 acc = make_float4(0.f, 0.f, 0.f, 0.f);
    for (int j = j0; j < j1; ++j) {
        int s = csr_src[j];
        float e = lrelu(als[s * 4 + h] + adh);
        float alpha = __expf(e - mh) * invh;
        float4 v = *(const float4*)&hg[(size_t)s * 256 + col];
        acc.x += v.x * alpha; acc.y += v.y * alpha;
        acc.z += v.z * alpha; acc.w += v.w * alpha;
    }
    float4 bb = *(const float4*)&bg[col];
    float4 o;
    o.x = fmaxf(acc.x + bb.x, 0.f);
    o.y = fmaxf(acc.y + bb.y, 0.f);
    o.z = fmaxf(acc.z + bb.z, 0.f);
    o.w = fmaxf(acc.w + bb.w, 0.f);
    *(float4*)&out[(size_t)wid * 256 + col] = o;
}

// ---------------- pooling + MLP ----------------
__global__ __launch_bounds__(256) void pool_kernel(const float* __restrict__ hatt, float* __restrict__ pooled) {
    int col = threadIdx.x;
    int r0 = blockIdx.x * 256;
    int r1 = r0 + 256 < NNODES ? r0 + 256 : NNODES;
    float s = 0.f;
    for (int r = r0; r < r1; ++r) s += hatt[(size_t)r * 256 + col];
    atomicAdd(&pooled[col], s);
}

__global__ __launch_bounds__(256) void mlp_kernel(const float* __restrict__ pooled,
                                                  const float* __restrict__ Wc1, const float* __restrict__ bc1,
                                                  const float* __restrict__ Wc2, const float* __restrict__ bc2,
                                                  const float* __restrict__ Wc3, const float* __restrict__ bc3,
                                                  float* __restrict__ out) {
    __shared__ float p[256], z1[128], z2[64];
    int t = threadIdx.x;
    p[t] = pooled[t] * (1.0f / NNODES);
    __syncthreads();
    if (t < 128) {
        float s = bc1[t];
        for (int k = 0; k < 256; ++k) s += p[k] * Wc1[k * 128 + t];
        z1[t] = fmaxf(s, 0.f);
    }
    __syncthreads();
    if (t < 64) {
        float s = bc2[t];
        for (int k = 0; k < 128; ++k) s += z1[k] * Wc2[k * 64 + t];
        z2[t] = fmaxf(s, 0.f);
    }
    __syncthreads();
    if (t < 8) {
        float s = bc3[t];
        for (int k = 0; k < 64; ++k) s += z2[k] * Wc3[k * 8 + t];
        out[t] = s;
    }
}

extern "C" void kernel_launch(void* const* d_in, const int* in_sizes, int n_in,
                              void* d_out, int out_size, void* d_ws, size_t ws_size,
                              hipStream_t stream) {
    const float* x   = (const float*)d_in[0];
    const int*   ei  = (const int*)d_in[1];
    const float* W1  = (const float*)d_in[2];  const float* b1  = (const float*)d_in[3];
    const float* W2  = (const float*)d_in[4];  const float* b2  = (const float*)d_in[5];
    const float* W3  = (const float*)d_in[6];  const float* b3  = (const float*)d_in[7];
    const float* Wg  = (const float*)d_in[8];
    const float* asr = (const float*)d_in[9];  const float* ads = (const float*)d_in[10];
    const float* bg  = (const float*)d_in[11];
    const float* Wc1 = (const float*)d_in[12]; const float* bc1 = (const float*)d_in[13];
    const float* Wc2 = (const float*)d_in[14]; const float* bc2 = (const float*)d_in[15];
    const float* Wc3 = (const float*)d_in[16]; const float* bc3 = (const float*)d_in[17];
    float* out = (float*)d_out;

    char* w = (char*)d_ws;
    float* deg    = (float*)w; w += (size_t)NNODES * 4;
    float* dinv   = (float*)w; w += (size_t)NNODES * 4;
    int*   rowp   = (int*)w;   w += (size_t)(NNODES + 1) * 4;
    int*   cursor = (int*)w;   w += (size_t)NNODES * 4;
    int*   bsum   = (int*)w;   w += 256 * 4;
    int*   bofs   = (int*)w;   w += 256 * 4;
    int*   csr_src= (int*)w;   w += (size_t)EN * 4;
    float* csr_w  = (float*)w; w += (size_t)EN * 4;
    float* bufA   = (float*)w; w += (size_t)NNODES * 256 * 4;
    float* bufB   = (float*)w; w += (size_t)NNODES * 256 * 4;
    float* bufC   = (float*)w; w += (size_t)NNODES * 256 * 4;
    float* als    = (float*)w; w += (size_t)NNODES * 4 * 4;
    float* ald    = (float*)w; w += (size_t)NNODES * 4 * 4;
    float* pooled = (float*)w; w += 256 * 4;

    // degree / norm / CSR
    hipMemsetAsync(deg, 0, (size_t)NNODES * 4, stream);
    hipMemsetAsync(cursor, 0, (size_t)NNODES * 4, stream);
    deg_kernel<<<(NEDGES + 255) / 256, 256, 0, stream>>>(ei, deg);
    dinv_kernel<<<(NNODES + 255) / 256, 256, 0, stream>>>(deg, dinv);
    scan_part1<<<SCAN_B, 256, 0, stream>>>(deg, rowp, bsum);
    scan_part2<<<1, 256, 0, stream>>>(bsum, bofs, rowp);
    scan_part3<<<SCAN_B, 256, 0, stream>>>(rowp, bofs);
    scatter_kernel<<<(EN + 255) / 256, 256, 0, stream>>>(ei, rowp, cursor, dinv, csr_src, csr_w);

    dim3 g256((NNODES + 127) / 128, 2);   // Nc = 256
    dim3 g128((NNODES + 127) / 128, 1);   // Nc = 128
    int aggBlocks = (NNODES * 64 + 255) / 256;

    // GCN 1: h1 = relu(agg(x@W1) + b1)            -> bufB
    gemm_rrr<<<g256, 256, 0, stream>>>(x, W1, bufA, NNODES, 128, 256);
    gcn_agg_csr<256><<<aggBlocks, 256, 0, stream>>>(bufA, rowp, csr_src, csr_w, b1, nullptr, bufB);

    // GCN 2: h2 = relu(agg(h1@W2) + b2) + h1      -> bufC
    gemm_rrr<<<g256, 256, 0, stream>>>(bufB, W2, bufA, NNODES, 256, 256);
    gcn_agg_csr<256><<<aggBlocks, 256, 0, stream>>>(bufA, rowp, csr_src, csr_w, b2, bufB, bufC);

    // GCN 3: h3 = relu(agg(h2@W3) + b3)           -> bufB [N,128]
    gemm_rrr<<<g128, 256, 0, stream>>>(bufC, W3, bufA, NNODES, 256, 128);
    gcn_agg_csr<128><<<aggBlocks, 256, 0, stream>>>(bufA, rowp, csr_src, csr_w, b3, nullptr, bufB);

    // GAT: hg = h3@Wg -> bufA [N,256]; fused softmax-aggregate -> bufC
    gemm_rrr<<<g256, 256, 0, stream>>>(bufB, Wg, bufA, NNODES, 128, 256);
    att_logits<<<(NNODES * 4 + 255) / 256, 256, 0, stream>>>(bufA, asr, ads, als, ald);
    gat_csr<<<aggBlocks, 256, 0, stream>>>(bufA, rowp, csr_src, als, ald, bg, bufC);

    // mean pool + MLP
    hipMemsetAsync(pooled, 0, 256 * 4, stream);
    pool_kernel<<<(NNODES + 255) / 256, 256, 0, stream>>>(bufC, pooled);
    mlp_kernel<<<1, 256, 0, stream>>>(pooled, Wc1, bc1, Wc2, bc2, Wc3, bc3, out);
}

// Round 4
// 861.189 us; speedup vs baseline: 12.0536x; 1.1843x over previous
//
#include <hip/hip_runtime.h>
#include <hip/hip_bf16.h>

#define NNODES 50000
#define NEDGES 800000
#define EN 850000   // edges + self loops
#define SCAN_B 196  // ceil(NNODES/256)

typedef __attribute__((ext_vector_type(8))) short bf16x8;
typedef __attribute__((ext_vector_type(4))) float f32x4;

// ---------------- degree / norm ----------------
__global__ __launch_bounds__(256) void deg_kernel(const int* __restrict__ ei, float* __restrict__ deg) {
    int e = blockIdx.x * blockDim.x + threadIdx.x;
    if (e < NEDGES) atomicAdd(&deg[ei[NEDGES + e]], 1.0f);
}

__global__ __launch_bounds__(256) void dinv_kernel(const float* __restrict__ deg, float* __restrict__ dinv) {
    int i = blockIdx.x * blockDim.x + threadIdx.x;
    if (i < NNODES) dinv[i] = rsqrtf(deg[i] + 1.0f);   // +1 = self loop
}

// ---------------- hierarchical exclusive scan of (deg[i]+1) ----------------
__global__ __launch_bounds__(256) void scan_part1(const float* __restrict__ deg, int* __restrict__ row,
                                                  int* __restrict__ bsum) {
    __shared__ int sdata[256];
    int t = threadIdx.x;
    int idx = blockIdx.x * 256 + t;
    int v = idx < NNODES ? (int)deg[idx] + 1 : 0;
    sdata[t] = v;
    __syncthreads();
    for (int off = 1; off < 256; off <<= 1) {
        int tmp = t >= off ? sdata[t - off] : 0;
        __syncthreads();
        sdata[t] += tmp;
        __syncthreads();
    }
    if (idx < NNODES) row[idx] = sdata[t] - v;
    if (t == 255) bsum[blockIdx.x] = sdata[255];
}

__global__ __launch_bounds__(256) void scan_part2(int* __restrict__ bsum, int* __restrict__ bofs,
                                                  int* __restrict__ row) {
    __shared__ int sdata[256];
    int t = threadIdx.x;
    int v = t < SCAN_B ? bsum[t] : 0;
    sdata[t] = v;
    __syncthreads();
    for (int off = 1; off < 256; off <<= 1) {
        int tmp = t >= off ? sdata[t - off] : 0;
        __syncthreads();
        sdata[t] += tmp;
        __syncthreads();
    }
    if (t < SCAN_B) bofs[t] = sdata[t] - v;
    if (t == 0) row[NNODES] = EN;
}

__global__ __launch_bounds__(256) void scan_part3(int* __restrict__ row, const int* __restrict__ bofs) {
    int idx = blockIdx.x * 256 + threadIdx.x;
    if (idx < NNODES) row[idx] += bofs[blockIdx.x];
}

__global__ __launch_bounds__(256) void scatter_kernel(const int* __restrict__ ei, const int* __restrict__ row,
                                                      int* __restrict__ cursor, const float* __restrict__ dinv,
                                                      int* __restrict__ csr_src, float* __restrict__ csr_w) {
    int e = blockIdx.x * blockDim.x + threadIdx.x;
    if (e >= EN) return;
    int s, d;
    if (e < NEDGES) { s = ei[e]; d = ei[NEDGES + e]; } else { s = e - NEDGES; d = s; }
    int pos = row[d] + atomicAdd(&cursor[d], 1);
    csr_src[pos] = s;
    csr_w[pos] = dinv[s] * dinv[d];
}

// ---------------- split helpers: fp32 -> bf16 hi + bf16 lo (truncation; residual ~2^-16) ----------------
__device__ __forceinline__ void split_bf(float x, unsigned short& h, unsigned short& l) {
    unsigned u = __float_as_uint(x);
    h = (unsigned short)(u >> 16);
    float r = x - __uint_as_float(u & 0xffff0000u);
    l = (unsigned short)(__float_as_uint(r) >> 16);
}

// W [K][N] row-major -> Wt_hi/Wt_lo [N][K] (transposed, split)
__global__ __launch_bounds__(256) void wsplit_kernel(const float* __restrict__ W, unsigned short* __restrict__ Wh,
                                                     unsigned short* __restrict__ Wl, int K, int N) {
    int idx = blockIdx.x * 256 + threadIdx.x;
    if (idx >= K * N) return;
    int n = idx / K, k = idx % K;
    unsigned short h, l;
    split_bf(W[(size_t)k * N + n], h, l);
    Wh[idx] = h; Wl[idx] = l;
}

// ---------------- split-bf16 MFMA GEMM: C[M,Nc] = A[M,K] @ W[K,Nc] ----------------
// A fp32 row-major (converted hi/lo during staging); W pre-transposed+split: Wt[N][K] bf16.
// 128x128 tile, BK=32, 4 waves (2x2 of 64x64), mfma_f32_16x16x32_bf16, 3-pass split.
// MODE 0: raw store; MODE 1: store relu(c + bias[col]).
template<int MODE>
__global__ __launch_bounds__(256) void gemm_split(const float* __restrict__ A,
                                                  const unsigned short* __restrict__ Wth,
                                                  const unsigned short* __restrict__ Wtl,
                                                  const float* __restrict__ bias,
                                                  float* __restrict__ C, int M, int K, int Nc) {
    __shared__ unsigned short As_h[128][40], As_l[128][40];
    __shared__ unsigned short Bs_h[128][40], Bs_l[128][40];
    int t = threadIdx.x;
    int row0 = blockIdx.x * 128, col0 = blockIdx.y * 128;
    int lane = t & 63, w = t >> 6;
    int mb = (w >> 1) * 64, nb = (w & 1) * 64;
    int lr = lane & 15, kg = (lane >> 4) * 8;

    f32x4 acc[4][4];
#pragma unroll
    for (int i = 0; i < 4; ++i)
#pragma unroll
        for (int j = 0; j < 4; ++j) acc[i][j] = (f32x4){0.f, 0.f, 0.f, 0.f};

    for (int k0 = 0; k0 < K; k0 += 32) {
        // stage A tile 128x32 fp32 -> hi/lo bf16
#pragma unroll
        for (int it = 0; it < 4; ++it) {
            int q = it * 256 + t;          // 0..1023
            int row = q >> 3;              // 0..127
            int kq = (q & 7) * 4;          // 0,4,..,28
            int grow = row0 + row;
            float4 v = make_float4(0.f, 0.f, 0.f, 0.f);
            if (grow < M) v = *(const float4*)&A[(size_t)grow * K + k0 + kq];
            unsigned short h0, h1, h2, h3, l0, l1, l2, l3;
            split_bf(v.x, h0, l0); split_bf(v.y, h1, l1);
            split_bf(v.z, h2, l2); split_bf(v.w, h3, l3);
            unsigned hh0 = (unsigned)h0 | ((unsigned)h1 << 16);
            unsigned hh1 = (unsigned)h2 | ((unsigned)h3 << 16);
            unsigned ll0 = (unsigned)l0 | ((unsigned)l1 << 16);
            unsigned ll1 = (unsigned)l2 | ((unsigned)l3 << 16);
            *(uint2*)&As_h[row][kq] = make_uint2(hh0, hh1);
            *(uint2*)&As_l[row][kq] = make_uint2(ll0, ll1);
        }
        // stage B tile (Wt rows = output cols) 128x32 bf16 hi/lo
#pragma unroll
        for (int it = 0; it < 2; ++it) {
            int o = it * 256 + t;          // 0..511
            int n = o >> 2;                // 0..127
            int ko = (o & 3) * 8;          // 0,8,16,24
            size_t gofs = (size_t)(col0 + n) * K + k0 + ko;
            *(uint4*)&Bs_h[n][ko] = *(const uint4*)&Wth[gofs];
            *(uint4*)&Bs_l[n][ko] = *(const uint4*)&Wtl[gofs];
        }
        __syncthreads();

        bf16x8 ah[4], al[4], bh[4], bl[4];
#pragma unroll
        for (int mf = 0; mf < 4; ++mf) {
            ah[mf] = *(const bf16x8*)&As_h[mb + mf * 16 + lr][kg];
            al[mf] = *(const bf16x8*)&As_l[mb + mf * 16 + lr][kg];
        }
#pragma unroll
        for (int nf = 0; nf < 4; ++nf) {
            bh[nf] = *(const bf16x8*)&Bs_h[nb + nf * 16 + lr][kg];
            bl[nf] = *(const bf16x8*)&Bs_l[nb + nf * 16 + lr][kg];
        }
#pragma unroll
        for (int mf = 0; mf < 4; ++mf)
#pragma unroll
            for (int nf = 0; nf < 4; ++nf) {
                acc[mf][nf] = __builtin_amdgcn_mfma_f32_16x16x32_bf16(ah[mf], bh[nf], acc[mf][nf], 0, 0, 0);
                acc[mf][nf] = __builtin_amdgcn_mfma_f32_16x16x32_bf16(al[mf], bh[nf], acc[mf][nf], 0, 0, 0);
                acc[mf][nf] = __builtin_amdgcn_mfma_f32_16x16x32_bf16(ah[mf], bl[nf], acc[mf][nf], 0, 0, 0);
            }
        __syncthreads();
    }

    // epilogue: C[row][col], col = lane&15 within frag, row = (lane>>4)*4 + reg
#pragma unroll
    for (int nf = 0; nf < 4; ++nf) {
        int col = col0 + nb + nf * 16 + lr;
        float bv = 0.f;
        if (MODE == 1) bv = bias[col];
#pragma unroll
        for (int mf = 0; mf < 4; ++mf) {
#pragma unroll
            for (int r = 0; r < 4; ++r) {
                int row = row0 + mb + mf * 16 + (lane >> 4) * 4 + r;
                if (row < M) {
                    float v = acc[mf][nf][r];
                    if (MODE == 1) v = fmaxf(v + bv, 0.f);
                    C[(size_t)row * Nc + col] = v;
                }
            }
        }
    }
}

// ---------------- GCN gather aggregation: one wave per dst node ----------------
// MODE 0: raw sum; MODE 1: relu(sum + b); MODE 2: relu(sum + b) + res
template<int NC, int MODE>
__global__ __launch_bounds__(256) void gcn_agg_csr(const float* __restrict__ h, const int* __restrict__ row,
                                                   const int* __restrict__ csr_src, const float* __restrict__ csr_w,
                                                   const float* __restrict__ b, const float* __restrict__ res,
                                                   float* __restrict__ out) {
    int wid = (int)((blockIdx.x * blockDim.x + threadIdx.x) >> 6);
    if (wid >= NNODES) return;
    int lane = threadIdx.x & 63;
    constexpr int V = NC / 64;
    int col = lane * V;
    float acc[V];
#pragma unroll
    for (int i = 0; i < V; ++i) acc[i] = 0.f;
    int j0 = row[wid], j1 = row[wid + 1];
    for (int j = j0; j < j1; ++j) {
        int s = csr_src[j];
        float wg = csr_w[j];
        const float* hp = &h[(size_t)s * NC + col];
        if constexpr (V == 4) {
            float4 v = *(const float4*)hp;
            acc[0] += v.x * wg; acc[1] += v.y * wg; acc[2] += v.z * wg; acc[3] += v.w * wg;
        } else {
            float2 v = *(const float2*)hp;
            acc[0] += v.x * wg; acc[1] += v.y * wg;
        }
    }
    float* op = &out[(size_t)wid * NC + col];
#pragma unroll
    for (int i = 0; i < V; ++i) {
        float v = acc[i];
        if (MODE >= 1) v = fmaxf(v + b[col + i], 0.f);
        if (MODE == 2) v += res[(size_t)wid * NC + col + i];
        op[i] = v;
    }
}

// ---------------- GAT ----------------
__global__ __launch_bounds__(256) void att_logits(const float* __restrict__ hg, const float* __restrict__ a_src,
                                                  const float* __restrict__ a_dst, float* __restrict__ als,
                                                  float* __restrict__ ald) {
    int gid = blockIdx.x * blockDim.x + threadIdx.x;
    if (gid >= NNODES * 4) return;
    int n = gid >> 2, h = gid & 3;
    const float* hr = hg + (size_t)n * 256 + h * 64;
    const float* as_ = a_src + h * 64;
    const float* ad_ = a_dst + h * 64;
    float s1 = 0.f, s2 = 0.f;
#pragma unroll
    for (int f = 0; f < 64; ++f) { float x = hr[f]; s1 += x * as_[f]; s2 += x * ad_[f]; }
    als[gid] = s1; ald[gid] = s2;
}

__device__ __forceinline__ float lrelu(float x) { return x < 0.f ? 0.2f * x : x; }

__global__ __launch_bounds__(256) void gat_csr(const float* __restrict__ hg, const int* __restrict__ row,
                                               const int* __restrict__ csr_src, const float* __restrict__ als,
                                               const float* __restrict__ ald, const float* __restrict__ bg,
                                               float* __restrict__ out) {
    int wid = (int)((blockIdx.x * blockDim.x + threadIdx.x) >> 6);
    if (wid >= NNODES) return;
    int lane = threadIdx.x & 63;
    int j0 = row[wid], j1 = row[wid + 1];
    float4 ad = *(const float4*)&ald[wid * 4];

    float m0 = -1e30f, m1 = -1e30f, m2 = -1e30f, m3 = -1e30f;
    for (int j = j0 + lane; j < j1; j += 64) {
        int s = csr_src[j];
        float4 as4 = *(const float4*)&als[s * 4];
        m0 = fmaxf(m0, lrelu(as4.x + ad.x));
        m1 = fmaxf(m1, lrelu(as4.y + ad.y));
        m2 = fmaxf(m2, lrelu(as4.z + ad.z));
        m3 = fmaxf(m3, lrelu(as4.w + ad.w));
    }
#pragma unroll
    for (int off = 32; off >= 1; off >>= 1) {
        m0 = fmaxf(m0, __shfl_xor(m0, off));
        m1 = fmaxf(m1, __shfl_xor(m1, off));
        m2 = fmaxf(m2, __shfl_xor(m2, off));
        m3 = fmaxf(m3, __shfl_xor(m3, off));
    }
    float d0 = 0.f, d1 = 0.f, d2 = 0.f, d3 = 0.f;
    for (int j = j0 + lane; j < j1; j += 64) {
        int s = csr_src[j];
        float4 as4 = *(const float4*)&als[s * 4];
        d0 += __expf(lrelu(as4.x + ad.x) - m0);
        d1 += __expf(lrelu(as4.y + ad.y) - m1);
        d2 += __expf(lrelu(as4.z + ad.z) - m2);
        d3 += __expf(lrelu(as4.w + ad.w) - m3);
    }
#pragma unroll
    for (int off = 32; off >= 1; off >>= 1) {
        d0 += __shfl_xor(d0, off);
        d1 += __shfl_xor(d1, off);
        d2 += __shfl_xor(d2, off);
        d3 += __shfl_xor(d3, off);
    }
    int h = lane >> 4;
    float mh   = h == 0 ? m0 : h == 1 ? m1 : h == 2 ? m2 : m3;
    float invh = 1.f / (h == 0 ? d0 : h == 1 ? d1 : h == 2 ? d2 : d3);
    float adh  = h == 0 ? ad.x : h == 1 ? ad.y : h == 2 ? ad.z : ad.w;

    int col = lane * 4;
    float4 acc = make_float4(0.f, 0.f, 0.f, 0.f);
    for (int j = j0; j < j1; ++j) {
        int s = csr_src[j];
        float e = lrelu(als[s * 4 + h] + adh);
        float alpha = __expf(e - mh) * invh;
        float4 v = *(const float4*)&hg[(size_t)s * 256 + col];
        acc.x += v.x * alpha; acc.y += v.y * alpha;
        acc.z += v.z * alpha; acc.w += v.w * alpha;
    }
    float4 bb = *(const float4*)&bg[col];
    float4 o;
    o.x = fmaxf(acc.x + bb.x, 0.f);
    o.y = fmaxf(acc.y + bb.y, 0.f);
    o.z = fmaxf(acc.z + bb.z, 0.f);
    o.w = fmaxf(acc.w + bb.w, 0.f);
    *(float4*)&out[(size_t)wid * 256 + col] = o;
}

// ---------------- pooling + MLP ----------------
__global__ __launch_bounds__(256) void pool_kernel(const float* __restrict__ hatt, float* __restrict__ pooled) {
    int col = threadIdx.x;
    int r0 = blockIdx.x * 256;
    int r1 = r0 + 256 < NNODES ? r0 + 256 : NNODES;
    float s = 0.f;
    for (int r = r0; r < r1; ++r) s += hatt[(size_t)r * 256 + col];
    atomicAdd(&pooled[col], s);
}

__global__ __launch_bounds__(256) void mlp_kernel(const float* __restrict__ pooled,
                                                  const float* __restrict__ Wc1, const float* __restrict__ bc1,
                                                  const float* __restrict__ Wc2, const float* __restrict__ bc2,
                                                  const float* __restrict__ Wc3, const float* __restrict__ bc3,
                                                  float* __restrict__ out) {
    __shared__ float p[256], z1[128], z2[64];
    int t = threadIdx.x;
    p[t] = pooled[t] * (1.0f / NNODES);
    __syncthreads();
    if (t < 128) {
        float s = bc1[t];
        for (int k = 0; k < 256; ++k) s += p[k] * Wc1[k * 128 + t];
        z1[t] = fmaxf(s, 0.f);
    }
    __syncthreads();
    if (t < 64) {
        float s = bc2[t];
        for (int k = 0; k < 128; ++k) s += z1[k] * Wc2[k * 64 + t];
        z2[t] = fmaxf(s, 0.f);
    }
    __syncthreads();
    if (t < 8) {
        float s = bc3[t];
        for (int k = 0; k < 64; ++k) s += z2[k] * Wc3[k * 8 + t];
        out[t] = s;
    }
}

extern "C" void kernel_launch(void* const* d_in, const int* in_sizes, int n_in,
                              void* d_out, int out_size, void* d_ws, size_t ws_size,
                              hipStream_t stream) {
    const float* x   = (const float*)d_in[0];
    const int*   ei  = (const int*)d_in[1];
    const float* W1  = (const float*)d_in[2];  const float* b1  = (const float*)d_in[3];
    const float* W2  = (const float*)d_in[4];  const float* b2  = (const float*)d_in[5];
    const float* W3  = (const float*)d_in[6];  const float* b3  = (const float*)d_in[7];
    const float* Wg  = (const float*)d_in[8];
    const float* asr = (const float*)d_in[9];  const float* ads = (const float*)d_in[10];
    const float* bg  = (const float*)d_in[11];
    const float* Wc1 = (const float*)d_in[12]; const float* bc1 = (const float*)d_in[13];
    const float* Wc2 = (const float*)d_in[14]; const float* bc2 = (const float*)d_in[15];
    const float* Wc3 = (const float*)d_in[16]; const float* bc3 = (const float*)d_in[17];
    float* out = (float*)d_out;

    char* w = (char*)d_ws;
    float* deg    = (float*)w; w += (size_t)NNODES * 4;          // 200000 (mult 16)
    float* dinv   = (float*)w; w += (size_t)NNODES * 4;
    int*   rowp   = (int*)w;   w += 200016;                      // (NNODES+1)*4 padded to mult 16
    int*   cursor = (int*)w;   w += (size_t)NNODES * 4;
    int*   bsum   = (int*)w;   w += 256 * 4;
    int*   bofs   = (int*)w;   w += 256 * 4;
    int*   csr_src= (int*)w;   w += (size_t)EN * 4;
    float* csr_w  = (float*)w; w += (size_t)EN * 4;
    float* bufA   = (float*)w; w += (size_t)NNODES * 256 * 4;
    float* bufB   = (float*)w; w += (size_t)NNODES * 256 * 4;
    float* bufC   = (float*)w; w += (size_t)NNODES * 256 * 4;
    float* als    = (float*)w; w += (size_t)NNODES * 4 * 4;
    float* ald    = (float*)w; w += (size_t)NNODES * 4 * 4;
    float* pooled = (float*)w; w += 256 * 4;
    unsigned short* W1th = (unsigned short*)w; w += 128 * 256 * 2;
    unsigned short* W1tl = (unsigned short*)w; w += 128 * 256 * 2;
    unsigned short* W2th = (unsigned short*)w; w += 256 * 256 * 2;
    unsigned short* W2tl = (unsigned short*)w; w += 256 * 256 * 2;
    unsigned short* W3th = (unsigned short*)w; w += 256 * 128 * 2;
    unsigned short* W3tl = (unsigned short*)w; w += 256 * 128 * 2;
    unsigned short* Wgth = (unsigned short*)w; w += 128 * 256 * 2;
    unsigned short* Wgtl = (unsigned short*)w; w += 128 * 256 * 2;

    // degree / norm / CSR
    hipMemsetAsync(deg, 0, (size_t)NNODES * 4, stream);
    hipMemsetAsync(cursor, 0, (size_t)NNODES * 4, stream);
    deg_kernel<<<(NEDGES + 255) / 256, 256, 0, stream>>>(ei, deg);
    dinv_kernel<<<(NNODES + 255) / 256, 256, 0, stream>>>(deg, dinv);
    scan_part1<<<SCAN_B, 256, 0, stream>>>(deg, rowp, bsum);
    scan_part2<<<1, 256, 0, stream>>>(bsum, bofs, rowp);
    scan_part3<<<SCAN_B, 256, 0, stream>>>(rowp, bofs);
    scatter_kernel<<<(EN + 255) / 256, 256, 0, stream>>>(ei, rowp, cursor, dinv, csr_src, csr_w);

    // weight transpose + split
    wsplit_kernel<<<(128 * 256 + 255) / 256, 256, 0, stream>>>(W1, W1th, W1tl, 128, 256);
    wsplit_kernel<<<(256 * 256 + 255) / 256, 256, 0, stream>>>(W2, W2th, W2tl, 256, 256);
    wsplit_kernel<<<(256 * 128 + 255) / 256, 256, 0, stream>>>(W3, W3th, W3tl, 256, 128);
    wsplit_kernel<<<(128 * 256 + 255) / 256, 256, 0, stream>>>(Wg, Wgth, Wgtl, 128, 256);

    dim3 gA((NNODES + 127) / 128, 2);   // Nc = 256
    dim3 gB((NNODES + 127) / 128, 1);   // Nc = 128
    int aggBlocks = (NNODES * 64 + 255) / 256;

    // GCN 1 (reordered): aggX = agg(x) [N,128] -> bufC; h1 = relu(aggX@W1 + b1) -> bufB
    gcn_agg_csr<128, 0><<<aggBlocks, 256, 0, stream>>>(x, rowp, csr_src, csr_w, nullptr, nullptr, bufC);
    gemm_split<1><<<gA, 256, 0, stream>>>(bufC, W1th, W1tl, b1, bufB, NNODES, 128, 256);

    // GCN 2: h2 = relu(agg(h1@W2) + b2) + h1 -> bufC
    gemm_split<0><<<gA, 256, 0, stream>>>(bufB, W2th, W2tl, nullptr, bufA, NNODES, 256, 256);
    gcn_agg_csr<256, 2><<<aggBlocks, 256, 0, stream>>>(bufA, rowp, csr_src, csr_w, b2, bufB, bufC);

    // GCN 3: h3 = relu(agg(h2@W3) + b3) -> bufB [N,128]
    gemm_split<0><<<gB, 256, 0, stream>>>(bufC, W3th, W3tl, nullptr, bufA, NNODES, 256, 128);
    gcn_agg_csr<128, 1><<<aggBlocks, 256, 0, stream>>>(bufA, rowp, csr_src, csr_w, b3, nullptr, bufB);

    // GAT: hg = h3@Wg -> bufA [N,256]; fused softmax-aggregate -> bufC
    gemm_split<0><<<gA, 256, 0, stream>>>(bufB, Wgth, Wgtl, nullptr, bufA, NNODES, 128, 256);
    att_logits<<<(NNODES * 4 + 255) / 256, 256, 0, stream>>>(bufA, asr, ads, als, ald);
    gat_csr<<<aggBlocks, 256, 0, stream>>>(bufA, rowp, csr_src, als, ald, bg, bufC);

    // mean pool + MLP
    hipMemsetAsync(pooled, 0, 256 * 4, stream);
    pool_kernel<<<(NNODES + 255) / 256, 256, 0, stream>>>(bufC, pooled);
    mlp_kernel<<<1, 256, 0, stream>>>(pooled, Wc1, bc1, Wc2, bc2, Wc3, bc3, out);
}

// Round 5
// 716.442 us; speedup vs baseline: 14.4888x; 1.2020x over previous
//
#include <hip/hip_runtime.h>
#include <hip/hip_bf16.h>

#define NNODES 50000
#define NEDGES 800000
#define EN 850000   // edges + self loops
#define SCAN_B 196  // ceil(NNODES/256)

typedef __attribute__((ext_vector_type(8))) short bf16x8;
typedef __attribute__((ext_vector_type(4))) float f32x4;

__device__ __forceinline__ float bf2f(unsigned short u) {
    return __uint_as_float(((unsigned)u) << 16);
}
__device__ __forceinline__ unsigned short f2bf(float x) {   // RNE
    unsigned u = __float_as_uint(x);
    u += 0x7fffu + ((u >> 16) & 1u);
    return (unsigned short)(u >> 16);
}

// ---------------- degree / norm ----------------
__global__ __launch_bounds__(256) void deg_kernel(const int* __restrict__ ei, float* __restrict__ deg) {
    int e = blockIdx.x * blockDim.x + threadIdx.x;
    if (e < NEDGES) atomicAdd(&deg[ei[NEDGES + e]], 1.0f);
}

__global__ __launch_bounds__(256) void dinv_kernel(const float* __restrict__ deg, float* __restrict__ dinv) {
    int i = blockIdx.x * blockDim.x + threadIdx.x;
    if (i < NNODES) dinv[i] = rsqrtf(deg[i] + 1.0f);   // +1 = self loop
}

// ---------------- hierarchical exclusive scan of (deg[i]+1) ----------------
__global__ __launch_bounds__(256) void scan_part1(const float* __restrict__ deg, int* __restrict__ row,
                                                  int* __restrict__ bsum) {
    __shared__ int sdata[256];
    int t = threadIdx.x;
    int idx = blockIdx.x * 256 + t;
    int v = idx < NNODES ? (int)deg[idx] + 1 : 0;
    sdata[t] = v;
    __syncthreads();
    for (int off = 1; off < 256; off <<= 1) {
        int tmp = t >= off ? sdata[t - off] : 0;
        __syncthreads();
        sdata[t] += tmp;
        __syncthreads();
    }
    if (idx < NNODES) row[idx] = sdata[t] - v;
    if (t == 255) bsum[blockIdx.x] = sdata[255];
}

__global__ __launch_bounds__(256) void scan_part2(int* __restrict__ bsum, int* __restrict__ bofs,
                                                  int* __restrict__ row) {
    __shared__ int sdata[256];
    int t = threadIdx.x;
    int v = t < SCAN_B ? bsum[t] : 0;
    sdata[t] = v;
    __syncthreads();
    for (int off = 1; off < 256; off <<= 1) {
        int tmp = t >= off ? sdata[t - off] : 0;
        __syncthreads();
        sdata[t] += tmp;
        __syncthreads();
    }
    if (t < SCAN_B) bofs[t] = sdata[t] - v;
    if (t == 0) row[NNODES] = EN;
}

__global__ __launch_bounds__(256) void scan_part3(int* __restrict__ row, const int* __restrict__ bofs) {
    int idx = blockIdx.x * 256 + threadIdx.x;
    if (idx < NNODES) row[idx] += bofs[blockIdx.x];
}

__global__ __launch_bounds__(256) void scatter_kernel(const int* __restrict__ ei, const int* __restrict__ row,
                                                      int* __restrict__ cursor, const float* __restrict__ dinv,
                                                      int* __restrict__ csr_src, float* __restrict__ csr_w) {
    int e = blockIdx.x * blockDim.x + threadIdx.x;
    if (e >= EN) return;
    int s, d;
    if (e < NEDGES) { s = ei[e]; d = ei[NEDGES + e]; } else { s = e - NEDGES; d = s; }
    int pos = row[d] + atomicAdd(&cursor[d], 1);
    csr_src[pos] = s;
    csr_w[pos] = dinv[s] * dinv[d];
}

// ---------------- fp32 -> bf16 conversion (8 elems/thread) ----------------
__global__ __launch_bounds__(256) void tobf16_kernel(const float* __restrict__ in, unsigned short* __restrict__ out,
                                                     int total8) {
    int i = blockIdx.x * 256 + threadIdx.x;
    if (i >= total8) return;
    float4 a = *(const float4*)&in[(size_t)i * 8];
    float4 b = *(const float4*)&in[(size_t)i * 8 + 4];
    *(ushort4*)&out[(size_t)i * 8]     = make_ushort4(f2bf(a.x), f2bf(a.y), f2bf(a.z), f2bf(a.w));
    *(ushort4*)&out[(size_t)i * 8 + 4] = make_ushort4(f2bf(b.x), f2bf(b.y), f2bf(b.z), f2bf(b.w));
}

// ---------------- W [K][N] fp32 -> Wt_hi/Wt_lo [N][K] bf16 (transposed, split) ----------------
__device__ __forceinline__ void split_bf(float x, unsigned short& h, unsigned short& l) {
    unsigned u = __float_as_uint(x);
    h = (unsigned short)(u >> 16);
    float r = x - __uint_as_float(u & 0xffff0000u);
    l = (unsigned short)(__float_as_uint(r) >> 16);
}

__global__ __launch_bounds__(256) void wsplit_kernel(const float* __restrict__ W, unsigned short* __restrict__ Wh,
                                                     unsigned short* __restrict__ Wl, int K, int N) {
    int idx = blockIdx.x * 256 + threadIdx.x;
    if (idx >= K * N) return;
    int n = idx / K, k = idx % K;
    unsigned short h, l;
    split_bf(W[(size_t)k * N + n], h, l);
    Wh[idx] = h; Wl[idx] = l;
}

// ---------------- bf16-input MFMA GEMM: C[M,Nc] = A[M,K] @ W[K,Nc] ----------------
// A bf16 [M][K]; W pre-transposed+split bf16 [N][K] hi/lo (2-pass split for weight fidelity).
// 128x128 tile, BK=32, 4 waves (2x2 of 64x64), mfma_f32_16x16x32_bf16.
// MODE 0: raw bf16 store; MODE 1: bf16 store of relu(c + bias[col]).
template<int MODE>
__global__ __launch_bounds__(256) void gemm_bf(const unsigned short* __restrict__ A,
                                               const unsigned short* __restrict__ Wth,
                                               const unsigned short* __restrict__ Wtl,
                                               const float* __restrict__ bias,
                                               unsigned short* __restrict__ C, int M, int K, int Nc) {
    __shared__ unsigned short As[128][40];
    __shared__ unsigned short Bh[128][40], Bl[128][40];
    int t = threadIdx.x;
    int row0 = blockIdx.x * 128, col0 = blockIdx.y * 128;
    int lane = t & 63, w = t >> 6;
    int mb = (w >> 1) * 64, nb = (w & 1) * 64;
    int lr = lane & 15, kg = (lane >> 4) * 8;

    f32x4 acc[4][4];
#pragma unroll
    for (int i = 0; i < 4; ++i)
#pragma unroll
        for (int j = 0; j < 4; ++j) acc[i][j] = (f32x4){0.f, 0.f, 0.f, 0.f};

    for (int k0 = 0; k0 < K; k0 += 32) {
        // stage A tile 128x32 bf16 (512 x 16B chunks)
#pragma unroll
        for (int it = 0; it < 2; ++it) {
            int q = it * 256 + t;
            int row = q >> 2, seg = (q & 3) * 8;
            int grow = row0 + row;
            uint4 v = make_uint4(0, 0, 0, 0);
            if (grow < M) v = *(const uint4*)&A[(size_t)grow * K + k0 + seg];
            *(uint4*)&As[row][seg] = v;
        }
        // stage B tile (Wt rows = output cols) 128x32 bf16 hi/lo
#pragma unroll
        for (int it = 0; it < 2; ++it) {
            int o = it * 256 + t;
            int n = o >> 2, ko = (o & 3) * 8;
            size_t g = (size_t)(col0 + n) * K + k0 + ko;
            *(uint4*)&Bh[n][ko] = *(const uint4*)&Wth[g];
            *(uint4*)&Bl[n][ko] = *(const uint4*)&Wtl[g];
        }
        __syncthreads();

        bf16x8 a[4], bh[4], bl[4];
#pragma unroll
        for (int mf = 0; mf < 4; ++mf) a[mf] = *(const bf16x8*)&As[mb + mf * 16 + lr][kg];
#pragma unroll
        for (int nf = 0; nf < 4; ++nf) {
            bh[nf] = *(const bf16x8*)&Bh[nb + nf * 16 + lr][kg];
            bl[nf] = *(const bf16x8*)&Bl[nb + nf * 16 + lr][kg];
        }
#pragma unroll
        for (int mf = 0; mf < 4; ++mf)
#pragma unroll
            for (int nf = 0; nf < 4; ++nf) {
                acc[mf][nf] = __builtin_amdgcn_mfma_f32_16x16x32_bf16(a[mf], bh[nf], acc[mf][nf], 0, 0, 0);
                acc[mf][nf] = __builtin_amdgcn_mfma_f32_16x16x32_bf16(a[mf], bl[nf], acc[mf][nf], 0, 0, 0);
            }
        __syncthreads();
    }

#pragma unroll
    for (int nf = 0; nf < 4; ++nf) {
        int col = col0 + nb + nf * 16 + lr;
        float bv = (MODE == 1) ? bias[col] : 0.f;
#pragma unroll
        for (int mf = 0; mf < 4; ++mf) {
#pragma unroll
            for (int r = 0; r < 4; ++r) {
                int row = row0 + mb + mf * 16 + (lane >> 4) * 4 + r;
                if (row < M) {
                    float v = acc[mf][nf][r];
                    if (MODE == 1) v = fmaxf(v + bv, 0.f);
                    C[(size_t)row * Nc + col] = f2bf(v);
                }
            }
        }
    }
}

// ---------------- GCN gather aggregation (bf16 features): one wave per dst node ----------------
// MODE 0: raw sum; MODE 1: relu(sum + b); MODE 2: relu(sum + b) + res(bf16)
template<int NC, int MODE>
__global__ __launch_bounds__(256) void gcn_agg_bf(const unsigned short* __restrict__ h, const int* __restrict__ row,
                                                  const int* __restrict__ csr_src, const float* __restrict__ csr_w,
                                                  const float* __restrict__ b, const unsigned short* __restrict__ res,
                                                  unsigned short* __restrict__ out) {
    int wid = (int)((blockIdx.x * blockDim.x + threadIdx.x) >> 6);
    if (wid >= NNODES) return;
    int lane = threadIdx.x & 63;
    constexpr int V = NC / 64;
    int col = lane * V;
    float acc[V];
#pragma unroll
    for (int i = 0; i < V; ++i) acc[i] = 0.f;
    int j0 = row[wid], j1 = row[wid + 1];
    for (int j = j0; j < j1; ++j) {
        int s = csr_src[j];
        float wg = csr_w[j];
        const unsigned short* hp = &h[(size_t)s * NC + col];
        if constexpr (V == 4) {
            ushort4 v = *(const ushort4*)hp;
            acc[0] += bf2f(v.x) * wg; acc[1] += bf2f(v.y) * wg;
            acc[2] += bf2f(v.z) * wg; acc[3] += bf2f(v.w) * wg;
        } else {
            ushort2 v = *(const ushort2*)hp;
            acc[0] += bf2f(v.x) * wg; acc[1] += bf2f(v.y) * wg;
        }
    }
    unsigned short o[V];
#pragma unroll
    for (int i = 0; i < V; ++i) {
        float v = acc[i];
        if (MODE >= 1) v = fmaxf(v + b[col + i], 0.f);
        if (MODE == 2) v += bf2f(res[(size_t)wid * NC + col + i]);
        o[i] = f2bf(v);
    }
    if constexpr (V == 4) *(ushort4*)&out[(size_t)wid * NC + col] = make_ushort4(o[0], o[1], o[2], o[3]);
    else *(ushort2*)&out[(size_t)wid * NC + col] = make_ushort2(o[0], o[1]);
}

// ---------------- GAT ----------------
__global__ __launch_bounds__(256) void att_logits(const unsigned short* __restrict__ hg,
                                                  const float* __restrict__ a_src, const float* __restrict__ a_dst,
                                                  float* __restrict__ als, float* __restrict__ ald) {
    int gid = blockIdx.x * blockDim.x + threadIdx.x;
    if (gid >= NNODES * 4) return;
    int n = gid >> 2, h = gid & 3;
    const unsigned short* hr = hg + (size_t)n * 256 + h * 64;
    const float* as_ = a_src + h * 64;
    const float* ad_ = a_dst + h * 64;
    float s1 = 0.f, s2 = 0.f;
#pragma unroll
    for (int f = 0; f < 64; f += 4) {
        ushort4 v = *(const ushort4*)&hr[f];
        float x0 = bf2f(v.x), x1 = bf2f(v.y), x2 = bf2f(v.z), x3 = bf2f(v.w);
        s1 += x0 * as_[f] + x1 * as_[f + 1] + x2 * as_[f + 2] + x3 * as_[f + 3];
        s2 += x0 * ad_[f] + x1 * ad_[f + 1] + x2 * ad_[f + 2] + x3 * ad_[f + 3];
    }
    als[gid] = s1; ald[gid] = s2;
}

__device__ __forceinline__ float lrelu(float x) { return x < 0.f ? 0.2f * x : x; }

__global__ __launch_bounds__(256) void gat_csr(const unsigned short* __restrict__ hg, const int* __restrict__ row,
                                               const int* __restrict__ csr_src, const float* __restrict__ als,
                                               const float* __restrict__ ald, const float* __restrict__ bg,
                                               unsigned short* __restrict__ out) {
    int wid = (int)((blockIdx.x * blockDim.x + threadIdx.x) >> 6);
    if (wid >= NNODES) return;
    int lane = threadIdx.x & 63;
    int j0 = row[wid], j1 = row[wid + 1];
    float4 ad = *(const float4*)&ald[wid * 4];

    float m0 = -1e30f, m1 = -1e30f, m2 = -1e30f, m3 = -1e30f;
    for (int j = j0 + lane; j < j1; j += 64) {
        int s = csr_src[j];
        float4 as4 = *(const float4*)&als[s * 4];
        m0 = fmaxf(m0, lrelu(as4.x + ad.x));
        m1 = fmaxf(m1, lrelu(as4.y + ad.y));
        m2 = fmaxf(m2, lrelu(as4.z + ad.z));
        m3 = fmaxf(m3, lrelu(as4.w + ad.w));
    }
#pragma unroll
    for (int off = 32; off >= 1; off >>= 1) {
        m0 = fmaxf(m0, __shfl_xor(m0, off));
        m1 = fmaxf(m1, __shfl_xor(m1, off));
        m2 = fmaxf(m2, __shfl_xor(m2, off));
        m3 = fmaxf(m3, __shfl_xor(m3, off));
    }
    float d0 = 0.f, d1 = 0.f, d2 = 0.f, d3 = 0.f;
    for (int j = j0 + lane; j < j1; j += 64) {
        int s = csr_src[j];
        float4 as4 = *(const float4*)&als[s * 4];
        d0 += __expf(lrelu(as4.x + ad.x) - m0);
        d1 += __expf(lrelu(as4.y + ad.y) - m1);
        d2 += __expf(lrelu(as4.z + ad.z) - m2);
        d3 += __expf(lrelu(as4.w + ad.w) - m3);
    }
#pragma unroll
    for (int off = 32; off >= 1; off >>= 1) {
        d0 += __shfl_xor(d0, off);
        d1 += __shfl_xor(d1, off);
        d2 += __shfl_xor(d2, off);
        d3 += __shfl_xor(d3, off);
    }
    int h = lane >> 4;
    float mh   = h == 0 ? m0 : h == 1 ? m1 : h == 2 ? m2 : m3;
    float invh = 1.f / (h == 0 ? d0 : h == 1 ? d1 : h == 2 ? d2 : d3);
    float adh  = h == 0 ? ad.x : h == 1 ? ad.y : h == 2 ? ad.z : ad.w;

    int col = lane * 4;
    float4 acc = make_float4(0.f, 0.f, 0.f, 0.f);
    for (int j = j0; j < j1; ++j) {
        int s = csr_src[j];
        float e = lrelu(als[s * 4 + h] + adh);
        float alpha = __expf(e - mh) * invh;
        ushort4 v = *(const ushort4*)&hg[(size_t)s * 256 + col];
        acc.x += bf2f(v.x) * alpha; acc.y += bf2f(v.y) * alpha;
        acc.z += bf2f(v.z) * alpha; acc.w += bf2f(v.w) * alpha;
    }
    float4 bb = *(const float4*)&bg[col];
    unsigned short o0 = f2bf(fmaxf(acc.x + bb.x, 0.f));
    unsigned short o1 = f2bf(fmaxf(acc.y + bb.y, 0.f));
    unsigned short o2 = f2bf(fmaxf(acc.z + bb.z, 0.f));
    unsigned short o3 = f2bf(fmaxf(acc.w + bb.w, 0.f));
    *(ushort4*)&out[(size_t)wid * 256 + col] = make_ushort4(o0, o1, o2, o3);
}

// ---------------- pooling + MLP ----------------
__global__ __launch_bounds__(256) void pool_kernel(const unsigned short* __restrict__ hatt, float* __restrict__ pooled) {
    int col = threadIdx.x;
    int r0 = blockIdx.x * 256;
    int r1 = r0 + 256 < NNODES ? r0 + 256 : NNODES;
    float s = 0.f;
    for (int r = r0; r < r1; ++r) s += bf2f(hatt[(size_t)r * 256 + col]);
    atomicAdd(&pooled[col], s);
}

__global__ __launch_bounds__(256) void mlp_kernel(const float* __restrict__ pooled,
                                                  const float* __restrict__ Wc1, const float* __restrict__ bc1,
                                                  const float* __restrict__ Wc2, const float* __restrict__ bc2,
                                                  const float* __restrict__ Wc3, const float* __restrict__ bc3,
                                                  float* __restrict__ out) {
    __shared__ float p[256], z1[128], z2[64];
    int t = threadIdx.x;
    p[t] = pooled[t] * (1.0f / NNODES);
    __syncthreads();
    if (t < 128) {
        float s = bc1[t];
        for (int k = 0; k < 256; ++k) s += p[k] * Wc1[k * 128 + t];
        z1[t] = fmaxf(s, 0.f);
    }
    __syncthreads();
    if (t < 64) {
        float s = bc2[t];
        for (int k = 0; k < 128; ++k) s += z1[k] * Wc2[k * 64 + t];
        z2[t] = fmaxf(s, 0.f);
    }
    __syncthreads();
    if (t < 8) {
        float s = bc3[t];
        for (int k = 0; k < 64; ++k) s += z2[k] * Wc3[k * 8 + t];
        out[t] = s;
    }
}

extern "C" void kernel_launch(void* const* d_in, const int* in_sizes, int n_in,
                              void* d_out, int out_size, void* d_ws, size_t ws_size,
                              hipStream_t stream) {
    const float* x   = (const float*)d_in[0];
    const int*   ei  = (const int*)d_in[1];
    const float* W1  = (const float*)d_in[2];  const float* b1  = (const float*)d_in[3];
    const float* W2  = (const float*)d_in[4];  const float* b2  = (const float*)d_in[5];
    const float* W3  = (const float*)d_in[6];  const float* b3  = (const float*)d_in[7];
    const float* Wg  = (const float*)d_in[8];
    const float* asr = (const float*)d_in[9];  const float* ads = (const float*)d_in[10];
    const float* bg  = (const float*)d_in[11];
    const float* Wc1 = (const float*)d_in[12]; const float* bc1 = (const float*)d_in[13];
    const float* Wc2 = (const float*)d_in[14]; const float* bc2 = (const float*)d_in[15];
    const float* Wc3 = (const float*)d_in[16]; const float* bc3 = (const float*)d_in[17];
    float* out = (float*)d_out;

    char* w = (char*)d_ws;
    float* deg    = (float*)w; w += (size_t)NNODES * 4;
    float* dinv   = (float*)w; w += (size_t)NNODES * 4;
    int*   rowp   = (int*)w;   w += 200016;                      // (NNODES+1)*4 padded
    int*   cursor = (int*)w;   w += (size_t)NNODES * 4;
    int*   bsum   = (int*)w;   w += 256 * 4;
    int*   bofs   = (int*)w;   w += 256 * 4;
    int*   csr_src= (int*)w;   w += (size_t)EN * 4;
    float* csr_w  = (float*)w; w += (size_t)EN * 4;
    float* als    = (float*)w; w += (size_t)NNODES * 4 * 4;
    float* ald    = (float*)w; w += (size_t)NNODES * 4 * 4;
    float* pooled = (float*)w; w += 256 * 4;
    unsigned short* W1th = (unsigned short*)w; w += 128 * 256 * 2;
    unsigned short* W1tl = (unsigned short*)w; w += 128 * 256 * 2;
    unsigned short* W2th = (unsigned short*)w; w += 256 * 256 * 2;
    unsigned short* W2tl = (unsigned short*)w; w += 256 * 256 * 2;
    unsigned short* W3th = (unsigned short*)w; w += 256 * 128 * 2;
    unsigned short* W3tl = (unsigned short*)w; w += 256 * 128 * 2;
    unsigned short* Wgth = (unsigned short*)w; w += 128 * 256 * 2;
    unsigned short* Wgtl = (unsigned short*)w; w += 128 * 256 * 2;
    unsigned short* U1 = (unsigned short*)w; w += (size_t)NNODES * 256 * 2;
    unsigned short* U2 = (unsigned short*)w; w += (size_t)NNODES * 256 * 2;
    unsigned short* U3 = (unsigned short*)w; w += (size_t)NNODES * 256 * 2;
    unsigned short* U4 = (unsigned short*)w; w += (size_t)NNODES * 256 * 2;

    // degree / norm / CSR
    hipMemsetAsync(deg, 0, (size_t)NNODES * 4, stream);
    hipMemsetAsync(cursor, 0, (size_t)NNODES * 4, stream);
    deg_kernel<<<(NEDGES + 255) / 256, 256, 0, stream>>>(ei, deg);
    dinv_kernel<<<(NNODES + 255) / 256, 256, 0, stream>>>(deg, dinv);
    scan_part1<<<SCAN_B, 256, 0, stream>>>(deg, rowp, bsum);
    scan_part2<<<1, 256, 0, stream>>>(bsum, bofs, rowp);
    scan_part3<<<SCAN_B, 256, 0, stream>>>(rowp, bofs);
    scatter_kernel<<<(EN + 255) / 256, 256, 0, stream>>>(ei, rowp, cursor, dinv, csr_src, csr_w);

    // weight transpose + split; x -> bf16
    wsplit_kernel<<<(128 * 256 + 255) / 256, 256, 0, stream>>>(W1, W1th, W1tl, 128, 256);
    wsplit_kernel<<<(256 * 256 + 255) / 256, 256, 0, stream>>>(W2, W2th, W2tl, 256, 256);
    wsplit_kernel<<<(256 * 128 + 255) / 256, 256, 0, stream>>>(W3, W3th, W3tl, 256, 128);
    wsplit_kernel<<<(128 * 256 + 255) / 256, 256, 0, stream>>>(Wg, Wgth, Wgtl, 128, 256);
    tobf16_kernel<<<(NNODES * 128 / 8 + 255) / 256, 256, 0, stream>>>(x, U1, NNODES * 128 / 8);

    dim3 gA((NNODES + 127) / 128, 2);   // Nc = 256
    dim3 gB((NNODES + 127) / 128, 1);   // Nc = 128
    int aggBlocks = (NNODES * 64 + 255) / 256;

    // GCN 1 (reordered): aggX = agg(xbf) [N,128] -> U2; h1 = relu(aggX@W1 + b1) -> U3
    gcn_agg_bf<128, 0><<<aggBlocks, 256, 0, stream>>>(U1, rowp, csr_src, csr_w, nullptr, nullptr, U2);
    gemm_bf<1><<<gA, 256, 0, stream>>>(U2, W1th, W1tl, b1, U3, NNODES, 128, 256);

    // GCN 2: t2 = h1@W2 -> U1; h2 = relu(agg(t2) + b2) + h1 -> U2
    gemm_bf<0><<<gA, 256, 0, stream>>>(U3, W2th, W2tl, nullptr, U1, NNODES, 256, 256);
    gcn_agg_bf<256, 2><<<aggBlocks, 256, 0, stream>>>(U1, rowp, csr_src, csr_w, b2, U3, U2);

    // GCN 3: t3 = h2@W3 -> U4 [N,128]; h3 = relu(agg(t3) + b3) -> U1 [N,128]
    gemm_bf<0><<<gB, 256, 0, stream>>>(U2, W3th, W3tl, nullptr, U4, NNODES, 256, 128);
    gcn_agg_bf<128, 1><<<aggBlocks, 256, 0, stream>>>(U4, rowp, csr_src, csr_w, b3, nullptr, U1);

    // GAT: hg = h3@Wg -> U2 [N,256]; logits; fused softmax-aggregate -> U3
    gemm_bf<0><<<gA, 256, 0, stream>>>(U1, Wgth, Wgtl, nullptr, U2, NNODES, 128, 256);
    att_logits<<<(NNODES * 4 + 255) / 256, 256, 0, stream>>>(U2, asr, ads, als, ald);
    gat_csr<<<aggBlocks, 256, 0, stream>>>(U2, rowp, csr_src, als, ald, bg, U3);

    // mean pool + MLP
    hipMemsetAsync(pooled, 0, 256 * 4, stream);
    pool_kernel<<<(NNODES + 255) / 256, 256, 0, stream>>>(U3, pooled);
    mlp_kernel<<<1, 256, 0, stream>>>(pooled, Wc1, bc1, Wc2, bc2, Wc3, bc3, out);
}

// Round 6
// 574.380 us; speedup vs baseline: 18.0724x; 1.2473x over previous
//
#include <hip/hip_runtime.h>
#include <hip/hip_bf16.h>

#define NNODES 50000
#define NEDGES 800000
#define EN 850000   // edges + self loops
#define SCAN_B 196  // ceil(NNODES/256)

typedef __attribute__((ext_vector_type(8))) short bf16x8;
typedef __attribute__((ext_vector_type(4))) float f32x4;

__device__ __forceinline__ float bf2f(unsigned short u) {
    return __uint_as_float(((unsigned)u) << 16);
}
__device__ __forceinline__ float bflo(unsigned u) { return __uint_as_float(u << 16); }
__device__ __forceinline__ float bfhi(unsigned u) { return __uint_as_float(u & 0xffff0000u); }
__device__ __forceinline__ unsigned short f2bf(float x) {   // RNE
    unsigned u = __float_as_uint(x);
    u += 0x7fffu + ((u >> 16) & 1u);
    return (unsigned short)(u >> 16);
}
__device__ __forceinline__ unsigned pack2bf(float a, float b) {
    return (unsigned)f2bf(a) | ((unsigned)f2bf(b) << 16);
}

// ---------------- degree / norm ----------------
__global__ __launch_bounds__(256) void deg_kernel(const int* __restrict__ ei, float* __restrict__ deg) {
    int e = blockIdx.x * blockDim.x + threadIdx.x;
    if (e < NEDGES) atomicAdd(&deg[ei[NEDGES + e]], 1.0f);
}

__global__ __launch_bounds__(256) void dinv_kernel(const float* __restrict__ deg, float* __restrict__ dinv) {
    int i = blockIdx.x * blockDim.x + threadIdx.x;
    if (i < NNODES) dinv[i] = rsqrtf(deg[i] + 1.0f);   // +1 = self loop
}

// ---------------- hierarchical exclusive scan of (deg[i]+1) ----------------
__global__ __launch_bounds__(256) void scan_part1(const float* __restrict__ deg, int* __restrict__ row,
                                                  int* __restrict__ bsum) {
    __shared__ int sdata[256];
    int t = threadIdx.x;
    int idx = blockIdx.x * 256 + t;
    int v = idx < NNODES ? (int)deg[idx] + 1 : 0;
    sdata[t] = v;
    __syncthreads();
    for (int off = 1; off < 256; off <<= 1) {
        int tmp = t >= off ? sdata[t - off] : 0;
        __syncthreads();
        sdata[t] += tmp;
        __syncthreads();
    }
    if (idx < NNODES) row[idx] = sdata[t] - v;
    if (t == 255) bsum[blockIdx.x] = sdata[255];
}

__global__ __launch_bounds__(256) void scan_part2(int* __restrict__ bsum, int* __restrict__ bofs,
                                                  int* __restrict__ row) {
    __shared__ int sdata[256];
    int t = threadIdx.x;
    int v = t < SCAN_B ? bsum[t] : 0;
    sdata[t] = v;
    __syncthreads();
    for (int off = 1; off < 256; off <<= 1) {
        int tmp = t >= off ? sdata[t - off] : 0;
        __syncthreads();
        sdata[t] += tmp;
        __syncthreads();
    }
    if (t < SCAN_B) bofs[t] = sdata[t] - v;
    if (t == 0) row[NNODES] = EN;
}

__global__ __launch_bounds__(256) void scan_part3(int* __restrict__ row, const int* __restrict__ bofs) {
    int idx = blockIdx.x * 256 + threadIdx.x;
    if (idx < NNODES) row[idx] += bofs[blockIdx.x];
}

// csr entry: {src, weight-bits} interleaved -> one 8B random write / one 8B gather read
__global__ __launch_bounds__(256) void scatter_kernel(const int* __restrict__ ei, const int* __restrict__ row,
                                                      int* __restrict__ cursor, const float* __restrict__ dinv,
                                                      uint2* __restrict__ csr) {
    int e = blockIdx.x * blockDim.x + threadIdx.x;
    if (e >= EN) return;
    int s, d;
    if (e < NEDGES) { s = ei[e]; d = ei[NEDGES + e]; } else { s = e - NEDGES; d = s; }
    int pos = row[d] + atomicAdd(&cursor[d], 1);
    csr[pos] = make_uint2((unsigned)s, __float_as_uint(dinv[s] * dinv[d]));
}

// ---------------- fp32 -> bf16 conversion (8 elems/thread) ----------------
__global__ __launch_bounds__(256) void tobf16_kernel(const float* __restrict__ in, unsigned short* __restrict__ out,
                                                     int total8) {
    int i = blockIdx.x * 256 + threadIdx.x;
    if (i >= total8) return;
    float4 a = *(const float4*)&in[(size_t)i * 8];
    float4 b = *(const float4*)&in[(size_t)i * 8 + 4];
    uint4 o;
    o.x = pack2bf(a.x, a.y); o.y = pack2bf(a.z, a.w);
    o.z = pack2bf(b.x, b.y); o.w = pack2bf(b.z, b.w);
    *(uint4*)&out[(size_t)i * 8] = o;
}

// ---------------- W [K][N] fp32 -> Wt_hi/Wt_lo [N][K] bf16 (transposed, split) ----------------
__device__ __forceinline__ void split_bf(float x, unsigned short& h, unsigned short& l) {
    unsigned u = __float_as_uint(x);
    h = (unsigned short)(u >> 16);
    float r = x - __uint_as_float(u & 0xffff0000u);
    l = (unsigned short)(__float_as_uint(r) >> 16);
}

__global__ __launch_bounds__(256) void wsplit_kernel(const float* __restrict__ W, unsigned short* __restrict__ Wh,
                                                     unsigned short* __restrict__ Wl, int K, int N) {
    int idx = blockIdx.x * 256 + threadIdx.x;
    if (idx >= K * N) return;
    int n = idx / K, k = idx % K;
    unsigned short h, l;
    split_bf(W[(size_t)k * N + n], h, l);
    Wh[idx] = h; Wl[idx] = l;
}

// ---------------- bf16-input MFMA GEMM: C[M,Nc] = A[M,K] @ W[K,Nc] ----------------
template<int MODE>
__global__ __launch_bounds__(256) void gemm_bf(const unsigned short* __restrict__ A,
                                               const unsigned short* __restrict__ Wth,
                                               const unsigned short* __restrict__ Wtl,
                                               const float* __restrict__ bias,
                                               unsigned short* __restrict__ C, int M, int K, int Nc) {
    __shared__ unsigned short As[128][40];
    __shared__ unsigned short Bh[128][40], Bl[128][40];
    int t = threadIdx.x;
    int row0 = blockIdx.x * 128, col0 = blockIdx.y * 128;
    int lane = t & 63, w = t >> 6;
    int mb = (w >> 1) * 64, nb = (w & 1) * 64;
    int lr = lane & 15, kg = (lane >> 4) * 8;

    f32x4 acc[4][4];
#pragma unroll
    for (int i = 0; i < 4; ++i)
#pragma unroll
        for (int j = 0; j < 4; ++j) acc[i][j] = (f32x4){0.f, 0.f, 0.f, 0.f};

    for (int k0 = 0; k0 < K; k0 += 32) {
#pragma unroll
        for (int it = 0; it < 2; ++it) {
            int q = it * 256 + t;
            int row = q >> 2, seg = (q & 3) * 8;
            int grow = row0 + row;
            uint4 v = make_uint4(0, 0, 0, 0);
            if (grow < M) v = *(const uint4*)&A[(size_t)grow * K + k0 + seg];
            *(uint4*)&As[row][seg] = v;
        }
#pragma unroll
        for (int it = 0; it < 2; ++it) {
            int o = it * 256 + t;
            int n = o >> 2, ko = (o & 3) * 8;
            size_t g = (size_t)(col0 + n) * K + k0 + ko;
            *(uint4*)&Bh[n][ko] = *(const uint4*)&Wth[g];
            *(uint4*)&Bl[n][ko] = *(const uint4*)&Wtl[g];
        }
        __syncthreads();

        bf16x8 a[4], bh[4], bl[4];
#pragma unroll
        for (int mf = 0; mf < 4; ++mf) a[mf] = *(const bf16x8*)&As[mb + mf * 16 + lr][kg];
#pragma unroll
        for (int nf = 0; nf < 4; ++nf) {
            bh[nf] = *(const bf16x8*)&Bh[nb + nf * 16 + lr][kg];
            bl[nf] = *(const bf16x8*)&Bl[nb + nf * 16 + lr][kg];
        }
#pragma unroll
        for (int mf = 0; mf < 4; ++mf)
#pragma unroll
            for (int nf = 0; nf < 4; ++nf) {
                acc[mf][nf] = __builtin_amdgcn_mfma_f32_16x16x32_bf16(a[mf], bh[nf], acc[mf][nf], 0, 0, 0);
                acc[mf][nf] = __builtin_amdgcn_mfma_f32_16x16x32_bf16(a[mf], bl[nf], acc[mf][nf], 0, 0, 0);
            }
        __syncthreads();
    }

#pragma unroll
    for (int nf = 0; nf < 4; ++nf) {
        int col = col0 + nb + nf * 16 + lr;
        float bv = (MODE == 1) ? bias[col] : 0.f;
#pragma unroll
        for (int mf = 0; mf < 4; ++mf) {
#pragma unroll
            for (int r = 0; r < 4; ++r) {
                int row = row0 + mb + mf * 16 + (lane >> 4) * 4 + r;
                if (row < M) {
                    float v = acc[mf][nf][r];
                    if (MODE == 1) v = fmaxf(v + bv, 0.f);
                    C[(size_t)row * Nc + col] = f2bf(v);
                }
            }
        }
    }
}

// ---------------- GCN gather aggregation (bf16, multi-edge per iter, 16B/lane) ----------------
// MODE 0: raw sum; MODE 1: relu(sum + b); MODE 2: relu(sum + b) + res(bf16)
template<int NC, int MODE>
__global__ __launch_bounds__(256) void gcn_agg_bf(const unsigned short* __restrict__ h, const int* __restrict__ row,
                                                  const uint2* __restrict__ csr,
                                                  const float* __restrict__ b, const unsigned short* __restrict__ res,
                                                  unsigned short* __restrict__ out) {
    int wid = (int)((blockIdx.x * blockDim.x + threadIdx.x) >> 6);
    if (wid >= NNODES) return;
    int lane = threadIdx.x & 63;
    constexpr int LPE = NC / 8;      // lanes per edge: 32 (NC=256) or 16 (NC=128)
    constexpr int EPI = 64 / LPE;    // edges per iter: 2 or 4
    int sub = lane / LPE, li = lane % LPE;
    int col = li * 8;
    float acc[8];
#pragma unroll
    for (int i = 0; i < 8; ++i) acc[i] = 0.f;
    int j0 = row[wid], j1 = row[wid + 1];
    for (int j = j0 + sub; j < j1; j += EPI) {
        uint2 sw = csr[j];
        float wg = __uint_as_float(sw.y);
        uint4 v = *(const uint4*)&h[(size_t)sw.x * NC + col];
        acc[0] += bflo(v.x) * wg; acc[1] += bfhi(v.x) * wg;
        acc[2] += bflo(v.y) * wg; acc[3] += bfhi(v.y) * wg;
        acc[4] += bflo(v.z) * wg; acc[5] += bfhi(v.z) * wg;
        acc[6] += bflo(v.w) * wg; acc[7] += bfhi(v.w) * wg;
    }
#pragma unroll
    for (int i = 0; i < 8; ++i) {
        acc[i] += __shfl_xor(acc[i], 32);
        if constexpr (EPI == 4) acc[i] += __shfl_xor(acc[i], 16);
    }
    if (lane < LPE) {
        if constexpr (MODE >= 1) {
#pragma unroll
            for (int i = 0; i < 8; ++i) acc[i] = fmaxf(acc[i] + b[col + i], 0.f);
        }
        if constexpr (MODE == 2) {
            uint4 rv = *(const uint4*)&res[(size_t)wid * NC + col];
            acc[0] += bflo(rv.x); acc[1] += bfhi(rv.x);
            acc[2] += bflo(rv.y); acc[3] += bfhi(rv.y);
            acc[4] += bflo(rv.z); acc[5] += bfhi(rv.z);
            acc[6] += bflo(rv.w); acc[7] += bfhi(rv.w);
        }
        uint4 o;
        o.x = pack2bf(acc[0], acc[1]); o.y = pack2bf(acc[2], acc[3]);
        o.z = pack2bf(acc[4], acc[5]); o.w = pack2bf(acc[6], acc[7]);
        *(uint4*)&out[(size_t)wid * NC + col] = o;
    }
}

// ---------------- GAT ----------------
__global__ __launch_bounds__(256) void att_logits(const unsigned short* __restrict__ hg,
                                                  const float* __restrict__ a_src, const float* __restrict__ a_dst,
                                                  float* __restrict__ als, float* __restrict__ ald) {
    int gid = blockIdx.x * blockDim.x + threadIdx.x;
    if (gid >= NNODES * 4) return;
    int n = gid >> 2, h = gid & 3;
    const unsigned short* hr = hg + (size_t)n * 256 + h * 64;
    const float* as_ = a_src + h * 64;
    const float* ad_ = a_dst + h * 64;
    float s1 = 0.f, s2 = 0.f;
#pragma unroll
    for (int f = 0; f < 64; f += 8) {
        uint4 v = *(const uint4*)&hr[f];
        float x0 = bflo(v.x), x1 = bfhi(v.x), x2 = bflo(v.y), x3 = bfhi(v.y);
        float x4 = bflo(v.z), x5 = bfhi(v.z), x6 = bflo(v.w), x7 = bfhi(v.w);
        s1 += x0 * as_[f] + x1 * as_[f + 1] + x2 * as_[f + 2] + x3 * as_[f + 3]
            + x4 * as_[f + 4] + x5 * as_[f + 5] + x6 * as_[f + 6] + x7 * as_[f + 7];
        s2 += x0 * ad_[f] + x1 * ad_[f + 1] + x2 * ad_[f + 2] + x3 * ad_[f + 3]
            + x4 * ad_[f + 4] + x5 * ad_[f + 5] + x6 * ad_[f + 6] + x7 * ad_[f + 7];
    }
    als[gid] = s1; ald[gid] = s2;
}

__device__ __forceinline__ float lrelu(float x) { return x < 0.f ? 0.2f * x : x; }

__global__ __launch_bounds__(256) void gat_csr(const unsigned short* __restrict__ hg, const int* __restrict__ row,
                                               const uint2* __restrict__ csr, const float* __restrict__ als,
                                               const float* __restrict__ ald, const float* __restrict__ bg,
                                               unsigned short* __restrict__ out) {
    int wid = (int)((blockIdx.x * blockDim.x + threadIdx.x) >> 6);
    if (wid >= NNODES) return;
    int lane = threadIdx.x & 63;
    int j0 = row[wid], j1 = row[wid + 1];
    float4 ad = *(const float4*)&ald[wid * 4];

    // pass 1: per-head max (lane-strided; deg<=64 typically => 1 iter)
    float m0 = -1e30f, m1 = -1e30f, m2 = -1e30f, m3 = -1e30f;
    for (int j = j0 + lane; j < j1; j += 64) {
        int s = (int)csr[j].x;
        float4 as4 = *(const float4*)&als[s * 4];
        m0 = fmaxf(m0, lrelu(as4.x + ad.x));
        m1 = fmaxf(m1, lrelu(as4.y + ad.y));
        m2 = fmaxf(m2, lrelu(as4.z + ad.z));
        m3 = fmaxf(m3, lrelu(as4.w + ad.w));
    }
#pragma unroll
    for (int off = 32; off >= 1; off >>= 1) {
        m0 = fmaxf(m0, __shfl_xor(m0, off));
        m1 = fmaxf(m1, __shfl_xor(m1, off));
        m2 = fmaxf(m2, __shfl_xor(m2, off));
        m3 = fmaxf(m3, __shfl_xor(m3, off));
    }
    // pass 2: per-head denominator
    float d0 = 0.f, d1 = 0.f, d2 = 0.f, d3 = 0.f;
    for (int j = j0 + lane; j < j1; j += 64) {
        int s = (int)csr[j].x;
        float4 as4 = *(const float4*)&als[s * 4];
        d0 += __expf(lrelu(as4.x + ad.x) - m0);
        d1 += __expf(lrelu(as4.y + ad.y) - m1);
        d2 += __expf(lrelu(as4.z + ad.z) - m2);
        d3 += __expf(lrelu(as4.w + ad.w) - m3);
    }
#pragma unroll
    for (int off = 32; off >= 1; off >>= 1) {
        d0 += __shfl_xor(d0, off);
        d1 += __shfl_xor(d1, off);
        d2 += __shfl_xor(d2, off);
        d3 += __shfl_xor(d3, off);
    }
    // pass 3: weighted gather, 2 edges/iter, 16B/lane
    int sub = lane >> 5, li = lane & 31;
    int h = li >> 3;                 // head for this lane's 8-col slice
    float mh   = h == 0 ? m0 : h == 1 ? m1 : h == 2 ? m2 : m3;
    float invh = 1.f / (h == 0 ? d0 : h == 1 ? d1 : h == 2 ? d2 : d3);
    float adh  = h == 0 ? ad.x : h == 1 ? ad.y : h == 2 ? ad.z : ad.w;
    int col = li * 8;
    float acc[8];
#pragma unroll
    for (int i = 0; i < 8; ++i) acc[i] = 0.f;
    for (int j = j0 + sub; j < j1; j += 2) {
        int s = (int)csr[j].x;
        float e = lrelu(als[s * 4 + h] + adh);
        float alpha = __expf(e - mh) * invh;
        uint4 v = *(const uint4*)&hg[(size_t)s * 256 + col];
        acc[0] += bflo(v.x) * alpha; acc[1] += bfhi(v.x) * alpha;
        acc[2] += bflo(v.y) * alpha; acc[3] += bfhi(v.y) * alpha;
        acc[4] += bflo(v.z) * alpha; acc[5] += bfhi(v.z) * alpha;
        acc[6] += bflo(v.w) * alpha; acc[7] += bfhi(v.w) * alpha;
    }
#pragma unroll
    for (int i = 0; i < 8; ++i) acc[i] += __shfl_xor(acc[i], 32);
    if (lane < 32) {
        uint4 o;
        o.x = pack2bf(fmaxf(acc[0] + bg[col], 0.f),     fmaxf(acc[1] + bg[col + 1], 0.f));
        o.y = pack2bf(fmaxf(acc[2] + bg[col + 2], 0.f), fmaxf(acc[3] + bg[col + 3], 0.f));
        o.z = pack2bf(fmaxf(acc[4] + bg[col + 4], 0.f), fmaxf(acc[5] + bg[col + 5], 0.f));
        o.w = pack2bf(fmaxf(acc[6] + bg[col + 6], 0.f), fmaxf(acc[7] + bg[col + 7], 0.f));
        *(uint4*)&out[(size_t)wid * 256 + col] = o;
    }
}

// ---------------- pooling + MLP ----------------
__global__ __launch_bounds__(256) void pool_kernel(const unsigned short* __restrict__ hatt, float* __restrict__ pooled) {
    int col = threadIdx.x;
    int r0 = blockIdx.x * 256;
    int r1 = r0 + 256 < NNODES ? r0 + 256 : NNODES;
    float s = 0.f;
    for (int r = r0; r < r1; ++r) s += bf2f(hatt[(size_t)r * 256 + col]);
    atomicAdd(&pooled[col], s);
}

__global__ __launch_bounds__(256) void mlp_kernel(const float* __restrict__ pooled,
                                                  const float* __restrict__ Wc1, const float* __restrict__ bc1,
                                                  const float* __restrict__ Wc2, const float* __restrict__ bc2,
                                                  const float* __restrict__ Wc3, const float* __restrict__ bc3,
                                                  float* __restrict__ out) {
    __shared__ float p[256], z1[128], z2[64];
    int t = threadIdx.x;
    p[t] = pooled[t] * (1.0f / NNODES);
    __syncthreads();
    if (t < 128) {
        float s = bc1[t];
        for (int k = 0; k < 256; ++k) s += p[k] * Wc1[k * 128 + t];
        z1[t] = fmaxf(s, 0.f);
    }
    __syncthreads();
    if (t < 64) {
        float s = bc2[t];
        for (int k = 0; k < 128; ++k) s += z1[k] * Wc2[k * 64 + t];
        z2[t] = fmaxf(s, 0.f);
    }
    __syncthreads();
    if (t < 8) {
        float s = bc3[t];
        for (int k = 0; k < 64; ++k) s += z2[k] * Wc3[k * 8 + t];
        out[t] = s;
    }
}

extern "C" void kernel_launch(void* const* d_in, const int* in_sizes, int n_in,
                              void* d_out, int out_size, void* d_ws, size_t ws_size,
                              hipStream_t stream) {
    const float* x   = (const float*)d_in[0];
    const int*   ei  = (const int*)d_in[1];
    const float* W1  = (const float*)d_in[2];  const float* b1  = (const float*)d_in[3];
    const float* W2  = (const float*)d_in[4];  const float* b2  = (const float*)d_in[5];
    const float* W3  = (const float*)d_in[6];  const float* b3  = (const float*)d_in[7];
    const float* Wg  = (const float*)d_in[8];
    const float* asr = (const float*)d_in[9];  const float* ads = (const float*)d_in[10];
    const float* bg  = (const float*)d_in[11];
    const float* Wc1 = (const float*)d_in[12]; const float* bc1 = (const float*)d_in[13];
    const float* Wc2 = (const float*)d_in[14]; const float* bc2 = (const float*)d_in[15];
    const float* Wc3 = (const float*)d_in[16]; const float* bc3 = (const float*)d_in[17];
    float* out = (float*)d_out;

    char* w = (char*)d_ws;
    float* deg    = (float*)w; w += (size_t)NNODES * 4;
    float* dinv   = (float*)w; w += (size_t)NNODES * 4;
    int*   rowp   = (int*)w;   w += 200016;                      // (NNODES+1)*4 padded
    int*   cursor = (int*)w;   w += (size_t)NNODES * 4;
    int*   bsum   = (int*)w;   w += 256 * 4;
    int*   bofs   = (int*)w;   w += 256 * 4;
    uint2* csr    = (uint2*)w; w += (size_t)EN * 8;
    float* als    = (float*)w; w += (size_t)NNODES * 4 * 4;
    float* ald    = (float*)w; w += (size_t)NNODES * 4 * 4;
    float* pooled = (float*)w; w += 256 * 4;
    unsigned short* W1th = (unsigned short*)w; w += 128 * 256 * 2;
    unsigned short* W1tl = (unsigned short*)w; w += 128 * 256 * 2;
    unsigned short* W2th = (unsigned short*)w; w += 256 * 256 * 2;
    unsigned short* W2tl = (unsigned short*)w; w += 256 * 256 * 2;
    unsigned short* W3th = (unsigned short*)w; w += 256 * 128 * 2;
    unsigned short* W3tl = (unsigned short*)w; w += 256 * 128 * 2;
    unsigned short* Wgth = (unsigned short*)w; w += 128 * 256 * 2;
    unsigned short* Wgtl = (unsigned short*)w; w += 128 * 256 * 2;
    unsigned short* U1 = (unsigned short*)w; w += (size_t)NNODES * 256 * 2;
    unsigned short* U2 = (unsigned short*)w; w += (size_t)NNODES * 256 * 2;
    unsigned short* U3 = (unsigned short*)w; w += (size_t)NNODES * 256 * 2;
    unsigned short* U4 = (unsigned short*)w; w += (size_t)NNODES * 256 * 2;

    // degree / norm / CSR
    hipMemsetAsync(deg, 0, (size_t)NNODES * 4, stream);
    hipMemsetAsync(cursor, 0, (size_t)NNODES * 4, stream);
    deg_kernel<<<(NEDGES + 255) / 256, 256, 0, stream>>>(ei, deg);
    dinv_kernel<<<(NNODES + 255) / 256, 256, 0, stream>>>(deg, dinv);
    scan_part1<<<SCAN_B, 256, 0, stream>>>(deg, rowp, bsum);
    scan_part2<<<1, 256, 0, stream>>>(bsum, bofs, rowp);
    scan_part3<<<SCAN_B, 256, 0, stream>>>(rowp, bofs);
    scatter_kernel<<<(EN + 255) / 256, 256, 0, stream>>>(ei, rowp, cursor, dinv, csr);

    // weight transpose + split; x -> bf16
    wsplit_kernel<<<(128 * 256 + 255) / 256, 256, 0, stream>>>(W1, W1th, W1tl, 128, 256);
    wsplit_kernel<<<(256 * 256 + 255) / 256, 256, 0, stream>>>(W2, W2th, W2tl, 256, 256);
    wsplit_kernel<<<(256 * 128 + 255) / 256, 256, 0, stream>>>(W3, W3th, W3tl, 256, 128);
    wsplit_kernel<<<(128 * 256 + 255) / 256, 256, 0, stream>>>(Wg, Wgth, Wgtl, 128, 256);
    tobf16_kernel<<<(NNODES * 128 / 8 + 255) / 256, 256, 0, stream>>>(x, U1, NNODES * 128 / 8);

    dim3 gA((NNODES + 127) / 128, 2);   // Nc = 256
    dim3 gB((NNODES + 127) / 128, 1);   // Nc = 128
    int aggBlocks = (NNODES * 64 + 255) / 256;

    // GCN 1 (reordered): aggX = agg(xbf) [N,128] -> U2; h1 = relu(aggX@W1 + b1) -> U3
    gcn_agg_bf<128, 0><<<aggBlocks, 256, 0, stream>>>(U1, rowp, csr, nullptr, nullptr, U2);
    gemm_bf<1><<<gA, 256, 0, stream>>>(U2, W1th, W1tl, b1, U3, NNODES, 128, 256);

    // GCN 2: t2 = h1@W2 -> U1; h2 = relu(agg(t2) + b2) + h1 -> U2
    gemm_bf<0><<<gA, 256, 0, stream>>>(U3, W2th, W2tl, nullptr, U1, NNODES, 256, 256);
    gcn_agg_bf<256, 2><<<aggBlocks, 256, 0, stream>>>(U1, rowp, csr, b2, U3, U2);

    // GCN 3: t3 = h2@W3 -> U4 [N,128]; h3 = relu(agg(t3) + b3) -> U1 [N,128]
    gemm_bf<0><<<gB, 256, 0, stream>>>(U2, W3th, W3tl, nullptr, U4, NNODES, 256, 128);
    gcn_agg_bf<128, 1><<<aggBlocks, 256, 0, stream>>>(U4, rowp, csr, b3, nullptr, U1);

    // GAT: hg = h3@Wg -> U2 [N,256]; logits; fused softmax-aggregate -> U3
    gemm_bf<0><<<gA, 256, 0, stream>>>(U1, Wgth, Wgtl, nullptr, U2, NNODES, 128, 256);
    att_logits<<<(NNODES * 4 + 255) / 256, 256, 0, stream>>>(U2, asr, ads, als, ald);
    gat_csr<<<aggBlocks, 256, 0, stream>>>(U2, rowp, csr, als, ald, bg, U3);

    // mean pool + MLP
    hipMemsetAsync(pooled, 0, 256 * 4, stream);
    pool_kernel<<<(NNODES + 255) / 256, 256, 0, stream>>>(U3, pooled);
    mlp_kernel<<<1, 256, 0, stream>>>(pooled, Wc1, bc1, Wc2, bc2, Wc3, bc3, out);
}

// Round 7
// 550.000 us; speedup vs baseline: 18.8735x; 1.0443x over previous
//
#include <hip/hip_runtime.h>
#include <hip/hip_bf16.h>

#define NNODES 50000
#define NEDGES 800000
#define EN 850000   // edges + self loops
#define SCAN_B 196  // ceil(NNODES/256)

typedef __attribute__((ext_vector_type(8))) short bf16x8;
typedef __attribute__((ext_vector_type(4))) float f32x4;

__device__ __forceinline__ float bf2f(unsigned short u) {
    return __uint_as_float(((unsigned)u) << 16);
}
__device__ __forceinline__ float bflo(unsigned u) { return __uint_as_float(u << 16); }
__device__ __forceinline__ float bfhi(unsigned u) { return __uint_as_float(u & 0xffff0000u); }
__device__ __forceinline__ unsigned short f2bf(float x) {   // RNE
    unsigned u = __float_as_uint(x);
    u += 0x7fffu + ((u >> 16) & 1u);
    return (unsigned short)(u >> 16);
}
__device__ __forceinline__ unsigned pack2bf(float a, float b) {
    return (unsigned)f2bf(a) | ((unsigned)f2bf(b) << 16);
}
__device__ __forceinline__ void acc8(float* acc, uint4 v, float wg) {
    acc[0] += bflo(v.x) * wg; acc[1] += bfhi(v.x) * wg;
    acc[2] += bflo(v.y) * wg; acc[3] += bfhi(v.y) * wg;
    acc[4] += bflo(v.z) * wg; acc[5] += bfhi(v.z) * wg;
    acc[6] += bflo(v.w) * wg; acc[7] += bfhi(v.w) * wg;
}

// ---------------- degree ----------------
__global__ __launch_bounds__(256) void deg_kernel(const int* __restrict__ ei, float* __restrict__ deg) {
    int e = blockIdx.x * blockDim.x + threadIdx.x;
    if (e < NEDGES) atomicAdd(&deg[ei[NEDGES + e]], 1.0f);
}

// ---------------- hierarchical exclusive scan of (deg[i]+1), fused dinv ----------------
__global__ __launch_bounds__(256) void scan_part1(const float* __restrict__ deg, int* __restrict__ row,
                                                  int* __restrict__ bsum, float* __restrict__ dinv) {
    __shared__ int sdata[256];
    int t = threadIdx.x;
    int idx = blockIdx.x * 256 + t;
    float dg = idx < NNODES ? deg[idx] : 0.f;
    if (idx < NNODES) dinv[idx] = rsqrtf(dg + 1.0f);   // +1 = self loop
    int v = idx < NNODES ? (int)dg + 1 : 0;
    sdata[t] = v;
    __syncthreads();
    for (int off = 1; off < 256; off <<= 1) {
        int tmp = t >= off ? sdata[t - off] : 0;
        __syncthreads();
        sdata[t] += tmp;
        __syncthreads();
    }
    if (idx < NNODES) row[idx] = sdata[t] - v;
    if (t == 255) bsum[blockIdx.x] = sdata[255];
}

__global__ __launch_bounds__(256) void scan_part2(int* __restrict__ bsum, int* __restrict__ bofs,
                                                  int* __restrict__ row) {
    __shared__ int sdata[256];
    int t = threadIdx.x;
    int v = t < SCAN_B ? bsum[t] : 0;
    sdata[t] = v;
    __syncthreads();
    for (int off = 1; off < 256; off <<= 1) {
        int tmp = t >= off ? sdata[t - off] : 0;
        __syncthreads();
        sdata[t] += tmp;
        __syncthreads();
    }
    if (t < SCAN_B) bofs[t] = sdata[t] - v;
    if (t == 0) row[NNODES] = EN;
}

__global__ __launch_bounds__(256) void scan_part3(int* __restrict__ row, const int* __restrict__ bofs) {
    int idx = blockIdx.x * 256 + threadIdx.x;
    if (idx < NNODES) row[idx] += bofs[blockIdx.x];
}

// csr entry: {src, weight-bits} interleaved
__global__ __launch_bounds__(256) void scatter_kernel(const int* __restrict__ ei, const int* __restrict__ row,
                                                      int* __restrict__ cursor, const float* __restrict__ dinv,
                                                      uint2* __restrict__ csr) {
    int e = blockIdx.x * blockDim.x + threadIdx.x;
    if (e >= EN) return;
    int s, d;
    if (e < NEDGES) { s = ei[e]; d = ei[NEDGES + e]; } else { s = e - NEDGES; d = s; }
    int pos = row[d] + atomicAdd(&cursor[d], 1);
    csr[pos] = make_uint2((unsigned)s, __float_as_uint(dinv[s] * dinv[d]));
}

// ---------------- fp32 -> bf16 conversion (8 elems/thread) ----------------
__global__ __launch_bounds__(256) void tobf16_kernel(const float* __restrict__ in, unsigned short* __restrict__ out,
                                                     int total8) {
    int i = blockIdx.x * 256 + threadIdx.x;
    if (i >= total8) return;
    float4 a = *(const float4*)&in[(size_t)i * 8];
    float4 b = *(const float4*)&in[(size_t)i * 8 + 4];
    uint4 o;
    o.x = pack2bf(a.x, a.y); o.y = pack2bf(a.z, a.w);
    o.z = pack2bf(b.x, b.y); o.w = pack2bf(b.z, b.w);
    *(uint4*)&out[(size_t)i * 8] = o;
}

// ---------------- all four W [K][N] fp32 -> Wt_hi/Wt_lo [N][K] bf16 in one kernel ----------------
__device__ __forceinline__ void split_bf(float x, unsigned short& h, unsigned short& l) {
    unsigned u = __float_as_uint(x);
    h = (unsigned short)(u >> 16);
    float r = x - __uint_as_float(u & 0xffff0000u);
    l = (unsigned short)(__float_as_uint(r) >> 16);
}

__device__ __forceinline__ void do_split(const float* W, unsigned short* Wh, unsigned short* Wl,
                                         int i, int K, int N) {
    int n = i / K, k = i - n * K;
    unsigned short h, l;
    split_bf(W[(size_t)k * N + n], h, l);
    Wh[i] = h; Wl[i] = l;
}

__global__ __launch_bounds__(256) void wsplit4_kernel(const float* __restrict__ W1, const float* __restrict__ W2,
                                                      const float* __restrict__ W3, const float* __restrict__ Wg,
                                                      unsigned short* __restrict__ W1th, unsigned short* __restrict__ W1tl,
                                                      unsigned short* __restrict__ W2th, unsigned short* __restrict__ W2tl,
                                                      unsigned short* __restrict__ W3th, unsigned short* __restrict__ W3tl,
                                                      unsigned short* __restrict__ Wgth, unsigned short* __restrict__ Wgtl) {
    int idx = blockIdx.x * 256 + threadIdx.x;
    if (idx < 32768)        do_split(W1, W1th, W1tl, idx, 128, 256);
    else if (idx < 98304)   do_split(W2, W2th, W2tl, idx - 32768, 256, 256);
    else if (idx < 131072)  do_split(W3, W3th, W3tl, idx - 98304, 256, 128);
    else if (idx < 163840)  do_split(Wg, Wgth, Wgtl, idx - 131072, 128, 256);
}

// ---------------- bf16-input MFMA GEMM: C[M,Nc] = A[M,K] @ W[K,Nc] ----------------
template<int MODE>
__global__ __launch_bounds__(256) void gemm_bf(const unsigned short* __restrict__ A,
                                               const unsigned short* __restrict__ Wth,
                                               const unsigned short* __restrict__ Wtl,
                                               const float* __restrict__ bias,
                                               unsigned short* __restrict__ C, int M, int K, int Nc) {
    __shared__ unsigned short As[128][40];
    __shared__ unsigned short Bh[128][40], Bl[128][40];
    int t = threadIdx.x;
    int row0 = blockIdx.x * 128, col0 = blockIdx.y * 128;
    int lane = t & 63, w = t >> 6;
    int mb = (w >> 1) * 64, nb = (w & 1) * 64;
    int lr = lane & 15, kg = (lane >> 4) * 8;

    f32x4 acc[4][4];
#pragma unroll
    for (int i = 0; i < 4; ++i)
#pragma unroll
        for (int j = 0; j < 4; ++j) acc[i][j] = (f32x4){0.f, 0.f, 0.f, 0.f};

    for (int k0 = 0; k0 < K; k0 += 32) {
#pragma unroll
        for (int it = 0; it < 2; ++it) {
            int q = it * 256 + t;
            int row = q >> 2, seg = (q & 3) * 8;
            int grow = row0 + row;
            uint4 v = make_uint4(0, 0, 0, 0);
            if (grow < M) v = *(const uint4*)&A[(size_t)grow * K + k0 + seg];
            *(uint4*)&As[row][seg] = v;
        }
#pragma unroll
        for (int it = 0; it < 2; ++it) {
            int o = it * 256 + t;
            int n = o >> 2, ko = (o & 3) * 8;
            size_t g = (size_t)(col0 + n) * K + k0 + ko;
            *(uint4*)&Bh[n][ko] = *(const uint4*)&Wth[g];
            *(uint4*)&Bl[n][ko] = *(const uint4*)&Wtl[g];
        }
        __syncthreads();

        bf16x8 a[4], bh[4], bl[4];
#pragma unroll
        for (int mf = 0; mf < 4; ++mf) a[mf] = *(const bf16x8*)&As[mb + mf * 16 + lr][kg];
#pragma unroll
        for (int nf = 0; nf < 4; ++nf) {
            bh[nf] = *(const bf16x8*)&Bh[nb + nf * 16 + lr][kg];
            bl[nf] = *(const bf16x8*)&Bl[nb + nf * 16 + lr][kg];
        }
#pragma unroll
        for (int mf = 0; mf < 4; ++mf)
#pragma unroll
            for (int nf = 0; nf < 4; ++nf) {
                acc[mf][nf] = __builtin_amdgcn_mfma_f32_16x16x32_bf16(a[mf], bh[nf], acc[mf][nf], 0, 0, 0);
                acc[mf][nf] = __builtin_amdgcn_mfma_f32_16x16x32_bf16(a[mf], bl[nf], acc[mf][nf], 0, 0, 0);
            }
        __syncthreads();
    }

#pragma unroll
    for (int nf = 0; nf < 4; ++nf) {
        int col = col0 + nb + nf * 16 + lr;
        float bv = (MODE == 1) ? bias[col] : 0.f;
#pragma unroll
        for (int mf = 0; mf < 4; ++mf) {
#pragma unroll
            for (int r = 0; r < 4; ++r) {
                int row = row0 + mb + mf * 16 + (lane >> 4) * 4 + r;
                if (row < M) {
                    float v = acc[mf][nf][r];
                    if (MODE == 1) v = fmaxf(v + bv, 0.f);
                    C[(size_t)row * Nc + col] = f2bf(v);
                }
            }
        }
    }
}

// ---------------- GCN gather aggregation (bf16, multi-edge, unroll-2) ----------------
// MODE 0: raw sum; MODE 1: relu(sum + b); MODE 2: relu(sum + b) + res(bf16)
template<int NC, int MODE>
__global__ __launch_bounds__(256) void gcn_agg_bf(const unsigned short* __restrict__ h, const int* __restrict__ row,
                                                  const uint2* __restrict__ csr,
                                                  const float* __restrict__ b, const unsigned short* __restrict__ res,
                                                  unsigned short* __restrict__ out) {
    int wid = (int)((blockIdx.x * blockDim.x + threadIdx.x) >> 6);
    if (wid >= NNODES) return;
    int lane = threadIdx.x & 63;
    constexpr int LPE = NC / 8;      // lanes per edge: 32 (NC=256) or 16 (NC=128)
    constexpr int EPI = 64 / LPE;    // edges per iter: 2 or 4
    int sub = lane / LPE, li = lane % LPE;
    int col = li * 8;
    float acc[8];
#pragma unroll
    for (int i = 0; i < 8; ++i) acc[i] = 0.f;
    int j0 = row[wid], j1 = row[wid + 1];
    int j = j0 + sub;
    for (; j + EPI < j1; j += 2 * EPI) {
        uint2 c0 = csr[j], c1 = csr[j + EPI];
        uint4 v0 = *(const uint4*)&h[(size_t)c0.x * NC + col];
        uint4 v1 = *(const uint4*)&h[(size_t)c1.x * NC + col];
        acc8(acc, v0, __uint_as_float(c0.y));
        acc8(acc, v1, __uint_as_float(c1.y));
    }
    if (j < j1) {
        uint2 c0 = csr[j];
        uint4 v0 = *(const uint4*)&h[(size_t)c0.x * NC + col];
        acc8(acc, v0, __uint_as_float(c0.y));
    }
#pragma unroll
    for (int i = 0; i < 8; ++i) {
        acc[i] += __shfl_xor(acc[i], 32);
        if constexpr (EPI == 4) acc[i] += __shfl_xor(acc[i], 16);
    }
    if (lane < LPE) {
        if constexpr (MODE >= 1) {
#pragma unroll
            for (int i = 0; i < 8; ++i) acc[i] = fmaxf(acc[i] + b[col + i], 0.f);
        }
        if constexpr (MODE == 2) {
            uint4 rv = *(const uint4*)&res[(size_t)wid * NC + col];
            acc8(acc, rv, 1.0f);
        }
        uint4 o;
        o.x = pack2bf(acc[0], acc[1]); o.y = pack2bf(acc[2], acc[3]);
        o.z = pack2bf(acc[4], acc[5]); o.w = pack2bf(acc[6], acc[7]);
        *(uint4*)&out[(size_t)wid * NC + col] = o;
    }
}

// ---------------- GAT ----------------
__global__ __launch_bounds__(256) void att_logits(const unsigned short* __restrict__ hg,
                                                  const float* __restrict__ a_src, const float* __restrict__ a_dst,
                                                  float* __restrict__ als, float* __restrict__ ald) {
    int gid = blockIdx.x * blockDim.x + threadIdx.x;
    if (gid >= NNODES * 4) return;
    int n = gid >> 2, h = gid & 3;
    const unsigned short* hr = hg + (size_t)n * 256 + h * 64;
    const float* as_ = a_src + h * 64;
    const float* ad_ = a_dst + h * 64;
    float s1 = 0.f, s2 = 0.f;
#pragma unroll
    for (int f = 0; f < 64; f += 8) {
        uint4 v = *(const uint4*)&hr[f];
        float x0 = bflo(v.x), x1 = bfhi(v.x), x2 = bflo(v.y), x3 = bfhi(v.y);
        float x4 = bflo(v.z), x5 = bfhi(v.z), x6 = bflo(v.w), x7 = bfhi(v.w);
        s1 += x0 * as_[f] + x1 * as_[f + 1] + x2 * as_[f + 2] + x3 * as_[f + 3]
            + x4 * as_[f + 4] + x5 * as_[f + 5] + x6 * as_[f + 6] + x7 * as_[f + 7];
        s2 += x0 * ad_[f] + x1 * ad_[f + 1] + x2 * ad_[f + 2] + x3 * ad_[f + 3]
            + x4 * ad_[f + 4] + x5 * ad_[f + 5] + x6 * ad_[f + 6] + x7 * ad_[f + 7];
    }
    als[gid] = s1; ald[gid] = s2;
}

__device__ __forceinline__ float lrelu(float x) { return x < 0.f ? 0.2f * x : x; }

__global__ __launch_bounds__(256) void gat_csr(const unsigned short* __restrict__ hg, const int* __restrict__ row,
                                               const uint2* __restrict__ csr, const float* __restrict__ als,
                                               const float* __restrict__ ald, const float* __restrict__ bg,
                                               unsigned short* __restrict__ out) {
    int wid = (int)((blockIdx.x * blockDim.x + threadIdx.x) >> 6);
    if (wid >= NNODES) return;
    int lane = threadIdx.x & 63;
    int j0 = row[wid], j1 = row[wid + 1];
    int deg = j1 - j0;
    float4 ad = *(const float4*)&ald[wid * 4];

    float m0 = -1e30f, m1 = -1e30f, m2 = -1e30f, m3 = -1e30f;
    float d0 = 0.f, d1 = 0.f, d2 = 0.f, d3 = 0.f;
    if (deg <= 64) {
        // fast path: one edge per lane, logits cached in regs for both reductions
        float e0 = -1e30f, e1 = -1e30f, e2 = -1e30f, e3 = -1e30f;
        if (lane < deg) {
            int s = (int)csr[j0 + lane].x;
            float4 as4 = *(const float4*)&als[s * 4];
            e0 = lrelu(as4.x + ad.x); e1 = lrelu(as4.y + ad.y);
            e2 = lrelu(as4.z + ad.z); e3 = lrelu(as4.w + ad.w);
        }
        m0 = e0; m1 = e1; m2 = e2; m3 = e3;
#pragma unroll
        for (int off = 32; off >= 1; off >>= 1) {
            m0 = fmaxf(m0, __shfl_xor(m0, off));
            m1 = fmaxf(m1, __shfl_xor(m1, off));
            m2 = fmaxf(m2, __shfl_xor(m2, off));
            m3 = fmaxf(m3, __shfl_xor(m3, off));
        }
        d0 = __expf(e0 - m0); d1 = __expf(e1 - m1);   // invalid lanes underflow to 0
        d2 = __expf(e2 - m2); d3 = __expf(e3 - m3);
#pragma unroll
        for (int off = 32; off >= 1; off >>= 1) {
            d0 += __shfl_xor(d0, off);
            d1 += __shfl_xor(d1, off);
            d2 += __shfl_xor(d2, off);
            d3 += __shfl_xor(d3, off);
        }
    } else {
        for (int j = j0 + lane; j < j1; j += 64) {
            int s = (int)csr[j].x;
            float4 as4 = *(const float4*)&als[s * 4];
            m0 = fmaxf(m0, lrelu(as4.x + ad.x));
            m1 = fmaxf(m1, lrelu(as4.y + ad.y));
            m2 = fmaxf(m2, lrelu(as4.z + ad.z));
            m3 = fmaxf(m3, lrelu(as4.w + ad.w));
        }
#pragma unroll
        for (int off = 32; off >= 1; off >>= 1) {
            m0 = fmaxf(m0, __shfl_xor(m0, off));
            m1 = fmaxf(m1, __shfl_xor(m1, off));
            m2 = fmaxf(m2, __shfl_xor(m2, off));
            m3 = fmaxf(m3, __shfl_xor(m3, off));
        }
        for (int j = j0 + lane; j < j1; j += 64) {
            int s = (int)csr[j].x;
            float4 as4 = *(const float4*)&als[s * 4];
            d0 += __expf(lrelu(as4.x + ad.x) - m0);
            d1 += __expf(lrelu(as4.y + ad.y) - m1);
            d2 += __expf(lrelu(as4.z + ad.z) - m2);
            d3 += __expf(lrelu(as4.w + ad.w) - m3);
        }
#pragma unroll
        for (int off = 32; off >= 1; off >>= 1) {
            d0 += __shfl_xor(d0, off);
            d1 += __shfl_xor(d1, off);
            d2 += __shfl_xor(d2, off);
            d3 += __shfl_xor(d3, off);
        }
    }

    // pass 3: weighted gather, 2 edges/iter, 16B/lane, unroll-2
    int sub = lane >> 5, li = lane & 31;
    int h = li >> 3;                 // head for this lane's 8-col slice
    float mh   = h == 0 ? m0 : h == 1 ? m1 : h == 2 ? m2 : m3;
    float invh = 1.f / (h == 0 ? d0 : h == 1 ? d1 : h == 2 ? d2 : d3);
    float adh  = h == 0 ? ad.x : h == 1 ? ad.y : h == 2 ? ad.z : ad.w;
    int col = li * 8;
    float acc[8];
#pragma unroll
    for (int i = 0; i < 8; ++i) acc[i] = 0.f;
    int j = j0 + sub;
    for (; j + 2 < j1; j += 4) {
        uint2 c0 = csr[j], c1 = csr[j + 2];
        float a0 = __expf(lrelu(als[c0.x * 4 + h] + adh) - mh) * invh;
        float a1 = __expf(lrelu(als[c1.x * 4 + h] + adh) - mh) * invh;
        uint4 v0 = *(const uint4*)&hg[(size_t)c0.x * 256 + col];
        uint4 v1 = *(const uint4*)&hg[(size_t)c1.x * 256 + col];
        acc8(acc, v0, a0);
        acc8(acc, v1, a1);
    }
    if (j < j1) {
        uint2 c0 = csr[j];
        float a0 = __expf(lrelu(als[c0.x * 4 + h] + adh) - mh) * invh;
        uint4 v0 = *(const uint4*)&hg[(size_t)c0.x * 256 + col];
        acc8(acc, v0, a0);
    }
#pragma unroll
    for (int i = 0; i < 8; ++i) acc[i] += __shfl_xor(acc[i], 32);
    if (lane < 32) {
        uint4 o;
        o.x = pack2bf(fmaxf(acc[0] + bg[col], 0.f),     fmaxf(acc[1] + bg[col + 1], 0.f));
        o.y = pack2bf(fmaxf(acc[2] + bg[col + 2], 0.f), fmaxf(acc[3] + bg[col + 3], 0.f));
        o.z = pack2bf(fmaxf(acc[4] + bg[col + 4], 0.f), fmaxf(acc[5] + bg[col + 5], 0.f));
        o.w = pack2bf(fmaxf(acc[6] + bg[col + 6], 0.f), fmaxf(acc[7] + bg[col + 7], 0.f));
        *(uint4*)&out[(size_t)wid * 256 + col] = o;
    }
}

// ---------------- pooling + MLP ----------------
__global__ __launch_bounds__(256) void pool_kernel(const unsigned short* __restrict__ hatt, float* __restrict__ pooled) {
    int col = threadIdx.x;
    int r0 = blockIdx.x * 256;
    int r1 = r0 + 256 < NNODES ? r0 + 256 : NNODES;
    float s = 0.f;
    for (int r = r0; r < r1; ++r) s += bf2f(hatt[(size_t)r * 256 + col]);
    atomicAdd(&pooled[col], s);
}

__global__ __launch_bounds__(256) void mlp_kernel(const float* __restrict__ pooled,
                                                  const float* __restrict__ Wc1, const float* __restrict__ bc1,
                                                  const float* __restrict__ Wc2, const float* __restrict__ bc2,
                                                  const float* __restrict__ Wc3, const float* __restrict__ bc3,
                                                  float* __restrict__ out) {
    __shared__ float p[256], z1[128], z2[64];
    int t = threadIdx.x;
    p[t] = pooled[t] * (1.0f / NNODES);
    __syncthreads();
    if (t < 128) {
        float s = bc1[t];
        for (int k = 0; k < 256; ++k) s += p[k] * Wc1[k * 128 + t];
        z1[t] = fmaxf(s, 0.f);
    }
    __syncthreads();
    if (t < 64) {
        float s = bc2[t];
        for (int k = 0; k < 128; ++k) s += z1[k] * Wc2[k * 64 + t];
        z2[t] = fmaxf(s, 0.f);
    }
    __syncthreads();
    if (t < 8) {
        float s = bc3[t];
        for (int k = 0; k < 64; ++k) s += z2[k] * Wc3[k * 8 + t];
        out[t] = s;
    }
}

extern "C" void kernel_launch(void* const* d_in, const int* in_sizes, int n_in,
                              void* d_out, int out_size, void* d_ws, size_t ws_size,
                              hipStream_t stream) {
    const float* x   = (const float*)d_in[0];
    const int*   ei  = (const int*)d_in[1];
    const float* W1  = (const float*)d_in[2];  const float* b1  = (const float*)d_in[3];
    const float* W2  = (const float*)d_in[4];  const float* b2  = (const float*)d_in[5];
    const float* W3  = (const float*)d_in[6];  const float* b3  = (const float*)d_in[7];
    const float* Wg  = (const float*)d_in[8];
    const float* asr = (const float*)d_in[9];  const float* ads = (const float*)d_in[10];
    const float* bg  = (const float*)d_in[11];
    const float* Wc1 = (const float*)d_in[12]; const float* bc1 = (const float*)d_in[13];
    const float* Wc2 = (const float*)d_in[14]; const float* bc2 = (const float*)d_in[15];
    const float* Wc3 = (const float*)d_in[16]; const float* bc3 = (const float*)d_in[17];
    float* out = (float*)d_out;

    char* w = (char*)d_ws;
    float* deg    = (float*)w; w += (size_t)NNODES * 4;
    float* dinv   = (float*)w; w += (size_t)NNODES * 4;
    int*   rowp   = (int*)w;   w += 200016;                      // (NNODES+1)*4 padded
    int*   cursor = (int*)w;   w += (size_t)NNODES * 4;
    int*   bsum   = (int*)w;   w += 256 * 4;
    int*   bofs   = (int*)w;   w += 256 * 4;
    uint2* csr    = (uint2*)w; w += (size_t)EN * 8;
    float* als    = (float*)w; w += (size_t)NNODES * 4 * 4;
    float* ald    = (float*)w; w += (size_t)NNODES * 4 * 4;
    float* pooled = (float*)w; w += 256 * 4;
    unsigned short* W1th = (unsigned short*)w; w += 128 * 256 * 2;
    unsigned short* W1tl = (unsigned short*)w; w += 128 * 256 * 2;
    unsigned short* W2th = (unsigned short*)w; w += 256 * 256 * 2;
    unsigned short* W2tl = (unsigned short*)w; w += 256 * 256 * 2;
    unsigned short* W3th = (unsigned short*)w; w += 256 * 128 * 2;
    unsigned short* W3tl = (unsigned short*)w; w += 256 * 128 * 2;
    unsigned short* Wgth = (unsigned short*)w; w += 128 * 256 * 2;
    unsigned short* Wgtl = (unsigned short*)w; w += 128 * 256 * 2;
    unsigned short* U1 = (unsigned short*)w; w += (size_t)NNODES * 256 * 2;
    unsigned short* U2 = (unsigned short*)w; w += (size_t)NNODES * 256 * 2;
    unsigned short* U3 = (unsigned short*)w; w += (size_t)NNODES * 256 * 2;
    unsigned short* U4 = (unsigned short*)w; w += (size_t)NNODES * 256 * 2;

    // degree / norm / CSR
    hipMemsetAsync(deg, 0, (size_t)NNODES * 4, stream);
    hipMemsetAsync(cursor, 0, (size_t)NNODES * 4, stream);
    deg_kernel<<<(NEDGES + 255) / 256, 256, 0, stream>>>(ei, deg);
    scan_part1<<<SCAN_B, 256, 0, stream>>>(deg, rowp, bsum, dinv);
    scan_part2<<<1, 256, 0, stream>>>(bsum, bofs, rowp);
    scan_part3<<<SCAN_B, 256, 0, stream>>>(rowp, bofs);
    scatter_kernel<<<(EN + 255) / 256, 256, 0, stream>>>(ei, rowp, cursor, dinv, csr);

    // weight transpose + split (all 4 in one); x -> bf16
    wsplit4_kernel<<<640, 256, 0, stream>>>(W1, W2, W3, Wg, W1th, W1tl, W2th, W2tl, W3th, W3tl, Wgth, Wgtl);
    tobf16_kernel<<<(NNODES * 128 / 8 + 255) / 256, 256, 0, stream>>>(x, U1, NNODES * 128 / 8);

    dim3 gA((NNODES + 127) / 128, 2);   // Nc = 256
    dim3 gB((NNODES + 127) / 128, 1);   // Nc = 128
    int aggBlocks = (NNODES * 64 + 255) / 256;

    // GCN 1 (reordered): aggX = agg(xbf) [N,128] -> U2; h1 = relu(aggX@W1 + b1) -> U3
    gcn_agg_bf<128, 0><<<aggBlocks, 256, 0, stream>>>(U1, rowp, csr, nullptr, nullptr, U2);
    gemm_bf<1><<<gA, 256, 0, stream>>>(U2, W1th, W1tl, b1, U3, NNODES, 128, 256);

    // GCN 2: t2 = h1@W2 -> U1; h2 = relu(agg(t2) + b2) + h1 -> U2
    gemm_bf<0><<<gA, 256, 0, stream>>>(U3, W2th, W2tl, nullptr, U1, NNODES, 256, 256);
    gcn_agg_bf<256, 2><<<aggBlocks, 256, 0, stream>>>(U1, rowp, csr, b2, U3, U2);

    // GCN 3: t3 = h2@W3 -> U4 [N,128]; h3 = relu(agg(t3) + b3) -> U1 [N,128]
    gemm_bf<0><<<gB, 256, 0, stream>>>(U2, W3th, W3tl, nullptr, U4, NNODES, 256, 128);
    gcn_agg_bf<128, 1><<<aggBlocks, 256, 0, stream>>>(U4, rowp, csr, b3, nullptr, U1);

    // GAT: hg = h3@Wg -> U2 [N,256]; logits; fused softmax-aggregate -> U3
    gemm_bf<0><<<gA, 256, 0, stream>>>(U1, Wgth, Wgtl, nullptr, U2, NNODES, 128, 256);
    att_logits<<<(NNODES * 4 + 255) / 256, 256, 0, stream>>>(U2, asr, ads, als, ald);
    gat_csr<<<aggBlocks, 256, 0, stream>>>(U2, rowp, csr, als, ald, bg, U3);

    // mean pool + MLP
    hipMemsetAsync(pooled, 0, 256 * 4, stream);
    pool_kernel<<<(NNODES + 255) / 256, 256, 0, stream>>>(U3, pooled);
    mlp_kernel<<<1, 256, 0, stream>>>(pooled, Wc1, bc1, Wc2, bc2, Wc3, bc3, out);
}

// Round 8
// 538.285 us; speedup vs baseline: 19.2842x; 1.0218x over previous
//
#include <hip/hip_runtime.h>
#include <hip/hip_bf16.h>

#define NNODES 50000
#define NEDGES 800000
#define EN 850000   // edges + self loops
#define SCAN_B 196  // ceil(NNODES/256)

typedef __attribute__((ext_vector_type(8))) short bf16x8;
typedef __attribute__((ext_vector_type(4))) float f32x4;

__device__ __forceinline__ float bf2f(unsigned short u) {
    return __uint_as_float(((unsigned)u) << 16);
}
__device__ __forceinline__ float bflo(unsigned u) { return __uint_as_float(u << 16); }
__device__ __forceinline__ float bfhi(unsigned u) { return __uint_as_float(u & 0xffff0000u); }
__device__ __forceinline__ unsigned short f2bf(float x) {   // RNE
    unsigned u = __float_as_uint(x);
    u += 0x7fffu + ((u >> 16) & 1u);
    return (unsigned short)(u >> 16);
}
__device__ __forceinline__ unsigned pack2bf(float a, float b) {
    return (unsigned)f2bf(a) | ((unsigned)f2bf(b) << 16);
}
__device__ __forceinline__ void acc8(float* acc, uint4 v, float wg) {
    acc[0] += bflo(v.x) * wg; acc[1] += bfhi(v.x) * wg;
    acc[2] += bflo(v.y) * wg; acc[3] += bfhi(v.y) * wg;
    acc[4] += bflo(v.z) * wg; acc[5] += bfhi(v.z) * wg;
    acc[6] += bflo(v.w) * wg; acc[7] += bfhi(v.w) * wg;
}

// ---------------- split helpers ----------------
__device__ __forceinline__ void split_bf(float x, unsigned short& h, unsigned short& l) {
    unsigned u = __float_as_uint(x);
    h = (unsigned short)(u >> 16);
    float r = x - __uint_as_float(u & 0xffff0000u);
    l = (unsigned short)(__float_as_uint(r) >> 16);
}
__device__ __forceinline__ void do_split(const float* W, unsigned short* Wh, unsigned short* Wl,
                                         int i, int K, int N) {
    int n = i / K, k = i - n * K;
    unsigned short h, l;
    split_bf(W[(size_t)k * N + n], h, l);
    Wh[i] = h; Wl[i] = l;
}

// ---------------- fused prep: deg atomics + x->bf16 + weight transpose/split ----------------
// grid: 3125 blocks x 256 = 800000 threads
__global__ __launch_bounds__(256) void prep_kernel(const int* __restrict__ ei, float* __restrict__ deg,
                                                   const float* __restrict__ x, unsigned short* __restrict__ xbf,
                                                   const float* __restrict__ W1, const float* __restrict__ W2,
                                                   const float* __restrict__ W3, const float* __restrict__ Wg,
                                                   unsigned short* __restrict__ W1th, unsigned short* __restrict__ W1tl,
                                                   unsigned short* __restrict__ W2th, unsigned short* __restrict__ W2tl,
                                                   unsigned short* __restrict__ W3th, unsigned short* __restrict__ W3tl,
                                                   unsigned short* __restrict__ Wgth, unsigned short* __restrict__ Wgtl) {
    int idx = blockIdx.x * 256 + threadIdx.x;     // 0..799999
    atomicAdd(&deg[ei[NEDGES + idx]], 1.0f);      // idx < NEDGES always
    {   // x -> bf16, 8 elems/thread (800000 * 8 = 6.4M = NNODES*128)
        float4 a = *(const float4*)&x[(size_t)idx * 8];
        float4 b = *(const float4*)&x[(size_t)idx * 8 + 4];
        uint4 o;
        o.x = pack2bf(a.x, a.y); o.y = pack2bf(a.z, a.w);
        o.z = pack2bf(b.x, b.y); o.w = pack2bf(b.z, b.w);
        *(uint4*)&xbf[(size_t)idx * 8] = o;
    }
    if (idx < 32768)        do_split(W1, W1th, W1tl, idx, 128, 256);
    else if (idx < 98304)   do_split(W2, W2th, W2tl, idx - 32768, 256, 256);
    else if (idx < 131072)  do_split(W3, W3th, W3tl, idx - 98304, 256, 128);
    else if (idx < 163840)  do_split(Wg, Wgth, Wgtl, idx - 131072, 128, 256);
}

// ---------------- hierarchical exclusive scan of (deg[i]+1), fused dinv ----------------
__global__ __launch_bounds__(256) void scan_part1(const float* __restrict__ deg, int* __restrict__ row,
                                                  int* __restrict__ bsum, float* __restrict__ dinv) {
    __shared__ int sdata[256];
    int t = threadIdx.x;
    int idx = blockIdx.x * 256 + t;
    float dg = idx < NNODES ? deg[idx] : 0.f;
    if (idx < NNODES) dinv[idx] = rsqrtf(dg + 1.0f);   // +1 = self loop
    int v = idx < NNODES ? (int)dg + 1 : 0;
    sdata[t] = v;
    __syncthreads();
    for (int off = 1; off < 256; off <<= 1) {
        int tmp = t >= off ? sdata[t - off] : 0;
        __syncthreads();
        sdata[t] += tmp;
        __syncthreads();
    }
    if (idx < NNODES) row[idx] = sdata[t] - v;
    if (t == 255) bsum[blockIdx.x] = sdata[255];
}

__global__ __launch_bounds__(256) void scan_part2(int* __restrict__ bsum, int* __restrict__ bofs,
                                                  int* __restrict__ row) {
    __shared__ int sdata[256];
    int t = threadIdx.x;
    int v = t < SCAN_B ? bsum[t] : 0;
    sdata[t] = v;
    __syncthreads();
    for (int off = 1; off < 256; off <<= 1) {
        int tmp = t >= off ? sdata[t - off] : 0;
        __syncthreads();
        sdata[t] += tmp;
        __syncthreads();
    }
    if (t < SCAN_B) bofs[t] = sdata[t] - v;
    if (t == 0) row[NNODES] = EN;
}

__global__ __launch_bounds__(256) void scan_part3(int* __restrict__ row, const int* __restrict__ bofs) {
    int idx = blockIdx.x * 256 + threadIdx.x;
    if (idx < NNODES) row[idx] += bofs[blockIdx.x];
}

// csr entry: {src, weight-bits} interleaved
__global__ __launch_bounds__(256) void scatter_kernel(const int* __restrict__ ei, const int* __restrict__ row,
                                                      int* __restrict__ cursor, const float* __restrict__ dinv,
                                                      uint2* __restrict__ csr) {
    int e = blockIdx.x * blockDim.x + threadIdx.x;
    if (e >= EN) return;
    int s, d;
    if (e < NEDGES) { s = ei[e]; d = ei[NEDGES + e]; } else { s = e - NEDGES; d = s; }
    int pos = row[d] + atomicAdd(&cursor[d], 1);
    csr[pos] = make_uint2((unsigned)s, __float_as_uint(dinv[s] * dinv[d]));
}

// ---------------- bf16-input MFMA GEMM: C[M,Nc] = A[M,K] @ W[K,Nc] ----------------
template<int MODE>
__global__ __launch_bounds__(256) void gemm_bf(const unsigned short* __restrict__ A,
                                               const unsigned short* __restrict__ Wth,
                                               const unsigned short* __restrict__ Wtl,
                                               const float* __restrict__ bias,
                                               unsigned short* __restrict__ C, int M, int K, int Nc) {
    __shared__ unsigned short As[128][40];
    __shared__ unsigned short Bh[128][40], Bl[128][40];
    int t = threadIdx.x;
    int row0 = blockIdx.x * 128, col0 = blockIdx.y * 128;
    int lane = t & 63, w = t >> 6;
    int mb = (w >> 1) * 64, nb = (w & 1) * 64;
    int lr = lane & 15, kg = (lane >> 4) * 8;

    f32x4 acc[4][4];
#pragma unroll
    for (int i = 0; i < 4; ++i)
#pragma unroll
        for (int j = 0; j < 4; ++j) acc[i][j] = (f32x4){0.f, 0.f, 0.f, 0.f};

    for (int k0 = 0; k0 < K; k0 += 32) {
#pragma unroll
        for (int it = 0; it < 2; ++it) {
            int q = it * 256 + t;
            int row = q >> 2, seg = (q & 3) * 8;
            int grow = row0 + row;
            uint4 v = make_uint4(0, 0, 0, 0);
            if (grow < M) v = *(const uint4*)&A[(size_t)grow * K + k0 + seg];
            *(uint4*)&As[row][seg] = v;
        }
#pragma unroll
        for (int it = 0; it < 2; ++it) {
            int o = it * 256 + t;
            int n = o >> 2, ko = (o & 3) * 8;
            size_t g = (size_t)(col0 + n) * K + k0 + ko;
            *(uint4*)&Bh[n][ko] = *(const uint4*)&Wth[g];
            *(uint4*)&Bl[n][ko] = *(const uint4*)&Wtl[g];
        }
        __syncthreads();

        bf16x8 a[4], bh[4], bl[4];
#pragma unroll
        for (int mf = 0; mf < 4; ++mf) a[mf] = *(const bf16x8*)&As[mb + mf * 16 + lr][kg];
#pragma unroll
        for (int nf = 0; nf < 4; ++nf) {
            bh[nf] = *(const bf16x8*)&Bh[nb + nf * 16 + lr][kg];
            bl[nf] = *(const bf16x8*)&Bl[nb + nf * 16 + lr][kg];
        }
#pragma unroll
        for (int mf = 0; mf < 4; ++mf)
#pragma unroll
            for (int nf = 0; nf < 4; ++nf) {
                acc[mf][nf] = __builtin_amdgcn_mfma_f32_16x16x32_bf16(a[mf], bh[nf], acc[mf][nf], 0, 0, 0);
                acc[mf][nf] = __builtin_amdgcn_mfma_f32_16x16x32_bf16(a[mf], bl[nf], acc[mf][nf], 0, 0, 0);
            }
        __syncthreads();
    }

#pragma unroll
    for (int nf = 0; nf < 4; ++nf) {
        int col = col0 + nb + nf * 16 + lr;
        float bv = (MODE == 1) ? bias[col] : 0.f;
#pragma unroll
        for (int mf = 0; mf < 4; ++mf) {
#pragma unroll
            for (int r = 0; r < 4; ++r) {
                int row = row0 + mb + mf * 16 + (lane >> 4) * 4 + r;
                if (row < M) {
                    float v = acc[mf][nf][r];
                    if (MODE == 1) v = fmaxf(v + bv, 0.f);
                    C[(size_t)row * Nc + col] = f2bf(v);
                }
            }
        }
    }
}

// ---------------- GCN gather aggregation (bf16, multi-edge, unroll-4) ----------------
// MODE 0: raw sum; MODE 1: relu(sum + b); MODE 2: relu(sum + b) + res(bf16)
template<int NC, int MODE>
__global__ __launch_bounds__(256) void gcn_agg_bf(const unsigned short* __restrict__ h, const int* __restrict__ row,
                                                  const uint2* __restrict__ csr,
                                                  const float* __restrict__ b, const unsigned short* __restrict__ res,
                                                  unsigned short* __restrict__ out) {
    int wid = (int)((blockIdx.x * blockDim.x + threadIdx.x) >> 6);
    if (wid >= NNODES) return;
    int lane = threadIdx.x & 63;
    constexpr int LPE = NC / 8;      // lanes per edge: 32 (NC=256) or 16 (NC=128)
    constexpr int EPI = 64 / LPE;    // edges per iter: 2 or 4
    int sub = lane / LPE, li = lane % LPE;
    int col = li * 8;
    float acc[8];
#pragma unroll
    for (int i = 0; i < 8; ++i) acc[i] = 0.f;
    int j0 = row[wid], j1 = row[wid + 1];
    int j = j0 + sub;
    for (; j + 3 * EPI < j1; j += 4 * EPI) {
        uint2 c0 = csr[j], c1 = csr[j + EPI], c2 = csr[j + 2 * EPI], c3 = csr[j + 3 * EPI];
        uint4 v0 = *(const uint4*)&h[(size_t)c0.x * NC + col];
        uint4 v1 = *(const uint4*)&h[(size_t)c1.x * NC + col];
        uint4 v2 = *(const uint4*)&h[(size_t)c2.x * NC + col];
        uint4 v3 = *(const uint4*)&h[(size_t)c3.x * NC + col];
        acc8(acc, v0, __uint_as_float(c0.y));
        acc8(acc, v1, __uint_as_float(c1.y));
        acc8(acc, v2, __uint_as_float(c2.y));
        acc8(acc, v3, __uint_as_float(c3.y));
    }
    for (; j < j1; j += EPI) {
        uint2 c0 = csr[j];
        uint4 v0 = *(const uint4*)&h[(size_t)c0.x * NC + col];
        acc8(acc, v0, __uint_as_float(c0.y));
    }
#pragma unroll
    for (int i = 0; i < 8; ++i) {
        acc[i] += __shfl_xor(acc[i], 32);
        if constexpr (EPI == 4) acc[i] += __shfl_xor(acc[i], 16);
    }
    if (lane < LPE) {
        if constexpr (MODE >= 1) {
#pragma unroll
            for (int i = 0; i < 8; ++i) acc[i] = fmaxf(acc[i] + b[col + i], 0.f);
        }
        if constexpr (MODE == 2) {
            uint4 rv = *(const uint4*)&res[(size_t)wid * NC + col];
            acc8(acc, rv, 1.0f);
        }
        uint4 o;
        o.x = pack2bf(acc[0], acc[1]); o.y = pack2bf(acc[2], acc[3]);
        o.z = pack2bf(acc[4], acc[5]); o.w = pack2bf(acc[6], acc[7]);
        *(uint4*)&out[(size_t)wid * NC + col] = o;
    }
}

// ---------------- GAT ----------------
__global__ __launch_bounds__(256) void att_logits(const unsigned short* __restrict__ hg,
                                                  const float* __restrict__ a_src, const float* __restrict__ a_dst,
                                                  float* __restrict__ als, float* __restrict__ ald) {
    int gid = blockIdx.x * blockDim.x + threadIdx.x;
    if (gid >= NNODES * 4) return;
    int n = gid >> 2, h = gid & 3;
    const unsigned short* hr = hg + (size_t)n * 256 + h * 64;
    const float* as_ = a_src + h * 64;
    const float* ad_ = a_dst + h * 64;
    float s1 = 0.f, s2 = 0.f;
#pragma unroll
    for (int f = 0; f < 64; f += 8) {
        uint4 v = *(const uint4*)&hr[f];
        float x0 = bflo(v.x), x1 = bfhi(v.x), x2 = bflo(v.y), x3 = bfhi(v.y);
        float x4 = bflo(v.z), x5 = bfhi(v.z), x6 = bflo(v.w), x7 = bfhi(v.w);
        s1 += x0 * as_[f] + x1 * as_[f + 1] + x2 * as_[f + 2] + x3 * as_[f + 3]
            + x4 * as_[f + 4] + x5 * as_[f + 5] + x6 * as_[f + 6] + x7 * as_[f + 7];
        s2 += x0 * ad_[f] + x1 * ad_[f + 1] + x2 * ad_[f + 2] + x3 * ad_[f + 3]
            + x4 * ad_[f + 4] + x5 * ad_[f + 5] + x6 * ad_[f + 6] + x7 * ad_[f + 7];
    }
    als[gid] = s1; ald[gid] = s2;
}

__device__ __forceinline__ float lrelu(float x) { return x < 0.f ? 0.2f * x : x; }

__global__ __launch_bounds__(256) void gat_csr(const unsigned short* __restrict__ hg, const int* __restrict__ row,
                                               const uint2* __restrict__ csr, const float* __restrict__ als,
                                               const float* __restrict__ ald, const float* __restrict__ bg,
                                               unsigned short* __restrict__ out) {
    __shared__ float alds[4][64][4];   // [wave][edge slot][head] normalized alpha
    int wid = (int)((blockIdx.x * blockDim.x + threadIdx.x) >> 6);
    if (wid >= NNODES) return;
    int wv = threadIdx.x >> 6;
    int lane = threadIdx.x & 63;
    int j0 = row[wid], j1 = row[wid + 1];
    int deg = j1 - j0;
    float4 ad = *(const float4*)&ald[wid * 4];
    int sub = lane >> 5, li = lane & 31;
    int h = li >> 3;                 // head for this lane's 8-col slice
    int col = li * 8;
    float acc[8];
#pragma unroll
    for (int i = 0; i < 8; ++i) acc[i] = 0.f;

    if (deg <= 64) {
        // ---- one edge per lane; logits in regs; normalized alphas -> LDS ----
        int sreg = 0;
        float e0 = -1e30f, e1 = -1e30f, e2 = -1e30f, e3 = -1e30f;
        if (lane < deg) {
            sreg = (int)csr[j0 + lane].x;
            float4 as4 = *(const float4*)&als[sreg * 4];
            e0 = lrelu(as4.x + ad.x); e1 = lrelu(as4.y + ad.y);
            e2 = lrelu(as4.z + ad.z); e3 = lrelu(as4.w + ad.w);
        }
        float m0 = e0, m1 = e1, m2 = e2, m3 = e3;
#pragma unroll
        for (int off = 32; off >= 1; off >>= 1) {
            m0 = fmaxf(m0, __shfl_xor(m0, off));
            m1 = fmaxf(m1, __shfl_xor(m1, off));
            m2 = fmaxf(m2, __shfl_xor(m2, off));
            m3 = fmaxf(m3, __shfl_xor(m3, off));
        }
        float x0 = __expf(e0 - m0), x1 = __expf(e1 - m1);
        float x2 = __expf(e2 - m2), x3 = __expf(e3 - m3);
        float d0 = x0, d1 = x1, d2 = x2, d3 = x3;
#pragma unroll
        for (int off = 32; off >= 1; off >>= 1) {
            d0 += __shfl_xor(d0, off);
            d1 += __shfl_xor(d1, off);
            d2 += __shfl_xor(d2, off);
            d3 += __shfl_xor(d3, off);
        }
        float i0 = 1.f / d0, i1 = 1.f / d1, i2 = 1.f / d2, i3 = 1.f / d3;
        *(float4*)&alds[wv][lane][0] = make_float4(x0 * i0, x1 * i1, x2 * i2, x3 * i3);
        // ---- pass 3: ds_read alpha + shfl src, unroll-4 ----
        int k = sub;
        for (; k + 6 < deg; k += 8) {
            int s0 = __shfl(sreg, k),     s1 = __shfl(sreg, k + 2);
            int s2 = __shfl(sreg, k + 4), s3 = __shfl(sreg, k + 6);
            float a0 = alds[wv][k][h],     a1 = alds[wv][k + 2][h];
            float a2 = alds[wv][k + 4][h], a3 = alds[wv][k + 6][h];
            uint4 v0 = *(const uint4*)&hg[(size_t)s0 * 256 + col];
            uint4 v1 = *(const uint4*)&hg[(size_t)s1 * 256 + col];
            uint4 v2 = *(const uint4*)&hg[(size_t)s2 * 256 + col];
            uint4 v3 = *(const uint4*)&hg[(size_t)s3 * 256 + col];
            acc8(acc, v0, a0); acc8(acc, v1, a1);
            acc8(acc, v2, a2); acc8(acc, v3, a3);
        }
        for (; k < deg; k += 2) {
            int s0 = __shfl(sreg, k);
            float a0 = alds[wv][k][h];
            uint4 v0 = *(const uint4*)&hg[(size_t)s0 * 256 + col];
            acc8(acc, v0, a0);
        }
    } else {
        // ---- rare slow path: strided reductions + recompute in gather ----
        float m0 = -1e30f, m1 = -1e30f, m2 = -1e30f, m3 = -1e30f;
        float d0 = 0.f, d1 = 0.f, d2 = 0.f, d3 = 0.f;
        for (int j = j0 + lane; j < j1; j += 64) {
            int s = (int)csr[j].x;
            float4 as4 = *(const float4*)&als[s * 4];
            m0 = fmaxf(m0, lrelu(as4.x + ad.x));
            m1 = fmaxf(m1, lrelu(as4.y + ad.y));
            m2 = fmaxf(m2, lrelu(as4.z + ad.z));
            m3 = fmaxf(m3, lrelu(as4.w + ad.w));
        }
#pragma unroll
        for (int off = 32; off >= 1; off >>= 1) {
            m0 = fmaxf(m0, __shfl_xor(m0, off));
            m1 = fmaxf(m1, __shfl_xor(m1, off));
            m2 = fmaxf(m2, __shfl_xor(m2, off));
            m3 = fmaxf(m3, __shfl_xor(m3, off));
        }
        for (int j = j0 + lane; j < j1; j += 64) {
            int s = (int)csr[j].x;
            float4 as4 = *(const float4*)&als[s * 4];
            d0 += __expf(lrelu(as4.x + ad.x) - m0);
            d1 += __expf(lrelu(as4.y + ad.y) - m1);
            d2 += __expf(lrelu(as4.z + ad.z) - m2);
            d3 += __expf(lrelu(as4.w + ad.w) - m3);
        }
#pragma unroll
        for (int off = 32; off >= 1; off >>= 1) {
            d0 += __shfl_xor(d0, off);
            d1 += __shfl_xor(d1, off);
            d2 += __shfl_xor(d2, off);
            d3 += __shfl_xor(d3, off);
        }
        float mh   = h == 0 ? m0 : h == 1 ? m1 : h == 2 ? m2 : m3;
        float invh = 1.f / (h == 0 ? d0 : h == 1 ? d1 : h == 2 ? d2 : d3);
        float adh  = h == 0 ? ad.x : h == 1 ? ad.y : h == 2 ? ad.z : ad.w;
        for (int j = j0 + sub; j < j1; j += 2) {
            uint2 c0 = csr[j];
            float a0 = __expf(lrelu(als[c0.x * 4 + h] + adh) - mh) * invh;
            uint4 v0 = *(const uint4*)&hg[(size_t)c0.x * 256 + col];
            acc8(acc, v0, a0);
        }
    }

#pragma unroll
    for (int i = 0; i < 8; ++i) acc[i] += __shfl_xor(acc[i], 32);
    if (lane < 32) {
        uint4 o;
        o.x = pack2bf(fmaxf(acc[0] + bg[col], 0.f),     fmaxf(acc[1] + bg[col + 1], 0.f));
        o.y = pack2bf(fmaxf(acc[2] + bg[col + 2], 0.f), fmaxf(acc[3] + bg[col + 3], 0.f));
        o.z = pack2bf(fmaxf(acc[4] + bg[col + 4], 0.f), fmaxf(acc[5] + bg[col + 5], 0.f));
        o.w = pack2bf(fmaxf(acc[6] + bg[col + 6], 0.f), fmaxf(acc[7] + bg[col + 7], 0.f));
        *(uint4*)&out[(size_t)wid * 256 + col] = o;
    }
}

// ---------------- pooling + MLP ----------------
__global__ __launch_bounds__(256) void pool_kernel(const unsigned short* __restrict__ hatt, float* __restrict__ pooled) {
    int col = threadIdx.x;
    int r0 = blockIdx.x * 256;
    int r1 = r0 + 256 < NNODES ? r0 + 256 : NNODES;
    float s = 0.f;
    for (int r = r0; r < r1; ++r) s += bf2f(hatt[(size_t)r * 256 + col]);
    atomicAdd(&pooled[col], s);
}

__global__ __launch_bounds__(256) void mlp_kernel(const float* __restrict__ pooled,
                                                  const float* __restrict__ Wc1, const float* __restrict__ bc1,
                                                  const float* __restrict__ Wc2, const float* __restrict__ bc2,
                                                  const float* __restrict__ Wc3, const float* __restrict__ bc3,
                                                  float* __restrict__ out) {
    __shared__ float p[256], z1[128], z2[64];
    int t = threadIdx.x;
    p[t] = pooled[t] * (1.0f / NNODES);
    __syncthreads();
    if (t < 128) {
        float s = bc1[t];
        for (int k = 0; k < 256; ++k) s += p[k] * Wc1[k * 128 + t];
        z1[t] = fmaxf(s, 0.f);
    }
    __syncthreads();
    if (t < 64) {
        float s = bc2[t];
        for (int k = 0; k < 128; ++k) s += z1[k] * Wc2[k * 64 + t];
        z2[t] = fmaxf(s, 0.f);
    }
    __syncthreads();
    if (t < 8) {
        float s = bc3[t];
        for (int k = 0; k < 64; ++k) s += z2[k] * Wc3[k * 8 + t];
        out[t] = s;
    }
}

extern "C" void kernel_launch(void* const* d_in, const int* in_sizes, int n_in,
                              void* d_out, int out_size, void* d_ws, size_t ws_size,
                              hipStream_t stream) {
    const float* x   = (const float*)d_in[0];
    const int*   ei  = (const int*)d_in[1];
    const float* W1  = (const float*)d_in[2];  const float* b1  = (const float*)d_in[3];
    const float* W2  = (const float*)d_in[4];  const float* b2  = (const float*)d_in[5];
    const float* W3  = (const float*)d_in[6];  const float* b3  = (const float*)d_in[7];
    const float* Wg  = (const float*)d_in[8];
    const float* asr = (const float*)d_in[9];  const float* ads = (const float*)d_in[10];
    const float* bg  = (const float*)d_in[11];
    const float* Wc1 = (const float*)d_in[12]; const float* bc1 = (const float*)d_in[13];
    const float* Wc2 = (const float*)d_in[14]; const float* bc2 = (const float*)d_in[15];
    const float* Wc3 = (const float*)d_in[16]; const float* bc3 = (const float*)d_in[17];
    float* out = (float*)d_out;

    char* w = (char*)d_ws;
    float* deg    = (float*)w; w += (size_t)NNODES * 4;
    float* dinv   = (float*)w; w += (size_t)NNODES * 4;
    int*   rowp   = (int*)w;   w += 200016;                      // (NNODES+1)*4 padded
    int*   cursor = (int*)w;   w += (size_t)NNODES * 4;
    int*   bsum   = (int*)w;   w += 256 * 4;
    int*   bofs   = (int*)w;   w += 256 * 4;
    uint2* csr    = (uint2*)w; w += (size_t)EN * 8;
    float* als    = (float*)w; w += (size_t)NNODES * 4 * 4;
    float* ald    = (float*)w; w += (size_t)NNODES * 4 * 4;
    float* pooled = (float*)w; w += 256 * 4;
    unsigned short* W1th = (unsigned short*)w; w += 128 * 256 * 2;
    unsigned short* W1tl = (unsigned short*)w; w += 128 * 256 * 2;
    unsigned short* W2th = (unsigned short*)w; w += 256 * 256 * 2;
    unsigned short* W2tl = (unsigned short*)w; w += 256 * 256 * 2;
    unsigned short* W3th = (unsigned short*)w; w += 256 * 128 * 2;
    unsigned short* W3tl = (unsigned short*)w; w += 256 * 128 * 2;
    unsigned short* Wgth = (unsigned short*)w; w += 128 * 256 * 2;
    unsigned short* Wgtl = (unsigned short*)w; w += 128 * 256 * 2;
    unsigned short* U1 = (unsigned short*)w; w += (size_t)NNODES * 256 * 2;
    unsigned short* U2 = (unsigned short*)w; w += (size_t)NNODES * 256 * 2;
    unsigned short* U3 = (unsigned short*)w; w += (size_t)NNODES * 256 * 2;
    unsigned short* U4 = (unsigned short*)w; w += (size_t)NNODES * 256 * 2;

    // prep: deg atomics + x->bf16 + weight split (one kernel), then scan + CSR
    hipMemsetAsync(deg, 0, (size_t)NNODES * 4, stream);
    hipMemsetAsync(cursor, 0, (size_t)NNODES * 4, stream);
    prep_kernel<<<3125, 256, 0, stream>>>(ei, deg, x, U1, W1, W2, W3, Wg,
                                          W1th, W1tl, W2th, W2tl, W3th, W3tl, Wgth, Wgtl);
    scan_part1<<<SCAN_B, 256, 0, stream>>>(deg, rowp, bsum, dinv);
    scan_part2<<<1, 256, 0, stream>>>(bsum, bofs, rowp);
    scan_part3<<<SCAN_B, 256, 0, stream>>>(rowp, bofs);
    scatter_kernel<<<(EN + 255) / 256, 256, 0, stream>>>(ei, rowp, cursor, dinv, csr);

    dim3 gA((NNODES + 127) / 128, 2);   // Nc = 256
    dim3 gB((NNODES + 127) / 128, 1);   // Nc = 128
    int aggBlocks = (NNODES * 64 + 255) / 256;

    // GCN 1 (reordered): aggX = agg(xbf) [N,128] -> U2; h1 = relu(aggX@W1 + b1) -> U3
    gcn_agg_bf<128, 0><<<aggBlocks, 256, 0, stream>>>(U1, rowp, csr, nullptr, nullptr, U2);
    gemm_bf<1><<<gA, 256, 0, stream>>>(U2, W1th, W1tl, b1, U3, NNODES, 128, 256);

    // GCN 2: t2 = h1@W2 -> U1; h2 = relu(agg(t2) + b2) + h1 -> U2
    gemm_bf<0><<<gA, 256, 0, stream>>>(U3, W2th, W2tl, nullptr, U1, NNODES, 256, 256);
    gcn_agg_bf<256, 2><<<aggBlocks, 256, 0, stream>>>(U1, rowp, csr, b2, U3, U2);

    // GCN 3: t3 = h2@W3 -> U4 [N,128]; h3 = relu(agg(t3) + b3) -> U1 [N,128]
    gemm_bf<0><<<gB, 256, 0, stream>>>(U2, W3th, W3tl, nullptr, U4, NNODES, 256, 128);
    gcn_agg_bf<128, 1><<<aggBlocks, 256, 0, stream>>>(U4, rowp, csr, b3, nullptr, U1);

    // GAT: hg = h3@Wg -> U2 [N,256]; logits; fused softmax-aggregate -> U3
    gemm_bf<0><<<gA, 256, 0, stream>>>(U1, Wgth, Wgtl, nullptr, U2, NNODES, 128, 256);
    att_logits<<<(NNODES * 4 + 255) / 256, 256, 0, stream>>>(U2, asr, ads, als, ald);
    gat_csr<<<aggBlocks, 256, 0, stream>>>(U2, rowp, csr, als, ald, bg, U3);

    // mean pool + MLP
    hipMemsetAsync(pooled, 0, 256 * 4, stream);
    pool_kernel<<<(NNODES + 255) / 256, 256, 0, stream>>>(U3, pooled);
    mlp_kernel<<<1, 256, 0, stream>>>(pooled, Wc1, bc1, Wc2, bc2, Wc3, bc3, out);
}

// Round 9
// 533.173 us; speedup vs baseline: 19.4691x; 1.0096x over previous
//
#include <hip/hip_runtime.h>
#include <hip/hip_bf16.h>

#define NNODES 50000
#define NEDGES 800000
#define EN 850000   // edges + self loops
#define SCAN_B 196  // ceil(NNODES/256)

typedef __attribute__((ext_vector_type(8))) short bf16x8;
typedef __attribute__((ext_vector_type(4))) float f32x4;

__device__ __forceinline__ float bf2f(unsigned short u) {
    return __uint_as_float(((unsigned)u) << 16);
}
__device__ __forceinline__ float bflo(unsigned u) { return __uint_as_float(u << 16); }
__device__ __forceinline__ float bfhi(unsigned u) { return __uint_as_float(u & 0xffff0000u); }
__device__ __forceinline__ unsigned short f2bf(float x) {   // RNE
    unsigned u = __float_as_uint(x);
    u += 0x7fffu + ((u >> 16) & 1u);
    return (unsigned short)(u >> 16);
}
__device__ __forceinline__ unsigned pack2bf(float a, float b) {
    return (unsigned)f2bf(a) | ((unsigned)f2bf(b) << 16);
}
__device__ __forceinline__ void acc8(float* acc, uint4 v, float wg) {
    acc[0] += bflo(v.x) * wg; acc[1] += bfhi(v.x) * wg;
    acc[2] += bflo(v.y) * wg; acc[3] += bfhi(v.y) * wg;
    acc[4] += bflo(v.z) * wg; acc[5] += bfhi(v.z) * wg;
    acc[6] += bflo(v.w) * wg; acc[7] += bfhi(v.w) * wg;
}

// ---------------- split helpers ----------------
__device__ __forceinline__ void split_bf(float x, unsigned short& h, unsigned short& l) {
    unsigned u = __float_as_uint(x);
    h = (unsigned short)(u >> 16);
    float r = x - __uint_as_float(u & 0xffff0000u);
    l = (unsigned short)(__float_as_uint(r) >> 16);
}
__device__ __forceinline__ void do_split(const float* W, unsigned short* Wh, unsigned short* Wl,
                                         int i, int K, int N) {
    int n = i / K, k = i - n * K;
    unsigned short h, l;
    split_bf(W[(size_t)k * N + n], h, l);
    Wh[i] = h; Wl[i] = l;
}

// ---------------- fused prep: deg atomics + x->bf16 + weight transpose/split ----------------
__global__ __launch_bounds__(256) void prep_kernel(const int* __restrict__ ei, float* __restrict__ deg,
                                                   const float* __restrict__ x, unsigned short* __restrict__ xbf,
                                                   const float* __restrict__ W1, const float* __restrict__ W2,
                                                   const float* __restrict__ W3, const float* __restrict__ Wg,
                                                   unsigned short* __restrict__ W1th, unsigned short* __restrict__ W1tl,
                                                   unsigned short* __restrict__ W2th, unsigned short* __restrict__ W2tl,
                                                   unsigned short* __restrict__ W3th, unsigned short* __restrict__ W3tl,
                                                   unsigned short* __restrict__ Wgth, unsigned short* __restrict__ Wgtl) {
    int idx = blockIdx.x * 256 + threadIdx.x;     // 0..799999
    atomicAdd(&deg[ei[NEDGES + idx]], 1.0f);      // idx < NEDGES always
    {   // x -> bf16, 8 elems/thread
        float4 a = *(const float4*)&x[(size_t)idx * 8];
        float4 b = *(const float4*)&x[(size_t)idx * 8 + 4];
        uint4 o;
        o.x = pack2bf(a.x, a.y); o.y = pack2bf(a.z, a.w);
        o.z = pack2bf(b.x, b.y); o.w = pack2bf(b.z, b.w);
        *(uint4*)&xbf[(size_t)idx * 8] = o;
    }
    if (idx < 32768)        do_split(W1, W1th, W1tl, idx, 128, 256);
    else if (idx < 98304)   do_split(W2, W2th, W2tl, idx - 32768, 256, 256);
    else if (idx < 131072)  do_split(W3, W3th, W3tl, idx - 98304, 256, 128);
    else if (idx < 163840)  do_split(Wg, Wgth, Wgtl, idx - 131072, 128, 256);
}

// ---------------- hierarchical exclusive scan of (deg[i]+1), fused dinv ----------------
__global__ __launch_bounds__(256) void scan_part1(const float* __restrict__ deg, int* __restrict__ row,
                                                  int* __restrict__ bsum, float* __restrict__ dinv) {
    __shared__ int sdata[256];
    int t = threadIdx.x;
    int idx = blockIdx.x * 256 + t;
    float dg = idx < NNODES ? deg[idx] : 0.f;
    if (idx < NNODES) dinv[idx] = rsqrtf(dg + 1.0f);   // +1 = self loop
    int v = idx < NNODES ? (int)dg + 1 : 0;
    sdata[t] = v;
    __syncthreads();
    for (int off = 1; off < 256; off <<= 1) {
        int tmp = t >= off ? sdata[t - off] : 0;
        __syncthreads();
        sdata[t] += tmp;
        __syncthreads();
    }
    if (idx < NNODES) row[idx] = sdata[t] - v;
    if (t == 255) bsum[blockIdx.x] = sdata[255];
}

__global__ __launch_bounds__(256) void scan_part2(int* __restrict__ bsum, int* __restrict__ bofs,
                                                  int* __restrict__ row) {
    __shared__ int sdata[256];
    int t = threadIdx.x;
    int v = t < SCAN_B ? bsum[t] : 0;
    sdata[t] = v;
    __syncthreads();
    for (int off = 1; off < 256; off <<= 1) {
        int tmp = t >= off ? sdata[t - off] : 0;
        __syncthreads();
        sdata[t] += tmp;
        __syncthreads();
    }
    if (t < SCAN_B) bofs[t] = sdata[t] - v;
    if (t == 0) row[NNODES] = EN;
}

__global__ __launch_bounds__(256) void scan_part3(int* __restrict__ row, const int* __restrict__ bofs) {
    int idx = blockIdx.x * 256 + threadIdx.x;
    if (idx < NNODES) row[idx] += bofs[blockIdx.x];
}

// csr entry: {src, weight-bits} interleaved
__global__ __launch_bounds__(256) void scatter_kernel(const int* __restrict__ ei, const int* __restrict__ row,
                                                      int* __restrict__ cursor, const float* __restrict__ dinv,
                                                      uint2* __restrict__ csr) {
    int e = blockIdx.x * blockDim.x + threadIdx.x;
    if (e >= EN) return;
    int s, d;
    if (e < NEDGES) { s = ei[e]; d = ei[NEDGES + e]; } else { s = e - NEDGES; d = s; }
    int pos = row[d] + atomicAdd(&cursor[d], 1);
    csr[pos] = make_uint2((unsigned)s, __float_as_uint(dinv[s] * dinv[d]));
}

// ---------------- bf16-input MFMA GEMM: C[M,Nc] = A[M,K] @ W[K,Nc] ----------------
// MODE 0: raw bf16 store; MODE 1: bf16 store of relu(c + bias[col]);
// MODE 2: raw store + fused attention logits (als/ald) from fp32 accumulators.
template<int MODE>
__global__ __launch_bounds__(256) void gemm_bf(const unsigned short* __restrict__ A,
                                               const unsigned short* __restrict__ Wth,
                                               const unsigned short* __restrict__ Wtl,
                                               const float* __restrict__ bias,
                                               const float* __restrict__ asr, const float* __restrict__ ads,
                                               float* __restrict__ als, float* __restrict__ ald,
                                               unsigned short* __restrict__ C, int M, int K, int Nc) {
    __shared__ unsigned short As[128][40];
    __shared__ unsigned short Bh[128][40], Bl[128][40];
    int t = threadIdx.x;
    int row0 = blockIdx.x * 128, col0 = blockIdx.y * 128;
    int lane = t & 63, w = t >> 6;
    int mb = (w >> 1) * 64, nb = (w & 1) * 64;
    int lr = lane & 15, kg = (lane >> 4) * 8;

    f32x4 acc[4][4];
#pragma unroll
    for (int i = 0; i < 4; ++i)
#pragma unroll
        for (int j = 0; j < 4; ++j) acc[i][j] = (f32x4){0.f, 0.f, 0.f, 0.f};

    for (int k0 = 0; k0 < K; k0 += 32) {
#pragma unroll
        for (int it = 0; it < 2; ++it) {
            int q = it * 256 + t;
            int row = q >> 2, seg = (q & 3) * 8;
            int grow = row0 + row;
            uint4 v = make_uint4(0, 0, 0, 0);
            if (grow < M) v = *(const uint4*)&A[(size_t)grow * K + k0 + seg];
            *(uint4*)&As[row][seg] = v;
        }
#pragma unroll
        for (int it = 0; it < 2; ++it) {
            int o = it * 256 + t;
            int n = o >> 2, ko = (o & 3) * 8;
            size_t g = (size_t)(col0 + n) * K + k0 + ko;
            *(uint4*)&Bh[n][ko] = *(const uint4*)&Wth[g];
            *(uint4*)&Bl[n][ko] = *(const uint4*)&Wtl[g];
        }
        __syncthreads();

        bf16x8 a[4], bh[4], bl[4];
#pragma unroll
        for (int mf = 0; mf < 4; ++mf) a[mf] = *(const bf16x8*)&As[mb + mf * 16 + lr][kg];
#pragma unroll
        for (int nf = 0; nf < 4; ++nf) {
            bh[nf] = *(const bf16x8*)&Bh[nb + nf * 16 + lr][kg];
            bl[nf] = *(const bf16x8*)&Bl[nb + nf * 16 + lr][kg];
        }
#pragma unroll
        for (int mf = 0; mf < 4; ++mf)
#pragma unroll
            for (int nf = 0; nf < 4; ++nf) {
                acc[mf][nf] = __builtin_amdgcn_mfma_f32_16x16x32_bf16(a[mf], bh[nf], acc[mf][nf], 0, 0, 0);
                acc[mf][nf] = __builtin_amdgcn_mfma_f32_16x16x32_bf16(a[mf], bl[nf], acc[mf][nf], 0, 0, 0);
            }
        __syncthreads();
    }

    float s1[16], s2[16];
    if (MODE == 2) {
#pragma unroll
        for (int q = 0; q < 16; ++q) { s1[q] = 0.f; s2[q] = 0.f; }
    }

#pragma unroll
    for (int nf = 0; nf < 4; ++nf) {
        int col = col0 + nb + nf * 16 + lr;
        float bv = (MODE == 1) ? bias[col] : 0.f;
        float av = 0.f, dv = 0.f;
        if (MODE == 2) { av = asr[col]; dv = ads[col]; }
#pragma unroll
        for (int mf = 0; mf < 4; ++mf) {
#pragma unroll
            for (int r = 0; r < 4; ++r) {
                int row = row0 + mb + mf * 16 + (lane >> 4) * 4 + r;
                if (row < M) {
                    float v = acc[mf][nf][r];
                    if (MODE == 1) v = fmaxf(v + bv, 0.f);
                    C[(size_t)row * Nc + col] = f2bf(v);
                    if (MODE == 2) {
                        s1[mf * 4 + r] += v * av;
                        s2[mf * 4 + r] += v * dv;
                    }
                }
            }
        }
    }
    if (MODE == 2) {
        // reduce over the 16-lane col group (lr bits) -> complete 64-col (one-head) dots
        int head = (col0 + nb) >> 6;
#pragma unroll
        for (int q = 0; q < 16; ++q) {
#pragma unroll
            for (int off = 1; off < 16; off <<= 1) {
                s1[q] += __shfl_xor(s1[q], off);
                s2[q] += __shfl_xor(s2[q], off);
            }
        }
        if (lr == 0) {
#pragma unroll
            for (int mf = 0; mf < 4; ++mf) {
#pragma unroll
                for (int r = 0; r < 4; ++r) {
                    int row = row0 + mb + mf * 16 + (lane >> 4) * 4 + r;
                    if (row < M) {
                        als[row * 4 + head] = s1[mf * 4 + r];
                        ald[row * 4 + head] = s2[mf * 4 + r];
                    }
                }
            }
        }
    }
}

// ---------------- GCN gather aggregation (bf16, multi-edge, unroll-4) ----------------
// MODE 0: raw sum; MODE 1: relu(sum + b); MODE 2: relu(sum + b) + res(bf16)
template<int NC, int MODE>
__global__ __launch_bounds__(256) void gcn_agg_bf(const unsigned short* __restrict__ h, const int* __restrict__ row,
                                                  const uint2* __restrict__ csr,
                                                  const float* __restrict__ b, const unsigned short* __restrict__ res,
                                                  unsigned short* __restrict__ out) {
    int wid = (int)((blockIdx.x * blockDim.x + threadIdx.x) >> 6);
    if (wid >= NNODES) return;
    int lane = threadIdx.x & 63;
    constexpr int LPE = NC / 8;      // lanes per edge: 32 (NC=256) or 16 (NC=128)
    constexpr int EPI = 64 / LPE;    // edges per iter: 2 or 4
    int sub = lane / LPE, li = lane % LPE;
    int col = li * 8;
    float acc[8];
#pragma unroll
    for (int i = 0; i < 8; ++i) acc[i] = 0.f;
    int j0 = row[wid], j1 = row[wid + 1];
    int j = j0 + sub;
    for (; j + 3 * EPI < j1; j += 4 * EPI) {
        uint2 c0 = csr[j], c1 = csr[j + EPI], c2 = csr[j + 2 * EPI], c3 = csr[j + 3 * EPI];
        uint4 v0 = *(const uint4*)&h[(size_t)c0.x * NC + col];
        uint4 v1 = *(const uint4*)&h[(size_t)c1.x * NC + col];
        uint4 v2 = *(const uint4*)&h[(size_t)c2.x * NC + col];
        uint4 v3 = *(const uint4*)&h[(size_t)c3.x * NC + col];
        acc8(acc, v0, __uint_as_float(c0.y));
        acc8(acc, v1, __uint_as_float(c1.y));
        acc8(acc, v2, __uint_as_float(c2.y));
        acc8(acc, v3, __uint_as_float(c3.y));
    }
    for (; j < j1; j += EPI) {
        uint2 c0 = csr[j];
        uint4 v0 = *(const uint4*)&h[(size_t)c0.x * NC + col];
        acc8(acc, v0, __uint_as_float(c0.y));
    }
#pragma unroll
    for (int i = 0; i < 8; ++i) {
        acc[i] += __shfl_xor(acc[i], 32);
        if constexpr (EPI == 4) acc[i] += __shfl_xor(acc[i], 16);
    }
    if (lane < LPE) {
        if constexpr (MODE >= 1) {
#pragma unroll
            for (int i = 0; i < 8; ++i) acc[i] = fmaxf(acc[i] + b[col + i], 0.f);
        }
        if constexpr (MODE == 2) {
            uint4 rv = *(const uint4*)&res[(size_t)wid * NC + col];
            acc8(acc, rv, 1.0f);
        }
        uint4 o;
        o.x = pack2bf(acc[0], acc[1]); o.y = pack2bf(acc[2], acc[3]);
        o.z = pack2bf(acc[4], acc[5]); o.w = pack2bf(acc[6], acc[7]);
        *(uint4*)&out[(size_t)wid * NC + col] = o;
    }
}

__device__ __forceinline__ float lrelu(float x) { return x < 0.f ? 0.2f * x : x; }

// ---------------- GAT fused softmax + gather ----------------
__global__ __launch_bounds__(256) void gat_csr(const unsigned short* __restrict__ hg, const int* __restrict__ row,
                                               const uint2* __restrict__ csr, const float* __restrict__ als,
                                               const float* __restrict__ ald, const float* __restrict__ bg,
                                               unsigned short* __restrict__ out) {
    __shared__ float alds[4][64][4];   // [wave][edge slot][head] normalized alpha
    int wid = (int)((blockIdx.x * blockDim.x + threadIdx.x) >> 6);
    if (wid >= NNODES) return;
    int wv = threadIdx.x >> 6;
    int lane = threadIdx.x & 63;
    int j0 = row[wid], j1 = row[wid + 1];
    int deg = j1 - j0;
    float4 ad = *(const float4*)&ald[wid * 4];
    int sub = lane >> 5, li = lane & 31;
    int h = li >> 3;                 // head for this lane's 8-col slice
    int col = li * 8;
    float acc[8];
#pragma unroll
    for (int i = 0; i < 8; ++i) acc[i] = 0.f;

    if (deg <= 64) {
        int sreg = 0;
        float e0 = -1e30f, e1 = -1e30f, e2 = -1e30f, e3 = -1e30f;
        if (lane < deg) {
            sreg = (int)csr[j0 + lane].x;
            float4 as4 = *(const float4*)&als[sreg * 4];
            e0 = lrelu(as4.x + ad.x); e1 = lrelu(as4.y + ad.y);
            e2 = lrelu(as4.z + ad.z); e3 = lrelu(as4.w + ad.w);
        }
        float m0 = e0, m1 = e1, m2 = e2, m3 = e3;
#pragma unroll
        for (int off = 32; off >= 1; off >>= 1) {
            m0 = fmaxf(m0, __shfl_xor(m0, off));
            m1 = fmaxf(m1, __shfl_xor(m1, off));
            m2 = fmaxf(m2, __shfl_xor(m2, off));
            m3 = fmaxf(m3, __shfl_xor(m3, off));
        }
        float x0 = __expf(e0 - m0), x1 = __expf(e1 - m1);
        float x2 = __expf(e2 - m2), x3 = __expf(e3 - m3);
        float d0 = x0, d1 = x1, d2 = x2, d3 = x3;
#pragma unroll
        for (int off = 32; off >= 1; off >>= 1) {
            d0 += __shfl_xor(d0, off);
            d1 += __shfl_xor(d1, off);
            d2 += __shfl_xor(d2, off);
            d3 += __shfl_xor(d3, off);
        }
        float i0 = 1.f / d0, i1 = 1.f / d1, i2 = 1.f / d2, i3 = 1.f / d3;
        *(float4*)&alds[wv][lane][0] = make_float4(x0 * i0, x1 * i1, x2 * i2, x3 * i3);
        int k = sub;
        for (; k + 6 < deg; k += 8) {
            int s0 = __shfl(sreg, k),     s1 = __shfl(sreg, k + 2);
            int s2 = __shfl(sreg, k + 4), s3 = __shfl(sreg, k + 6);
            float a0 = alds[wv][k][h],     a1 = alds[wv][k + 2][h];
            float a2 = alds[wv][k + 4][h], a3 = alds[wv][k + 6][h];
            uint4 v0 = *(const uint4*)&hg[(size_t)s0 * 256 + col];
            uint4 v1 = *(const uint4*)&hg[(size_t)s1 * 256 + col];
            uint4 v2 = *(const uint4*)&hg[(size_t)s2 * 256 + col];
            uint4 v3 = *(const uint4*)&hg[(size_t)s3 * 256 + col];
            acc8(acc, v0, a0); acc8(acc, v1, a1);
            acc8(acc, v2, a2); acc8(acc, v3, a3);
        }
        for (; k < deg; k += 2) {
            int s0 = __shfl(sreg, k);
            float a0 = alds[wv][k][h];
            uint4 v0 = *(const uint4*)&hg[(size_t)s0 * 256 + col];
            acc8(acc, v0, a0);
        }
    } else {
        float m0 = -1e30f, m1 = -1e30f, m2 = -1e30f, m3 = -1e30f;
        float d0 = 0.f, d1 = 0.f, d2 = 0.f, d3 = 0.f;
        for (int j = j0 + lane; j < j1; j += 64) {
            int s = (int)csr[j].x;
            float4 as4 = *(const float4*)&als[s * 4];
            m0 = fmaxf(m0, lrelu(as4.x + ad.x));
            m1 = fmaxf(m1, lrelu(as4.y + ad.y));
            m2 = fmaxf(m2, lrelu(as4.z + ad.z));
            m3 = fmaxf(m3, lrelu(as4.w + ad.w));
        }
#pragma unroll
        for (int off = 32; off >= 1; off >>= 1) {
            m0 = fmaxf(m0, __shfl_xor(m0, off));
            m1 = fmaxf(m1, __shfl_xor(m1, off));
            m2 = fmaxf(m2, __shfl_xor(m2, off));
            m3 = fmaxf(m3, __shfl_xor(m3, off));
        }
        for (int j = j0 + lane; j < j1; j += 64) {
            int s = (int)csr[j].x;
            float4 as4 = *(const float4*)&als[s * 4];
            d0 += __expf(lrelu(as4.x + ad.x) - m0);
            d1 += __expf(lrelu(as4.y + ad.y) - m1);
            d2 += __expf(lrelu(as4.z + ad.z) - m2);
            d3 += __expf(lrelu(as4.w + ad.w) - m3);
        }
#pragma unroll
        for (int off = 32; off >= 1; off >>= 1) {
            d0 += __shfl_xor(d0, off);
            d1 += __shfl_xor(d1, off);
            d2 += __shfl_xor(d2, off);
            d3 += __shfl_xor(d3, off);
        }
        float mh   = h == 0 ? m0 : h == 1 ? m1 : h == 2 ? m2 : m3;
        float invh = 1.f / (h == 0 ? d0 : h == 1 ? d1 : h == 2 ? d2 : d3);
        float adh  = h == 0 ? ad.x : h == 1 ? ad.y : h == 2 ? ad.z : ad.w;
        for (int j = j0 + sub; j < j1; j += 2) {
            uint2 c0 = csr[j];
            float a0 = __expf(lrelu(als[c0.x * 4 + h] + adh) - mh) * invh;
            uint4 v0 = *(const uint4*)&hg[(size_t)c0.x * 256 + col];
            acc8(acc, v0, a0);
        }
    }

#pragma unroll
    for (int i = 0; i < 8; ++i) acc[i] += __shfl_xor(acc[i], 32);
    if (lane < 32) {
        uint4 o;
        o.x = pack2bf(fmaxf(acc[0] + bg[col], 0.f),     fmaxf(acc[1] + bg[col + 1], 0.f));
        o.y = pack2bf(fmaxf(acc[2] + bg[col + 2], 0.f), fmaxf(acc[3] + bg[col + 3], 0.f));
        o.z = pack2bf(fmaxf(acc[4] + bg[col + 4], 0.f), fmaxf(acc[5] + bg[col + 5], 0.f));
        o.w = pack2bf(fmaxf(acc[6] + bg[col + 6], 0.f), fmaxf(acc[7] + bg[col + 7], 0.f));
        *(uint4*)&out[(size_t)wid * 256 + col] = o;
    }
}

// ---------------- pooling (partials, no atomics) + MLP (reduces partials) ----------------
__global__ __launch_bounds__(256) void pool_kernel(const unsigned short* __restrict__ hatt, float* __restrict__ ppart) {
    int col = threadIdx.x;
    int r0 = blockIdx.x * 256;
    int r1 = r0 + 256 < NNODES ? r0 + 256 : NNODES;
    float s = 0.f;
    for (int r = r0; r < r1; ++r) s += bf2f(hatt[(size_t)r * 256 + col]);
    ppart[blockIdx.x * 256 + col] = s;
}

__global__ __launch_bounds__(256) void mlp_kernel(const float* __restrict__ ppart,
                                                  const float* __restrict__ Wc1, const float* __restrict__ bc1,
                                                  const float* __restrict__ Wc2, const float* __restrict__ bc2,
                                                  const float* __restrict__ Wc3, const float* __restrict__ bc3,
                                                  float* __restrict__ out) {
    __shared__ float p[256], z1[128], z2[64];
    int t = threadIdx.x;
    float s0 = 0.f;
    for (int b = 0; b < SCAN_B; ++b) s0 += ppart[b * 256 + t];
    p[t] = s0 * (1.0f / NNODES);
    __syncthreads();
    if (t < 128) {
        float s = bc1[t];
        for (int k = 0; k < 256; ++k) s += p[k] * Wc1[k * 128 + t];
        z1[t] = fmaxf(s, 0.f);
    }
    __syncthreads();
    if (t < 64) {
        float s = bc2[t];
        for (int k = 0; k < 128; ++k) s += z1[k] * Wc2[k * 64 + t];
        z2[t] = fmaxf(s, 0.f);
    }
    __syncthreads();
    if (t < 8) {
        float s = bc3[t];
        for (int k = 0; k < 64; ++k) s += z2[k] * Wc3[k * 8 + t];
        out[t] = s;
    }
}

extern "C" void kernel_launch(void* const* d_in, const int* in_sizes, int n_in,
                              void* d_out, int out_size, void* d_ws, size_t ws_size,
                              hipStream_t stream) {
    const float* x   = (const float*)d_in[0];
    const int*   ei  = (const int*)d_in[1];
    const float* W1  = (const float*)d_in[2];  const float* b1  = (const float*)d_in[3];
    const float* W2  = (const float*)d_in[4];  const float* b2  = (const float*)d_in[5];
    const float* W3  = (const float*)d_in[6];  const float* b3  = (const float*)d_in[7];
    const float* Wg  = (const float*)d_in[8];
    const float* asr = (const float*)d_in[9];  const float* ads = (const float*)d_in[10];
    const float* bg  = (const float*)d_in[11];
    const float* Wc1 = (const float*)d_in[12]; const float* bc1 = (const float*)d_in[13];
    const float* Wc2 = (const float*)d_in[14]; const float* bc2 = (const float*)d_in[15];
    const float* Wc3 = (const float*)d_in[16]; const float* bc3 = (const float*)d_in[17];
    float* out = (float*)d_out;

    char* w = (char*)d_ws;
    float* deg    = (float*)w; w += (size_t)NNODES * 4;          // deg+cursor adjacent: one memset
    int*   cursor = (int*)w;   w += (size_t)NNODES * 4;
    float* dinv   = (float*)w; w += (size_t)NNODES * 4;
    int*   rowp   = (int*)w;   w += 200016;                      // (NNODES+1)*4 padded
    int*   bsum   = (int*)w;   w += 256 * 4;
    int*   bofs   = (int*)w;   w += 256 * 4;
    uint2* csr    = (uint2*)w; w += (size_t)EN * 8;
    float* als    = (float*)w; w += (size_t)NNODES * 4 * 4;
    float* ald    = (float*)w; w += (size_t)NNODES * 4 * 4;
    float* ppart  = (float*)w; w += (size_t)SCAN_B * 256 * 4;
    unsigned short* W1th = (unsigned short*)w; w += 128 * 256 * 2;
    unsigned short* W1tl = (unsigned short*)w; w += 128 * 256 * 2;
    unsigned short* W2th = (unsigned short*)w; w += 256 * 256 * 2;
    unsigned short* W2tl = (unsigned short*)w; w += 256 * 256 * 2;
    unsigned short* W3th = (unsigned short*)w; w += 256 * 128 * 2;
    unsigned short* W3tl = (unsigned short*)w; w += 256 * 128 * 2;
    unsigned short* Wgth = (unsigned short*)w; w += 128 * 256 * 2;
    unsigned short* Wgtl = (unsigned short*)w; w += 128 * 256 * 2;
    unsigned short* U1 = (unsigned short*)w; w += (size_t)NNODES * 256 * 2;
    unsigned short* U2 = (unsigned short*)w; w += (size_t)NNODES * 256 * 2;
    unsigned short* U3 = (unsigned short*)w; w += (size_t)NNODES * 256 * 2;
    unsigned short* U4 = (unsigned short*)w; w += (size_t)NNODES * 256 * 2;

    // prep: one memset (deg+cursor contiguous), fused prep, scan, CSR
    hipMemsetAsync(deg, 0, (size_t)NNODES * 8, stream);
    prep_kernel<<<3125, 256, 0, stream>>>(ei, deg, x, U1, W1, W2, W3, Wg,
                                          W1th, W1tl, W2th, W2tl, W3th, W3tl, Wgth, Wgtl);
    scan_part1<<<SCAN_B, 256, 0, stream>>>(deg, rowp, bsum, dinv);
    scan_part2<<<1, 256, 0, stream>>>(bsum, bofs, rowp);
    scan_part3<<<SCAN_B, 256, 0, stream>>>(rowp, bofs);
    scatter_kernel<<<(EN + 255) / 256, 256, 0, stream>>>(ei, rowp, cursor, dinv, csr);

    dim3 gA((NNODES + 127) / 128, 2);   // Nc = 256
    dim3 gB((NNODES + 127) / 128, 1);   // Nc = 128
    int aggBlocks = (NNODES * 64 + 255) / 256;

    // GCN 1 (reordered): aggX = agg(xbf) [N,128] -> U2; h1 = relu(aggX@W1 + b1) -> U3
    gcn_agg_bf<128, 0><<<aggBlocks, 256, 0, stream>>>(U1, rowp, csr, nullptr, nullptr, U2);
    gemm_bf<1><<<gA, 256, 0, stream>>>(U2, W1th, W1tl, b1, nullptr, nullptr, nullptr, nullptr, U3, NNODES, 128, 256);

    // GCN 2: t2 = h1@W2 -> U1; h2 = relu(agg(t2) + b2) + h1 -> U2
    gemm_bf<0><<<gA, 256, 0, stream>>>(U3, W2th, W2tl, nullptr, nullptr, nullptr, nullptr, nullptr, U1, NNODES, 256, 256);
    gcn_agg_bf<256, 2><<<aggBlocks, 256, 0, stream>>>(U1, rowp, csr, b2, U3, U2);

    // GCN 3: t3 = h2@W3 -> U4 [N,128]; h3 = relu(agg(t3) + b3) -> U1 [N,128]
    gemm_bf<0><<<gB, 256, 0, stream>>>(U2, W3th, W3tl, nullptr, nullptr, nullptr, nullptr, nullptr, U4, NNODES, 256, 128);
    gcn_agg_bf<128, 1><<<aggBlocks, 256, 0, stream>>>(U4, rowp, csr, b3, nullptr, U1);

    // GAT: hg = h3@Wg -> U2 [N,256] with fused als/ald; fused softmax-aggregate -> U3
    gemm_bf<2><<<gA, 256, 0, stream>>>(U1, Wgth, Wgtl, nullptr, asr, ads, als, ald, U2, NNODES, 128, 256);
    gat_csr<<<aggBlocks, 256, 0, stream>>>(U2, rowp, csr, als, ald, bg, U3);

    // mean pool + MLP
    pool_kernel<<<SCAN_B, 256, 0, stream>>>(U3, ppart);
    mlp_kernel<<<1, 256, 0, stream>>>(ppart, Wc1, bc1, Wc2, bc2, Wc3, bc3, out);
}